// Round 7
// baseline (1599.085 us; speedup 1.0000x reference)
//
#include <hip/hip_runtime.h>
#include <hip/hip_bf16.h>

typedef unsigned short ushort_t;
typedef unsigned int uint_t;
typedef __attribute__((ext_vector_type(8))) short short8;
typedef __attribute__((ext_vector_type(4))) float float4v;

static constexpr int NN  = 100000;   // nodes
static constexpr int NE  = 400000;   // edges
static constexpr int NB  = 500;      // graphs
static constexpr int NS  = 75;       // seeds
static constexpr int H   = 128;
static constexpr int GN  = (NN + 255)/256;   // 391 scan chunks
static constexpr float SCALE = 0.08838834764831845f; // 1/sqrt(128)

union U32 { uint_t u; float f; };
__device__ __forceinline__ float bf2f(ushort_t b){ U32 t; t.u = ((uint_t)b) << 16; return t.f; }
__device__ __forceinline__ ushort_t f2bf(float f){
    U32 t; t.f = f;
    uint_t r = t.u + 0x7fffu + ((t.u >> 16) & 1u);   // RNE
    return (ushort_t)(r >> 16);
}
__device__ __forceinline__ void fma8(float* a, uint4 u, float c){
    a[0] += c * bf2f((ushort_t)(u.x & 0xffff)); a[1] += c * bf2f((ushort_t)(u.x >> 16));
    a[2] += c * bf2f((ushort_t)(u.y & 0xffff)); a[3] += c * bf2f((ushort_t)(u.y >> 16));
    a[4] += c * bf2f((ushort_t)(u.z & 0xffff)); a[5] += c * bf2f((ushort_t)(u.z >> 16));
    a[6] += c * bf2f((ushort_t)(u.w & 0xffff)); a[7] += c * bf2f((ushort_t)(u.w >> 16));
}

// ===== manual device-scope grid barrier (all blocks must be co-resident) =====
__device__ __forceinline__ void gridbar(int* bar, int nblk){
    __threadfence();
    __syncthreads();
    if (threadIdx.x == 0){
        int g = __hip_atomic_load(&bar[1], __ATOMIC_RELAXED, __HIP_MEMORY_SCOPE_AGENT);
        int v = __hip_atomic_fetch_add(&bar[0], 1, __ATOMIC_ACQ_REL, __HIP_MEMORY_SCOPE_AGENT);
        if (v == nblk - 1){
            __hip_atomic_store(&bar[0], 0, __ATOMIC_RELAXED, __HIP_MEMORY_SCOPE_AGENT);
            __hip_atomic_fetch_add(&bar[1], 1, __ATOMIC_RELEASE, __HIP_MEMORY_SCOPE_AGENT);
        } else {
            while (__hip_atomic_load(&bar[1], __ATOMIC_ACQUIRE, __HIP_MEMORY_SCOPE_AGENT) == g)
                __builtin_amdgcn_s_sleep(2);
        }
        __threadfence();
    }
    __syncthreads();
}

// ================= conversions sizes =================
static constexpr int CVT_W   = 17*16384;
static constexpr int CVT_W0  = 8192;
static constexpr int CVT_S1  = 9600;
static constexpr int CVT_S2  = 128;
static constexpr int CVT_X   = NN*64;
static constexpr int CVT_TOT = CVT_W + CVT_W0 + CVT_S1 + CVT_S2 + CVT_X;

// ===== fused preprocessing: CSR build + conversions + seedQ + hERG (1 launch) =====
struct PreArgs {
    int* counts; int* cursor; int* row_st; int* bSums; int* bOff;
    float* dinv; float* selfc; int* srcs_s; float* ce_s;
    const int* esrc; const int* edst;
    const float* w[17]; const float* w0; const float* s1; const float* s2; const float* x37;
    ushort_t* wbf; ushort_t* w0bf; ushort_t* s1bf; ushort_t* s2bf; ushort_t* xb64;
    const float* p1fqb; const float* p2fqb; ushort_t* q0; ushort_t* q2;
    const float* hem; const float* hlW; const float* hlb; float* hergv;
    int* bar;
};

__global__ __launch_bounds__(256, 2) void k_pre(PreArgs a){
    __shared__ float shf[1344];       // aliased: int s[256] / int s2[512] / float e[1280]
    const int tid  = threadIdx.x;
    const int gtid = blockIdx.x*256 + tid;
    const int gsz  = gridDim.x*256;
    const int nblk = gridDim.x;

    // ---- P1: zero counts + all dtype conversions ----
    for (int i = gtid; i < NN; i += gsz) a.counts[i] = 0;
    for (int j = gtid; j < CVT_TOT; j += gsz){
        int i = j;
        if (i < CVT_W){ int idx = i >> 14, off = i & 16383; a.wbf[i] = f2bf(a.w[idx][off]); continue; }
        i -= CVT_W;
        if (i < CVT_W0){ int r = i >> 6, c = i & 63; a.w0bf[i] = (c < 37) ? f2bf(a.w0[r*37 + c]) : (ushort_t)0; continue; }
        i -= CVT_W0;
        if (i < CVT_S1){ a.s1bf[i] = f2bf(a.s1[i]); continue; }
        i -= CVT_S1;
        if (i < CVT_S2){ a.s2bf[i] = f2bf(a.s2[i]); continue; }
        i -= CVT_S2;
        { int r = i >> 6, c = i & 63; a.xb64[i] = (c < 37) ? f2bf(a.x37[(size_t)r*37 + c]) : (ushort_t)0; }
    }
    gridbar(a.bar, nblk);

    // ---- P2: in-degree histogram ----
    for (int i = gtid; i < NE; i += gsz) atomicAdd(&a.counts[a.edst[i]], 1);
    gridbar(a.bar, nblk);

    // ---- P3: per-chunk scan (+ degree norms); spare blocks do seedQ + hERG ----
    for (int u = blockIdx.x; u < GN + 4; u += gridDim.x){
        if (u < GN){
            int* si = (int*)shf;
            int i = u*256 + tid;
            int v = (i < NN) ? a.counts[i] : 0;
            si[tid] = v; __syncthreads();
            #pragma unroll
            for (int off = 1; off < 256; off <<= 1){
                int add = (tid >= off) ? si[tid-off] : 0;
                __syncthreads();
                si[tid] += add;
                __syncthreads();
            }
            if (i < NN){
                a.row_st[i] = si[tid] - v;
                float r = rsqrtf(1.f + (float)v);
                a.dinv[i] = r; a.selfc[i] = r*r;
            }
            if (tid == 255) a.bSums[u] = si[255];
            __syncthreads();
        } else {
            int blk = u - GN;
            if (blk == 3){
                float* e = shf;
                for (int i = tid; i < 1280; i += 256) e[i] = a.hem[i];
                __syncthreads();
                if (tid < 128){
                    float acc = 0.f;
                    for (int k = 0; k < 1280; ++k) acc += e[k] * a.hlW[(size_t)tid*1280 + k];
                    a.hergv[tid] = fmaxf(acc + a.hlb[tid], 0.f);
                }
                __syncthreads();
            } else {
                const ushort_t* x = (blk < 2) ? a.s1bf : a.s2bf;
                const ushort_t* W = (blk < 2) ? (a.wbf + (size_t)15*16384) : (a.wbf + (size_t)16*16384);
                const float* bias = (blk < 2) ? a.p1fqb : a.p2fqb;
                ushort_t* out = (blk < 2) ? a.q0 : a.q2;
                int M = (blk < 2) ? NS : 1;
                int base = (blk < 2) ? blk*64 : 0;
                int wid  = tid >> 6;
                int lane = tid & 63;
                int l15  = lane & 15, quad = lane >> 4;
                int row0 = base + wid*16;
                int ar   = row0 + l15; if (ar > M-1) ar = M-1;
                const short* xr = (const short*)(x + (size_t)ar*H) + quad*8;
                float4v acc[8];
                #pragma unroll
                for (int i = 0; i < 8; ++i) acc[i] = (float4v)0.f;
                #pragma unroll
                for (int kc = 0; kc < 4; ++kc){
                    short8 av = *(const short8*)(xr + kc*32);
                    #pragma unroll
                    for (int nt = 0; nt < 8; ++nt){
                        short8 bv = *(const short8*)((const short*)(W + (size_t)(nt*16 + l15)*H) + kc*32 + quad*8);
                        acc[nt] = __builtin_amdgcn_mfma_f32_16x16x32_bf16(av, bv, acc[nt], 0, 0, 0);
                    }
                }
                #pragma unroll
                for (int nt = 0; nt < 8; ++nt){
                    int c = nt*16 + l15;
                    float bv = bias[c];
                    #pragma unroll
                    for (int reg = 0; reg < 4; ++reg){
                        int r = row0 + quad*4 + reg;
                        if (r >= M) continue;
                        out[(size_t)r*H + c] = f2bf(acc[nt][reg] + bv);
                    }
                }
            }
        }
    }
    gridbar(a.bar, nblk);

    // ---- P4: scan of block sums (block 0 only) ----
    if (blockIdx.x == 0){
        int* s2 = (int*)shf;
        s2[tid]       = (tid < GN) ? a.bSums[tid] : 0;
        s2[tid + 256] = (tid + 256 < GN) ? a.bSums[tid + 256] : 0;
        int v0 = s2[tid], v1 = s2[tid + 256];
        __syncthreads();
        for (int off = 1; off < 512; off <<= 1){
            int a0 = (tid >= off) ? s2[tid - off] : 0;
            int a1 = (tid + 256 >= off) ? s2[tid + 256 - off] : 0;
            __syncthreads();
            s2[tid] += a0; s2[tid + 256] += a1;
            __syncthreads();
        }
        if (tid < GN) a.bOff[tid] = s2[tid] - v0;
        if (tid + 256 < GN) a.bOff[tid + 256] = s2[tid + 256] - v1;
    }
    gridbar(a.bar, nblk);

    // ---- P5: apply block offsets, init cursor ----
    for (int i = gtid; i < NN; i += gsz){
        int v = a.row_st[i] + a.bOff[i >> 8];
        a.row_st[i] = v; a.cursor[i] = v;
    }
    if (gtid == 0) a.row_st[NN] = NE;
    gridbar(a.bar, nblk);

    // ---- P6: fill CSR ----
    for (int i = gtid; i < NE; i += gsz){
        int d = a.edst[i], s = a.esrc[i];
        int p = atomicAdd(&a.cursor[d], 1);
        a.srcs_s[p] = s;
        a.ce_s[p] = a.dinv[s] * a.dinv[d];
    }
}

// ========== two-stage GEMM: y = x + relu(x@Wfo+bfo); then N outputs SEQUENTIALLY ==========
template<int NOUT2>
__global__ __launch_bounds__(256, 4) void gemm_fo_then(
    const ushort_t* __restrict__ x, int M,
    const ushort_t* __restrict__ Wfo, const float* __restrict__ bfo,
    const ushort_t* __restrict__ W2,            // [NOUT2*128][128]
    const float* __restrict__ b20, const float* __restrict__ b21, const float* __restrict__ b22,
    ushort_t* __restrict__ o0, ushort_t* __restrict__ o1, ushort_t* __restrict__ o2,
    float* __restrict__ o32)
{
    __shared__ ushort_t As[64][136];
    const int tid = threadIdx.x, w = tid >> 6, lane = tid & 63;
    const int l15 = lane & 15, quad = lane >> 4;
    const int row0 = blockIdx.x*64 + w*16;
    int ar = row0 + l15; if (ar > M-1) ar = M-1;
    const short* xr = (const short*)(x + (size_t)ar*H) + quad*8;
    {
        float4v acc[8];
        #pragma unroll
        for (int i = 0; i < 8; ++i) acc[i] = (float4v)0.f;
        #pragma unroll
        for (int kc = 0; kc < 4; ++kc){
            short8 a = *(const short8*)(xr + kc*32);
            #pragma unroll
            for (int nt = 0; nt < 8; ++nt){
                short8 b = *(const short8*)((const short*)(Wfo + (size_t)(nt*16 + l15)*H) + kc*32 + quad*8);
                acc[nt] = __builtin_amdgcn_mfma_f32_16x16x32_bf16(a, b, acc[nt], 0, 0, 0);
            }
        }
        #pragma unroll
        for (int nt = 0; nt < 8; ++nt){
            int c = nt*16 + l15;
            float bv = bfo[c];
            #pragma unroll
            for (int reg = 0; reg < 4; ++reg){
                int r = row0 + quad*4 + reg;
                float v = 0.f;
                if (r < M) v = fmaxf(acc[nt][reg] + bv, 0.f) + bf2f(x[(size_t)r*H + c]);
                As[w*16 + quad*4 + reg][c] = f2bf(v);
            }
        }
    }
    __syncthreads();
    #pragma unroll 1
    for (int n = 0; n < NOUT2; ++n){
        float4v o[8];
        #pragma unroll
        for (int i = 0; i < 8; ++i) o[i] = (float4v)0.f;
        #pragma unroll
        for (int kc = 0; kc < 4; ++kc){
            short8 a = *(const short8*)(&As[w*16 + l15][kc*32 + quad*8]);
            #pragma unroll
            for (int nt = 0; nt < 8; ++nt){
                short8 b = *(const short8*)((const short*)(W2 + (size_t)((n*8 + nt)*16 + l15)*H) + kc*32 + quad*8);
                o[nt] = __builtin_amdgcn_mfma_f32_16x16x32_bf16(a, b, o[nt], 0, 0, 0);
            }
        }
        ushort_t* out = (n == 0) ? o0 : ((n == 1) ? o1 : o2);
        const float* bb = (n == 0) ? b20 : ((n == 1) ? b21 : b22);
        #pragma unroll
        for (int nt = 0; nt < 8; ++nt){
            int c = nt*16 + l15;
            float bv = bb[c];
            #pragma unroll
            for (int reg = 0; reg < 4; ++reg){
                int r = row0 + quad*4 + reg;
                if (r >= M) continue;
                float v = o[nt][reg] + bv;
                if (o32 && n == 0) o32[(size_t)r*H + c] = v;
                else               out[(size_t)r*H + c] = f2bf(v);
            }
        }
    }
}

// ========== fused gather + MFMA GEMM v3 (2-edge unroll + index prefetch) ==========
// NOUT==16 writes K/V head-major: record = 32 elems (64B) per (head-pair, node)
template<int NOUT, int RELU, int STAGE2, int MINW>
__global__ __launch_bounds__(256, MINW) void k_conv_fused3(
    const ushort_t* __restrict__ x,
    const int* __restrict__ row_st, const int* __restrict__ srcs,
    const float* __restrict__ ces, const float* __restrict__ selfc,
    const ushort_t* __restrict__ W, const float* __restrict__ bias0,
    const float* __restrict__ bias1,
    const ushort_t* __restrict__ W2, const float* __restrict__ bias2,
    ushort_t* __restrict__ out0, ushort_t* __restrict__ out1)
{
    __shared__ ushort_t As[32][136];
    __shared__ ushort_t Bs[(NOUT==16)?32:1][(NOUT==16)?136:1];
    const int tid = threadIdx.x;
    const int node = tid >> 3, qq = tid & 7;   // 8 threads/node, 16 cols each
    const int g = blockIdx.x*32 + node;
    float acc[16];
    #pragma unroll
    for (int i = 0; i < 16; ++i) acc[i] = 0.f;
    if (g < NN){
        const uint4* xr = (const uint4*)(x + (size_t)g*H + qq*16);
        float sc = selfc[g];
        uint4 u0 = xr[0], u1 = xr[1];
        fma8(acc+0, u0, sc); fma8(acc+8, u1, sc);
        int e = row_st[g], e1 = row_st[g+1];
        int sA = 0, sB = 0; float cA = 0.f, cB = 0.f;
        if (e < e1){ sA = srcs[e]; cA = ces[e]; }
        if (e + 1 < e1){ sB = srcs[e+1]; cB = ces[e+1]; }
        while (e + 2 <= e1){
            // prefetch next pair's indices (overlaps with data-load latency)
            int sA2 = 0, sB2 = 0; float cA2 = 0.f, cB2 = 0.f;
            if (e + 2 < e1){ sA2 = srcs[e+2]; cA2 = ces[e+2]; }
            if (e + 3 < e1){ sB2 = srcs[e+3]; cB2 = ces[e+3]; }
            const uint4* pa = (const uint4*)(x + (size_t)sA*H + qq*16);
            const uint4* pb = (const uint4*)(x + (size_t)sB*H + qq*16);
            uint4 a0 = pa[0], a1 = pa[1];
            uint4 c0 = pb[0], c1 = pb[1];
            fma8(acc+0, a0, cA); fma8(acc+8, a1, cA);
            fma8(acc+0, c0, cB); fma8(acc+8, c1, cB);
            sA = sA2; sB = sB2; cA = cA2; cB = cB2;
            e += 2;
        }
        if (e < e1){
            const uint4* pa = (const uint4*)(x + (size_t)sA*H + qq*16);
            uint4 a0 = pa[0], a1 = pa[1];
            fma8(acc+0, a0, cA); fma8(acc+8, a1, cA);
        }
    }
    {
        uint_t* dst = (uint_t*)&As[node][qq*16];
        #pragma unroll
        for (int i = 0; i < 8; ++i)
            dst[i] = (uint_t)f2bf(acc[2*i]) | ((uint_t)f2bf(acc[2*i+1]) << 16);
    }
    __syncthreads();
    const int w = tid >> 6, lane = tid & 63, l15 = lane & 15, quad = lane >> 4;
    const int rt = w & 1;                  // row tile (16 rows)
    constexpr int NT = NOUT/2;             // col tiles per wave
    const int ct0 = (w >> 1) * NT;
    float4v o[NT];
    #pragma unroll
    for (int t = 0; t < NT; ++t) o[t] = (float4v)0.f;
    #pragma unroll
    for (int kc = 0; kc < 4; ++kc){
        short8 a = *(const short8*)(&As[rt*16 + l15][kc*32 + quad*8]);
        #pragma unroll
        for (int t = 0; t < NT; ++t){
            short8 bfr = *(const short8*)(W + (size_t)((ct0 + t)*16 + l15)*H + kc*32 + quad*8);
            o[t] = __builtin_amdgcn_mfma_f32_16x16x32_bf16(a, bfr, o[t], 0, 0, 0);
        }
    }
    __syncthreads();
    #pragma unroll
    for (int t = 0; t < NT; ++t){
        int cg = (ct0 + t)*16 + l15;
        #pragma unroll
        for (int r = 0; r < 4; ++r){
            float v;
            if (NOUT == 8 || cg < 128){
                v = o[t][r] + bias0[cg];
                if (RELU) v = fmaxf(v, 0.f);
                As[rt*16 + quad*4 + r][cg] = f2bf(v);
            } else {
                v = o[t][r] + bias1[cg - 128];
                if (RELU) v = fmaxf(v, 0.f);
                Bs[rt*16 + quad*4 + r][cg - 128] = f2bf(v);
            }
        }
    }
    __syncthreads();
    if (STAGE2){
        float4v o2[4];
        #pragma unroll
        for (int t = 0; t < 4; ++t) o2[t] = (float4v)0.f;
        const int ct2 = (w >> 1) * 4;
        #pragma unroll
        for (int kc = 0; kc < 4; ++kc){
            short8 a = *(const short8*)(&As[rt*16 + l15][kc*32 + quad*8]);
            #pragma unroll
            for (int t = 0; t < 4; ++t){
                short8 bfr = *(const short8*)(W2 + (size_t)((ct2 + t)*16 + l15)*H + kc*32 + quad*8);
                o2[t] = __builtin_amdgcn_mfma_f32_16x16x32_bf16(a, bfr, o2[t], 0, 0, 0);
            }
        }
        __syncthreads();
        #pragma unroll
        for (int t = 0; t < 4; ++t){
            int cg = (ct2 + t)*16 + l15;
            #pragma unroll
            for (int r = 0; r < 4; ++r)
                As[rt*16 + quad*4 + r][cg] = f2bf(o2[t][r] + bias2[cg]);
        }
        __syncthreads();
    }
    if (g < NN){
        if (NOUT == 16){
            // head-major K/V for attention: dest = [(hp)*NN + node]*32 + (qq&1)*16 elems
            size_t kb = ((size_t)(qq >> 1)*NN + (size_t)g)*32 + (size_t)(qq & 1)*16;
            ((uint4*)(out0 + kb))[0] = *(const uint4*)&As[node][qq*16];
            ((uint4*)(out0 + kb))[1] = *(const uint4*)&As[node][qq*16 + 8];
            ((uint4*)(out1 + kb))[0] = *(const uint4*)&Bs[node][qq*16];
            ((uint4*)(out1 + kb))[1] = *(const uint4*)&Bs[node][qq*16 + 8];
        } else {
            uint4* op = (uint4*)(out0 + (size_t)g*H + qq*16);
            const uint4* sp = (const uint4*)&As[node][qq*16];
            op[0] = sp[0]; op[1] = sp[1];
        }
    }
}

// ========== conv0: gather padded-64 bf16 rows + MFMA GEMM (K=64) ==========
__global__ __launch_bounds__(256, 8) void k_conv0b(
    const ushort_t* __restrict__ x,   // [NN][64] bf16
    const int* __restrict__ row_st, const int* __restrict__ srcs,
    const float* __restrict__ ces, const float* __restrict__ selfc,
    const ushort_t* __restrict__ W,   // [128][64]
    const float* __restrict__ bias,
    ushort_t* __restrict__ out)
{
    __shared__ ushort_t As[32][136];
    const int tid = threadIdx.x;
    const int node = tid >> 3, qq = tid & 7;   // 8 cols (1 uint4) each
    const int g = blockIdx.x*32 + node;
    float acc[8];
    #pragma unroll
    for (int i = 0; i < 8; ++i) acc[i] = 0.f;
    if (g < NN){
        const uint4* xr = (const uint4*)(x + (size_t)g*64 + qq*8);
        float sc = selfc[g];
        fma8(acc, xr[0], sc);
        int e = row_st[g], e1 = row_st[g+1];
        int sA = 0, sB = 0; float cA = 0.f, cB = 0.f;
        if (e < e1){ sA = srcs[e]; cA = ces[e]; }
        if (e + 1 < e1){ sB = srcs[e+1]; cB = ces[e+1]; }
        while (e + 2 <= e1){
            int sA2 = 0, sB2 = 0; float cA2 = 0.f, cB2 = 0.f;
            if (e + 2 < e1){ sA2 = srcs[e+2]; cA2 = ces[e+2]; }
            if (e + 3 < e1){ sB2 = srcs[e+3]; cB2 = ces[e+3]; }
            uint4 a0 = *(const uint4*)(x + (size_t)sA*64 + qq*8);
            uint4 c0 = *(const uint4*)(x + (size_t)sB*64 + qq*8);
            fma8(acc, a0, cA);
            fma8(acc, c0, cB);
            sA = sA2; sB = sB2; cA = cA2; cB = cB2;
            e += 2;
        }
        if (e < e1){
            uint4 a0 = *(const uint4*)(x + (size_t)sA*64 + qq*8);
            fma8(acc, a0, cA);
        }
    }
    {
        uint_t* dst = (uint_t*)&As[node][qq*8];
        #pragma unroll
        for (int i = 0; i < 4; ++i)
            dst[i] = (uint_t)f2bf(acc[2*i]) | ((uint_t)f2bf(acc[2*i+1]) << 16);
    }
    __syncthreads();
    const int w = tid >> 6, lane = tid & 63, l15 = lane & 15, quad = lane >> 4;
    const int rt = w & 1;
    const int ct0 = (w >> 1) * 4;
    float4v o[4];
    #pragma unroll
    for (int t = 0; t < 4; ++t) o[t] = (float4v)0.f;
    #pragma unroll
    for (int kc = 0; kc < 2; ++kc){
        short8 a = *(const short8*)(&As[rt*16 + l15][kc*32 + quad*8]);
        #pragma unroll
        for (int t = 0; t < 4; ++t){
            short8 bfr = *(const short8*)(W + (size_t)((ct0 + t)*16 + l15)*64 + kc*32 + quad*8);
            o[t] = __builtin_amdgcn_mfma_f32_16x16x32_bf16(a, bfr, o[t], 0, 0, 0);
        }
    }
    __syncthreads();
    #pragma unroll
    for (int t = 0; t < 4; ++t){
        int cg = (ct0 + t)*16 + l15;
        #pragma unroll
        for (int r = 0; r < 4; ++r)
            As[rt*16 + quad*4 + r][cg] = f2bf(fmaxf(o[t][r] + bias[cg], 0.f));
    }
    __syncthreads();
    if (g < NN){
        uint4* op = (uint4*)(out + (size_t)g*H + qq*16);
        const uint4* sp = (const uint4*)&As[node][qq*16];
        op[0] = sp[0]; op[1] = sp[1];
    }
}

// ========== MFMA flash attention ==========
// HM=1: K,V are head-major [(hp)*NN + b*NK + key]*32 elems (64B records, 2 heads x 16)
template<int NK, int HM>
__global__ __launch_bounds__(256) void k_attn_mfma(
    const ushort_t* __restrict__ Q, int qbs,
    const ushort_t* __restrict__ K, const ushort_t* __restrict__ V,
    ushort_t* __restrict__ out, int nq)
{
    constexpr int NKT = (NK + 15) / 16;
    constexpr int NKC = (NK + 31) / 32;
    __shared__ ushort_t Ks[2][208][24];
    __shared__ ushort_t Vs[2][16][232];
    __shared__ ushort_t Ps[4][16][232];
    int b = blockIdx.x >> 2, hp = blockIdx.x & 3;
    int h0 = hp*2;
    int tid = threadIdx.x;
    {
        uint_t* p = (uint_t*)&Ps[0][0][0];
        for (int i = tid; i < 4*16*232/2; i += 256) p[i] = 0;
    }
    const ushort_t* Kb = HM ? (K + ((size_t)hp*NB + b)*NK*32)
                            : (K + (size_t)b*NK*H + h0*16);
    for (int idx = tid; idx < NK*8; idx += 256){
        int key = idx >> 3, p = idx & 7;
        int hh = p >> 2, dl = (p & 3)*4;
        const uint_t* src = HM ? (const uint_t*)(Kb + (size_t)key*32 + hh*16 + dl)
                               : (const uint_t*)(Kb + (size_t)key*H + hh*16 + dl);
        uint_t* d = (uint_t*)&Ks[hh][key][dl];
        d[0] = src[0]; d[1] = src[1];
    }
    const ushort_t* Vb = HM ? (V + ((size_t)hp*NB + b)*NK*32)
                            : (V + (size_t)b*NK*H + h0*16);
    for (int idx = tid; idx < NK*8; idx += 256){
        int key = idx >> 3, p = idx & 7;
        int hh = p >> 2, dl = (p & 3)*4;
        const ushort_t* src = HM ? (Vb + (size_t)key*32 + hh*16 + dl)
                                 : (Vb + (size_t)key*H + hh*16 + dl);
        Vs[hh][dl+0][key] = src[0];
        Vs[hh][dl+1][key] = src[1];
        Vs[hh][dl+2][key] = src[2];
        Vs[hh][dl+3][key] = src[3];
    }
    for (int idx = tid; idx < 2*16*(232-NK); idx += 256){
        int key = NK + idx % (232-NK), r = idx / (232-NK);
        Vs[r>>4][r&15][key] = 0;
    }
    __syncthreads();

    int w = tid >> 6, lane = tid & 63;
    int hh = w >> 1, half = w & 1;
    int h = h0 + hh;
    int l15 = lane & 15, quad = lane >> 4;
    bool klow = (quad < 2);
    int nqt = (nq + 15) >> 4;
    int split = (nqt + 1) >> 1;
    int qt0 = half ? split : 0;
    int qt1 = half ? nqt : split;
    for (int qt = qt0; qt < qt1; ++qt){
        int qr = qt*16 + l15; if (qr > nq-1) qr = nq-1;
        short8 av = *(const short8*)(Q + (size_t)b*qbs + (size_t)qr*H + h*16 + (quad & 1)*8);
        short8 zero8 = (short8)0;
        short8 afrag = klow ? av : zero8;
        float4v s[NKT];
        #pragma unroll
        for (int kt = 0; kt < NKT; ++kt){
            short8 bv = *(const short8*)(&Ks[hh][kt*16 + l15][(quad & 1)*8]);
            short8 bfrag = klow ? bv : zero8;
            s[kt] = __builtin_amdgcn_mfma_f32_16x16x32_bf16(afrag, bfrag, (float4v)0.f, 0, 0, 0);
        }
        float mx[4] = {-1e30f, -1e30f, -1e30f, -1e30f};
        #pragma unroll
        for (int kt = 0; kt < NKT; ++kt){
            if (kt*16 + l15 >= NK){ s[kt][0]=-1e30f; s[kt][1]=-1e30f; s[kt][2]=-1e30f; s[kt][3]=-1e30f; }
            #pragma unroll
            for (int r = 0; r < 4; ++r) mx[r] = fmaxf(mx[r], s[kt][r]);
        }
        #pragma unroll
        for (int off = 1; off < 16; off <<= 1){
            #pragma unroll
            for (int r = 0; r < 4; ++r) mx[r] = fmaxf(mx[r], __shfl_xor(mx[r], off));
        }
        float sum[4] = {0.f, 0.f, 0.f, 0.f};
        #pragma unroll
        for (int kt = 0; kt < NKT; ++kt){
            #pragma unroll
            for (int r = 0; r < 4; ++r){
                float e = __expf((s[kt][r] - mx[r]) * SCALE);
                sum[r] += e;
                Ps[w][quad*4 + r][kt*16 + l15] = f2bf(e);
            }
        }
        #pragma unroll
        for (int off = 1; off < 16; off <<= 1){
            #pragma unroll
            for (int r = 0; r < 4; ++r) sum[r] += __shfl_xor(sum[r], off);
        }
        float4v o = (float4v)0.f;
        #pragma unroll
        for (int kc = 0; kc < NKC; ++kc){
            short8 pa = *(const short8*)(&Ps[w][l15][kc*32 + quad*8]);
            short8 vb = *(const short8*)(&Vs[hh][l15][kc*32 + quad*8]);
            o = __builtin_amdgcn_mfma_f32_16x16x32_bf16(pa, vb, o, 0, 0, 0);
        }
        #pragma unroll
        for (int r = 0; r < 4; ++r){
            int row = qt*16 + quad*4 + r;
            if (row < nq){
                float qv = bf2f(Q[(size_t)b*qbs + (size_t)row*H + h*16 + l15]);
                out[((size_t)b*nq + row)*H + h*16 + l15] = f2bf(qv + o[r] / sum[r]);
            }
        }
    }
}

// ========== fused: gemm_fo_then<2> (SAB fo + PMA2 K,V) -> grid barrier -> GMPool_I + head ==========
__global__ __launch_bounds__(256, 4) void k_gft2_final(
    const ushort_t* __restrict__ x, int M,
    const ushort_t* __restrict__ Wfo, const float* __restrict__ bfo,
    const ushort_t* __restrict__ W2,
    const float* __restrict__ b20, const float* __restrict__ b21,
    ushort_t* __restrict__ o0, ushort_t* __restrict__ o1,
    const ushort_t* __restrict__ q2,
    const ushort_t* __restrict__ p2foW, const float* __restrict__ p2fob,
    const ushort_t* __restrict__ lin2W, const float* __restrict__ lin2b,
    const float* __restrict__ hergv,
    const float* __restrict__ hoW, const float* __restrict__ hob,
    const float* __restrict__ fcW, const float* __restrict__ fcb,
    const float* __restrict__ sWv, const float* __restrict__ sbv,
    float* __restrict__ outp, int* bar)
{
    __shared__ ushort_t As[64][136];
    const int tid = threadIdx.x, w = tid >> 6, lane = tid & 63;
    const int l15 = lane & 15, quad = lane >> 4;
    {
        // ---- phase 1: xb2 = x + relu(x@Wfo+bfo); K = xb2@W2[0], V = xb2@W2[1] ----
        const int row0 = blockIdx.x*64 + w*16;
        int ar = row0 + l15; if (ar > M-1) ar = M-1;
        const short* xr = (const short*)(x + (size_t)ar*H) + quad*8;
        {
            float4v acc[8];
            #pragma unroll
            for (int i = 0; i < 8; ++i) acc[i] = (float4v)0.f;
            #pragma unroll
            for (int kc = 0; kc < 4; ++kc){
                short8 a = *(const short8*)(xr + kc*32);
                #pragma unroll
                for (int nt = 0; nt < 8; ++nt){
                    short8 b = *(const short8*)((const short*)(Wfo + (size_t)(nt*16 + l15)*H) + kc*32 + quad*8);
                    acc[nt] = __builtin_amdgcn_mfma_f32_16x16x32_bf16(a, b, acc[nt], 0, 0, 0);
                }
            }
            #pragma unroll
            for (int nt = 0; nt < 8; ++nt){
                int c = nt*16 + l15;
                float bv = bfo[c];
                #pragma unroll
                for (int reg = 0; reg < 4; ++reg){
                    int r = row0 + quad*4 + reg;
                    float v = 0.f;
                    if (r < M) v = fmaxf(acc[nt][reg] + bv, 0.f) + bf2f(x[(size_t)r*H + c]);
                    As[w*16 + quad*4 + reg][c] = f2bf(v);
                }
            }
        }
        __syncthreads();
        #pragma unroll 1
        for (int n = 0; n < 2; ++n){
            float4v o[8];
            #pragma unroll
            for (int i = 0; i < 8; ++i) o[i] = (float4v)0.f;
            #pragma unroll
            for (int kc = 0; kc < 4; ++kc){
                short8 a = *(const short8*)(&As[w*16 + l15][kc*32 + quad*8]);
                #pragma unroll
                for (int nt = 0; nt < 8; ++nt){
                    short8 b = *(const short8*)((const short*)(W2 + (size_t)((n*8 + nt)*16 + l15)*H) + kc*32 + quad*8);
                    o[nt] = __builtin_amdgcn_mfma_f32_16x16x32_bf16(a, b, o[nt], 0, 0, 0);
                }
            }
            ushort_t* out = (n == 0) ? o0 : o1;
            const float* bb = (n == 0) ? b20 : b21;
            #pragma unroll
            for (int nt = 0; nt < 8; ++nt){
                int c = nt*16 + l15;
                float bv = bb[c];
                #pragma unroll
                for (int reg = 0; reg < 4; ++reg){
                    int r = row0 + quad*4 + reg;
                    if (r >= M) continue;
                    out[(size_t)r*H + c] = f2bf(o[nt][reg] + bv);
                }
            }
        }
    }
    gridbar(bar, gridDim.x);
    // ---- phase 2: per-graph GMPool_I (1 seed) + p2fo residual + lin2 + head MLP ----
    if (blockIdx.x < NB){
        int b = blockIdx.x, t = tid;
        char* sb8 = (char*)&As[0][0];
        float* sc       = (float*)sb8;              // 8*76 floats
        float* sumh     = (float*)(sb8 + 2432);     // 8
        ushort_t* xa    = (ushort_t*)(sb8 + 2464);  // 128
        ushort_t* xb3   = (ushort_t*)(sb8 + 2720);  // 128
        float* tt       = (float*)(sb8 + 2976);     // 128
        float* v256     = (float*)(sb8 + 3488);     // 256
        float* red      = (float*)(sb8 + 4512);     // 128
        const ushort_t* Kb = o0 + (size_t)b*NS*H;
        const ushort_t* Vb = o1 + (size_t)b*NS*H;
        {
            int h = t >> 5, l32 = t & 31;
            const ushort_t* qr = q2 + h*16;
            for (int k = l32; k < NS; k += 32){
                const ushort_t* kr = Kb + (size_t)k*H + h*16;
                float s = 0.f;
                #pragma unroll
                for (int d = 0; d < 16; ++d) s += bf2f(qr[d]) * bf2f(kr[d]);
                sc[h*76 + k] = s;
            }
        }
        __syncthreads();
        if (t < 128){
            int hh = t >> 4, i = t & 15;
            float mx = -1e30f;
            for (int k = i; k < NS; k += 16) mx = fmaxf(mx, sc[hh*76 + k]);
            #pragma unroll
            for (int off = 1; off < 16; off <<= 1) mx = fmaxf(mx, __shfl_xor(mx, off));
            float sm = 0.f;
            for (int k = i; k < NS; k += 16){
                float e = __expf((sc[hh*76 + k] - mx) * SCALE);
                sc[hh*76 + k] = e;
                sm += e;
            }
            #pragma unroll
            for (int off = 1; off < 16; off <<= 1) sm += __shfl_xor(sm, off);
            if (i == 0) sumh[hh] = sm;
        }
        __syncthreads();
        if (t < 128){
            int hh = t >> 4;
            float o = 0.f;
            for (int k = 0; k < NS; ++k) o += sc[hh*76 + k] * bf2f(Vb[(size_t)k*H + t]);
            xa[t] = f2bf(bf2f(q2[t]) + o / sumh[hh]);
        }
        __syncthreads();
        if (t < 128){
            float a = 0.f;
            const ushort_t* wr = p2foW + (size_t)t*H;
            for (int k = 0; k < H; ++k) a += bf2f(xa[k]) * bf2f(wr[k]);
            xb3[t] = f2bf(fmaxf(a + p2fob[t], 0.f) + bf2f(xa[t]));
        }
        __syncthreads();
        if (t < 128){
            float a = 0.f;
            const ushort_t* wr = lin2W + (size_t)t*H;
            for (int k = 0; k < H; ++k) a += bf2f(xb3[k]) * bf2f(wr[k]);
            v256[t] = a + lin2b[t];
            v256[128 + t] = hergv[t];
        }
        __syncthreads();
        if (t < 128){
            float acc = 0.f;
            const float* wr = hoW + (size_t)t*256;
            for (int k = 0; k < 256; ++k) acc += v256[k] * wr[k];
            tt[t] = fmaxf(acc + hob[t], 0.f);
        }
        __syncthreads();
        if (t < 128){
            float acc = 0.f;
            const float* wr = fcW + (size_t)t*128;
            for (int k = 0; k < 128; ++k) acc += tt[k] * wr[k];
            float uv = fmaxf(acc + fcb[t], 0.f);
            red[t] = uv * sWv[t];
        }
        __syncthreads();
        for (int s = 64; s > 0; s >>= 1){
            if (t < s) red[t] += red[t + s];
            __syncthreads();
        }
        if (t == 0){
            float logit = red[0] + sbv[0];
            outp[b] = 1.f / (1.f + expf(-logit));
        }
    }
}

extern "C" void kernel_launch(void* const* d_in, const int* in_sizes, int n_in,
                              void* d_out, int out_size, void* d_ws, size_t ws_size,
                              hipStream_t stream)
{
    (void)in_sizes; (void)n_in; (void)out_size; (void)ws_size;
    const float* herg_em = (const float*)d_in[0];
    const float* x_in    = (const float*)d_in[1];
    const float* convW[4] = {(const float*)d_in[4], (const float*)d_in[6], (const float*)d_in[8], (const float*)d_in[10]};
    const float* convB[4] = {(const float*)d_in[5], (const float*)d_in[7], (const float*)d_in[9], (const float*)d_in[11]};
    const float* lin1W = (const float*)d_in[12]; const float* lin1b = (const float*)d_in[13];
    const float* lin2W = (const float*)d_in[14]; const float* lin2b = (const float*)d_in[15];
    const float* S1    = (const float*)d_in[16];
    const float* p1fqW = (const float*)d_in[17]; const float* p1fqb = (const float*)d_in[18];
    const float* p1kW  = (const float*)d_in[19]; const float* p1kb  = (const float*)d_in[20];
    const float* p1vW  = (const float*)d_in[21]; const float* p1vb  = (const float*)d_in[22];
    const float* p1foW = (const float*)d_in[23]; const float* p1fob = (const float*)d_in[24];
    const float* sfqW  = (const float*)d_in[25]; const float* sfqb  = (const float*)d_in[26];
    const float* skW   = (const float*)d_in[27]; const float* skb   = (const float*)d_in[28];
    const float* svW   = (const float*)d_in[29]; const float* svb   = (const float*)d_in[30];
    const float* sfoW  = (const float*)d_in[31]; const float* sfob  = (const float*)d_in[32];
    const float* p2fqW = (const float*)d_in[33]; const float* p2fqb = (const float*)d_in[34];
    const float* p2kW  = (const float*)d_in[35]; const float* p2kb  = (const float*)d_in[36];
    const float* p2vW  = (const float*)d_in[37]; const float* p2vb  = (const float*)d_in[38];
    const float* p2foW = (const float*)d_in[39]; const float* p2fob = (const float*)d_in[40];
    const float* S2    = (const float*)d_in[41];
    const float* hlW   = (const float*)d_in[42]; const float* hlb   = (const float*)d_in[43];
    const float* hoW   = (const float*)d_in[44]; const float* hob   = (const float*)d_in[45];
    const float* fcW   = (const float*)d_in[46]; const float* fcb   = (const float*)d_in[47];
    const float* sW    = (const float*)d_in[48]; const float* sb    = (const float*)d_in[49];
    const int*  ei    = (const int*)d_in[50];
    const int*  esrc  = ei;
    const int*  edst  = ei + NE;
    float* outp = (float*)d_out;

    // -------- workspace layout (byte offsets, 16B-aligned) --------
    char* WS = (char*)d_ws;
    int*   counts = (int*)(WS + 0);
    int*   bar    = (int*)(WS + 400000);   // 4 ints: (cnt,gen) x2 — slack after counts
    int*   cursor = (int*)(WS + 400384);
    int*   row_st = (int*)(WS + 800768);
    int*   bSums  = (int*)(WS + 1201152);
    int*   bOff   = (int*)(WS + 1203200);
    float* dinv   = (float*)(WS + 1205248);
    float* selfc  = (float*)(WS + 1605632);
    int*   srcs_s = (int*)(WS + 2005632);
    float* ce_s   = (float*)(WS + 3605632);
    ushort_t* wbf = (ushort_t*)(WS + 5205632); // 17*16384
    ushort_t* w0bf= (ushort_t*)(WS + 5762688);
    ushort_t* s1bf= (ushort_t*)(WS + 5779072);
    ushort_t* s2bf= (ushort_t*)(WS + 5798272);
    ushort_t* q0  = (ushort_t*)(WS + 5798528);
    ushort_t* q2  = (ushort_t*)(WS + 5817728);
    float* hergv  = (float*)(WS + 5817984);
    ushort_t* xb64= (ushort_t*)(WS + 6074496); // NN*64 bf16 padded raw x
    ushort_t* b0  = (ushort_t*)(WS + 18874496);// NN*128
    ushort_t* b1  = (ushort_t*)(WS + 44474496);
    ushort_t* b2  = (ushort_t*)(WS + 70074496);
    ushort_t* xA  = (ushort_t*)(WS + 95674496);   // 37504*128
    ushort_t* xB  = (ushort_t*)(WS + 105275520);
    ushort_t* xQ  = (ushort_t*)(WS + 114876544);
    ushort_t* xK  = (ushort_t*)(WS + 124477568);
    ushort_t* xV  = (ushort_t*)(WS + 134078592);

    const int gC   = (NN + 31)/32;         // 3125
    const int gXb  = (NB*NS + 63)/64;      // 586

    // ---- barrier state ----
    hipMemsetAsync(bar, 0, 16, stream);

    // ---- fused preprocessing: CSR + conversions + seedQ + hERG (1 launch) ----
    PreArgs pa;
    pa.counts = counts; pa.cursor = cursor; pa.row_st = row_st; pa.bSums = bSums; pa.bOff = bOff;
    pa.dinv = dinv; pa.selfc = selfc; pa.srcs_s = srcs_s; pa.ce_s = ce_s;
    pa.esrc = esrc; pa.edst = edst;
    pa.w[0]=convW[1]; pa.w[1]=convW[2]; pa.w[2]=convW[3]; pa.w[3]=lin1W; pa.w[4]=lin2W;
    pa.w[5]=p1kW; pa.w[6]=p1vW; pa.w[7]=p1foW;
    pa.w[8]=sfqW; pa.w[9]=skW; pa.w[10]=svW; pa.w[11]=sfoW;
    pa.w[12]=p2kW; pa.w[13]=p2vW; pa.w[14]=p2foW; pa.w[15]=p1fqW; pa.w[16]=p2fqW;
    pa.w0 = convW[0]; pa.s1 = S1; pa.s2 = S2; pa.x37 = x_in;
    pa.wbf = wbf; pa.w0bf = w0bf; pa.s1bf = s1bf; pa.s2bf = s2bf; pa.xb64 = xb64;
    pa.p1fqb = p1fqb; pa.p2fqb = p2fqb; pa.q0 = q0; pa.q2 = q2;
    pa.hem = herg_em; pa.hlW = hlW; pa.hlb = hlb; pa.hergv = hergv;
    pa.bar = bar;
    k_pre<<<512, 256, 0, stream>>>(pa);

    // ---- conv0 (fused gather64 + GEMM) -> b0 ----
    k_conv0b<<<gC, 256, 0, stream>>>(xb64, row_st, srcs_s, ce_s, selfc, w0bf, convB[0], b0);
    // ---- conv1, conv2 ----
    k_conv_fused3<8,1,0,8><<<gC, 256, 0, stream>>>(b0, row_st, srcs_s, ce_s, selfc,
        wbf + (size_t)0*16384, convB[1], nullptr, nullptr, nullptr, b1, nullptr);
    k_conv_fused3<8,1,0,8><<<gC, 256, 0, stream>>>(b1, row_st, srcs_s, ce_s, selfc,
        wbf + (size_t)1*16384, convB[2], nullptr, nullptr, nullptr, b0, nullptr);
    // ---- conv3 + lin1 fused -> hx in b1 ----
    k_conv_fused3<8,1,1,8><<<gC, 256, 0, stream>>>(b0, row_st, srcs_s, ce_s, selfc,
        wbf + (size_t)2*16384, convB[3], nullptr, wbf + (size_t)3*16384, lin1b, b1, nullptr);
    // ---- pma1 K,V: fused shared-gather + dual GEMM, HEAD-MAJOR out (K->b2, V->b0) ----
    k_conv_fused3<16,0,0,4><<<gC, 256, 0, stream>>>(b1, row_st, srcs_s, ce_s, selfc,
        wbf + (size_t)5*16384, p1kb, p1vb, nullptr, nullptr, b2, b0);
    // ---- GMPool_G attention (head-major K/V) -> xA ----
    k_attn_mfma<200,1><<<NB*4, 256, 0, stream>>>(q0, 0, b2, b0, xA, NS);
    // ---- fused: xb1 = xA + relu(xA@p1fo+b); then SAB Q,K,V ----
    gemm_fo_then<3><<<gXb, 256, 0, stream>>>(xA, NB*NS, wbf + (size_t)7*16384, p1fob,
        wbf + (size_t)8*16384, sfqb, skb, svb, xQ, xK, xV, nullptr);
    // ---- SAB attention -> xB ----
    k_attn_mfma<75,0><<<NB*4, 256, 0, stream>>>(xQ, NS*H, xK, xV, xB, NS);
    // ---- fused: xb2 -> PMA2 K,V -> grid barrier -> GMPool_I + head MLP -> out ----
    k_gft2_final<<<gXb, 256, 0, stream>>>(xB, NB*NS, wbf + (size_t)11*16384, sfob,
        wbf + (size_t)12*16384, p2kb, p2vb, xK, xV,
        q2, wbf + (size_t)14*16384, p2fob, wbf + (size_t)4*16384, lin2b,
        hergv, hoW, hob, fcW, fcb, sW, sb, outp, bar + 2);
}

// Round 8
// 771.897 us; speedup vs baseline: 2.0716x; 2.0716x over previous
//
#include <hip/hip_runtime.h>
#include <hip/hip_bf16.h>

typedef unsigned short ushort_t;
typedef unsigned int uint_t;
typedef __attribute__((ext_vector_type(8))) short short8;
typedef __attribute__((ext_vector_type(4))) float float4v;

static constexpr int NN  = 100000;   // nodes
static constexpr int NE  = 400000;   // edges
static constexpr int NB  = 500;      // graphs
static constexpr int NS  = 75;       // seeds
static constexpr int H   = 128;
static constexpr float SCALE = 0.08838834764831845f; // 1/sqrt(128)

union U32 { uint_t u; float f; };
__device__ __forceinline__ float bf2f(ushort_t b){ U32 t; t.u = ((uint_t)b) << 16; return t.f; }
__device__ __forceinline__ ushort_t f2bf(float f){
    U32 t; t.f = f;
    uint_t r = t.u + 0x7fffu + ((t.u >> 16) & 1u);   // RNE
    return (ushort_t)(r >> 16);
}
__device__ __forceinline__ void fma8(float* a, uint4 u, float c){
    a[0] += c * bf2f((ushort_t)(u.x & 0xffff)); a[1] += c * bf2f((ushort_t)(u.x >> 16));
    a[2] += c * bf2f((ushort_t)(u.y & 0xffff)); a[3] += c * bf2f((ushort_t)(u.y >> 16));
    a[4] += c * bf2f((ushort_t)(u.z & 0xffff)); a[5] += c * bf2f((ushort_t)(u.z >> 16));
    a[6] += c * bf2f((ushort_t)(u.w & 0xffff)); a[7] += c * bf2f((ushort_t)(u.w >> 16));
}

// ================= CSR build =================
__global__ void k_hist(int* counts, const int* __restrict__ dst, int e){
    int i = blockIdx.x*256 + threadIdx.x;
    if (i < e) atomicAdd(&counts[dst[i]], 1);
}
// scan + degree norms fused
__global__ __launch_bounds__(256) void k_scan1(const int* __restrict__ counts,
    int* __restrict__ row_start, int* __restrict__ blockSums,
    float* __restrict__ dinv, float* __restrict__ selfc, int n){
    __shared__ int s[256];
    int t = threadIdx.x, i = blockIdx.x*256 + t;
    int v = (i < n) ? counts[i] : 0;
    s[t] = v; __syncthreads();
    #pragma unroll
    for (int off = 1; off < 256; off <<= 1){
        int add = (t >= off) ? s[t-off] : 0;
        __syncthreads();
        s[t] += add;
        __syncthreads();
    }
    if (i < n){
        row_start[i] = s[t] - v;
        float r = rsqrtf(1.f + (float)v);
        dinv[i] = r; selfc[i] = r*r;
    }
    if (t == 255) blockSums[blockIdx.x] = s[255];
}
__global__ __launch_bounds__(512) void k_scan2(const int* __restrict__ blockSums,
    int* __restrict__ blockOff, int nb){
    __shared__ int s[512];
    int t = threadIdx.x;
    int v = (t < nb) ? blockSums[t] : 0;
    s[t] = v; __syncthreads();
    #pragma unroll
    for (int off = 1; off < 512; off <<= 1){
        int add = (t >= off) ? s[t-off] : 0;
        __syncthreads();
        s[t] += add;
        __syncthreads();
    }
    blockOff[t] = s[t] - v;
}
__global__ void k_scan3(int* __restrict__ row_start, int* __restrict__ cursor,
                        const int* __restrict__ blockOff, int n, int total){
    int i = blockIdx.x*256 + threadIdx.x;
    if (i < n){
        int v = row_start[i] + blockOff[i >> 8];
        row_start[i] = v; cursor[i] = v;
    }
    if (i == 0) row_start[n] = total;
}
__global__ void k_fillcsr(const int* __restrict__ src, const int* __restrict__ dst,
    const float* __restrict__ dinv, int* cursor,
    int* __restrict__ srcs_s, float* __restrict__ ce_s, int e){
    int i = blockIdx.x*256 + threadIdx.x;
    if (i < e){
        int d = dst[i], s = src[i];
        int p = atomicAdd(&cursor[d], 1);
        srcs_s[p] = s;
        ce_s[p] = dinv[s] * dinv[d];
    }
}

// ================= merged conversions (+ counts zeroing) =================
struct CvtArgs { const float* w[17]; const float* w0; const float* s1; const float* s2; const float* x37; };
static constexpr int CVT_W   = 17*16384;
static constexpr int CVT_W0  = 8192;
static constexpr int CVT_S1  = 9600;
static constexpr int CVT_S2  = 128;
static constexpr int CVT_X   = NN*64;
__global__ void k_cvt_all(CvtArgs a, ushort_t* __restrict__ wbf, ushort_t* __restrict__ w0bf,
                          ushort_t* __restrict__ s1bf, ushort_t* __restrict__ s2bf,
                          ushort_t* __restrict__ xb64, int* __restrict__ counts){
    int i = blockIdx.x*256 + threadIdx.x;
    if (i < NN) counts[i] = 0;                       // folded k_zero_i
    if (i < CVT_W){ int idx = i >> 14, off = i & 16383; wbf[i] = f2bf(a.w[idx][off]); return; }
    i -= CVT_W;
    if (i < CVT_W0){ int r = i >> 6, c = i & 63; w0bf[i] = (c < 37) ? f2bf(a.w0[r*37 + c]) : (ushort_t)0; return; }
    i -= CVT_W0;
    if (i < CVT_S1){ s1bf[i] = f2bf(a.s1[i]); return; }
    i -= CVT_S1;
    if (i < CVT_S2){ s2bf[i] = f2bf(a.s2[i]); return; }
    i -= CVT_S2;
    if (i < CVT_X){ int r = i >> 6, c = i & 63; xb64[i] = (c < 37) ? f2bf(a.x37[(size_t)r*37 + c]) : (ushort_t)0; return; }
}

// ========== seed-Q projections + hERG fused ==========
// blocks 0-1: S1@p1fq (75 rows); block 2: S2@p2fq (1 row); block 3: hERG MLP (fp32)
__global__ __launch_bounds__(256) void k_seedq(
    const ushort_t* __restrict__ s1bf, const ushort_t* __restrict__ s2bf,
    const ushort_t* __restrict__ W1, const float* __restrict__ bias1,
    const ushort_t* __restrict__ W2q, const float* __restrict__ bias2,
    ushort_t* __restrict__ q0, ushort_t* __restrict__ q2,
    const float* __restrict__ hem, const float* __restrict__ hlW,
    const float* __restrict__ hlb, float* __restrict__ hergv)
{
    int blk = blockIdx.x;
    int tid  = threadIdx.x;
    if (blk == 3){
        __shared__ float e[1280];
        for (int i = tid; i < 1280; i += 256) e[i] = hem[i];
        __syncthreads();
        if (tid < 128){
            float acc = 0.f;
            for (int k = 0; k < 1280; ++k) acc += e[k] * hlW[(size_t)tid*1280 + k];
            hergv[tid] = fmaxf(acc + hlb[tid], 0.f);
        }
        return;
    }
    const ushort_t* x = (blk < 2) ? s1bf : s2bf;
    const ushort_t* W = (blk < 2) ? W1 : W2q;
    const float* bias = (blk < 2) ? bias1 : bias2;
    ushort_t* out = (blk < 2) ? q0 : q2;
    int M = (blk < 2) ? NS : 1;
    int base = (blk < 2) ? blk*64 : 0;
    int wid  = tid >> 6;
    int lane = tid & 63;
    int l15  = lane & 15, quad = lane >> 4;
    int row0 = base + wid*16;
    int ar   = row0 + l15; if (ar > M-1) ar = M-1;
    const short* xr = (const short*)(x + (size_t)ar*H) + quad*8;
    float4v acc[8];
    #pragma unroll
    for (int i = 0; i < 8; ++i) acc[i] = (float4v)0.f;
    #pragma unroll
    for (int kc = 0; kc < 4; ++kc){
        short8 a = *(const short8*)(xr + kc*32);
        #pragma unroll
        for (int nt = 0; nt < 8; ++nt){
            short8 b = *(const short8*)((const short*)(W + (size_t)(nt*16 + l15)*H) + kc*32 + quad*8);
            acc[nt] = __builtin_amdgcn_mfma_f32_16x16x32_bf16(a, b, acc[nt], 0, 0, 0);
        }
    }
    #pragma unroll
    for (int nt = 0; nt < 8; ++nt){
        int c = nt*16 + l15;
        float bv = bias[c];
        #pragma unroll
        for (int reg = 0; reg < 4; ++reg){
            int r = row0 + quad*4 + reg;
            if (r >= M) continue;
            out[(size_t)r*H + c] = f2bf(acc[nt][reg] + bv);
        }
    }
}

// ========== two-stage GEMM: y = x + relu(x@Wfo+bfo); then N outputs SEQUENTIALLY ==========
template<int NOUT2>
__global__ __launch_bounds__(256, 4) void gemm_fo_then(
    const ushort_t* __restrict__ x, int M,
    const ushort_t* __restrict__ Wfo, const float* __restrict__ bfo,
    const ushort_t* __restrict__ W2,            // [NOUT2*128][128]
    const float* __restrict__ b20, const float* __restrict__ b21, const float* __restrict__ b22,
    ushort_t* __restrict__ o0, ushort_t* __restrict__ o1, ushort_t* __restrict__ o2,
    float* __restrict__ o32)
{
    __shared__ ushort_t As[64][136];
    const int tid = threadIdx.x, w = tid >> 6, lane = tid & 63;
    const int l15 = lane & 15, quad = lane >> 4;
    const int row0 = blockIdx.x*64 + w*16;
    int ar = row0 + l15; if (ar > M-1) ar = M-1;
    const short* xr = (const short*)(x + (size_t)ar*H) + quad*8;
    {
        float4v acc[8];
        #pragma unroll
        for (int i = 0; i < 8; ++i) acc[i] = (float4v)0.f;
        #pragma unroll
        for (int kc = 0; kc < 4; ++kc){
            short8 a = *(const short8*)(xr + kc*32);
            #pragma unroll
            for (int nt = 0; nt < 8; ++nt){
                short8 b = *(const short8*)((const short*)(Wfo + (size_t)(nt*16 + l15)*H) + kc*32 + quad*8);
                acc[nt] = __builtin_amdgcn_mfma_f32_16x16x32_bf16(a, b, acc[nt], 0, 0, 0);
            }
        }
        #pragma unroll
        for (int nt = 0; nt < 8; ++nt){
            int c = nt*16 + l15;
            float bv = bfo[c];
            #pragma unroll
            for (int reg = 0; reg < 4; ++reg){
                int r = row0 + quad*4 + reg;
                float v = 0.f;
                if (r < M) v = fmaxf(acc[nt][reg] + bv, 0.f) + bf2f(x[(size_t)r*H + c]);
                As[w*16 + quad*4 + reg][c] = f2bf(v);
            }
        }
    }
    __syncthreads();
    #pragma unroll 1
    for (int n = 0; n < NOUT2; ++n){
        float4v o[8];
        #pragma unroll
        for (int i = 0; i < 8; ++i) o[i] = (float4v)0.f;
        #pragma unroll
        for (int kc = 0; kc < 4; ++kc){
            short8 a = *(const short8*)(&As[w*16 + l15][kc*32 + quad*8]);
            #pragma unroll
            for (int nt = 0; nt < 8; ++nt){
                short8 b = *(const short8*)((const short*)(W2 + (size_t)((n*8 + nt)*16 + l15)*H) + kc*32 + quad*8);
                o[nt] = __builtin_amdgcn_mfma_f32_16x16x32_bf16(a, b, o[nt], 0, 0, 0);
            }
        }
        ushort_t* out = (n == 0) ? o0 : ((n == 1) ? o1 : o2);
        const float* bb = (n == 0) ? b20 : ((n == 1) ? b21 : b22);
        #pragma unroll
        for (int nt = 0; nt < 8; ++nt){
            int c = nt*16 + l15;
            float bv = bb[c];
            #pragma unroll
            for (int reg = 0; reg < 4; ++reg){
                int r = row0 + quad*4 + reg;
                if (r >= M) continue;
                float v = o[nt][reg] + bv;
                if (o32 && n == 0) o32[(size_t)r*H + c] = v;
                else               out[(size_t)r*H + c] = f2bf(v);
            }
        }
    }
}

// ========== fused gather + MFMA GEMM v3 (2-edge unroll + index prefetch) ==========
// NOUT==16 writes K/V head-major: record = 32 elems (64B) per (head-pair, node)
template<int NOUT, int RELU, int STAGE2, int MINW>
__global__ __launch_bounds__(256, MINW) void k_conv_fused3(
    const ushort_t* __restrict__ x,
    const int* __restrict__ row_st, const int* __restrict__ srcs,
    const float* __restrict__ ces, const float* __restrict__ selfc,
    const ushort_t* __restrict__ W, const float* __restrict__ bias0,
    const float* __restrict__ bias1,
    const ushort_t* __restrict__ W2, const float* __restrict__ bias2,
    ushort_t* __restrict__ out0, ushort_t* __restrict__ out1)
{
    __shared__ ushort_t As[32][136];
    __shared__ ushort_t Bs[(NOUT==16)?32:1][(NOUT==16)?136:1];
    const int tid = threadIdx.x;
    const int node = tid >> 3, qq = tid & 7;   // 8 threads/node, 16 cols each
    const int g = blockIdx.x*32 + node;
    float acc[16];
    #pragma unroll
    for (int i = 0; i < 16; ++i) acc[i] = 0.f;
    if (g < NN){
        const uint4* xr = (const uint4*)(x + (size_t)g*H + qq*16);
        float sc = selfc[g];
        uint4 u0 = xr[0], u1 = xr[1];
        fma8(acc+0, u0, sc); fma8(acc+8, u1, sc);
        int e = row_st[g], e1 = row_st[g+1];
        int sA = 0, sB = 0; float cA = 0.f, cB = 0.f;
        if (e < e1){ sA = srcs[e]; cA = ces[e]; }
        if (e + 1 < e1){ sB = srcs[e+1]; cB = ces[e+1]; }
        while (e + 2 <= e1){
            // prefetch next pair's indices (overlaps with data-load latency)
            int sA2 = 0, sB2 = 0; float cA2 = 0.f, cB2 = 0.f;
            if (e + 2 < e1){ sA2 = srcs[e+2]; cA2 = ces[e+2]; }
            if (e + 3 < e1){ sB2 = srcs[e+3]; cB2 = ces[e+3]; }
            const uint4* pa = (const uint4*)(x + (size_t)sA*H + qq*16);
            const uint4* pb = (const uint4*)(x + (size_t)sB*H + qq*16);
            uint4 a0 = pa[0], a1 = pa[1];
            uint4 c0 = pb[0], c1 = pb[1];
            fma8(acc+0, a0, cA); fma8(acc+8, a1, cA);
            fma8(acc+0, c0, cB); fma8(acc+8, c1, cB);
            sA = sA2; sB = sB2; cA = cA2; cB = cB2;
            e += 2;
        }
        if (e < e1){
            const uint4* pa = (const uint4*)(x + (size_t)sA*H + qq*16);
            uint4 a0 = pa[0], a1 = pa[1];
            fma8(acc+0, a0, cA); fma8(acc+8, a1, cA);
        }
    }
    {
        uint_t* dst = (uint_t*)&As[node][qq*16];
        #pragma unroll
        for (int i = 0; i < 8; ++i)
            dst[i] = (uint_t)f2bf(acc[2*i]) | ((uint_t)f2bf(acc[2*i+1]) << 16);
    }
    __syncthreads();
    const int w = tid >> 6, lane = tid & 63, l15 = lane & 15, quad = lane >> 4;
    const int rt = w & 1;                  // row tile (16 rows)
    constexpr int NT = NOUT/2;             // col tiles per wave
    const int ct0 = (w >> 1) * NT;
    float4v o[NT];
    #pragma unroll
    for (int t = 0; t < NT; ++t) o[t] = (float4v)0.f;
    #pragma unroll
    for (int kc = 0; kc < 4; ++kc){
        short8 a = *(const short8*)(&As[rt*16 + l15][kc*32 + quad*8]);
        #pragma unroll
        for (int t = 0; t < NT; ++t){
            short8 bfr = *(const short8*)(W + (size_t)((ct0 + t)*16 + l15)*H + kc*32 + quad*8);
            o[t] = __builtin_amdgcn_mfma_f32_16x16x32_bf16(a, bfr, o[t], 0, 0, 0);
        }
    }
    __syncthreads();
    #pragma unroll
    for (int t = 0; t < NT; ++t){
        int cg = (ct0 + t)*16 + l15;
        #pragma unroll
        for (int r = 0; r < 4; ++r){
            float v;
            if (NOUT == 8 || cg < 128){
                v = o[t][r] + bias0[cg];
                if (RELU) v = fmaxf(v, 0.f);
                As[rt*16 + quad*4 + r][cg] = f2bf(v);
            } else {
                v = o[t][r] + bias1[cg - 128];
                if (RELU) v = fmaxf(v, 0.f);
                Bs[rt*16 + quad*4 + r][cg - 128] = f2bf(v);
            }
        }
    }
    __syncthreads();
    if (STAGE2){
        float4v o2[4];
        #pragma unroll
        for (int t = 0; t < 4; ++t) o2[t] = (float4v)0.f;
        const int ct2 = (w >> 1) * 4;
        #pragma unroll
        for (int kc = 0; kc < 4; ++kc){
            short8 a = *(const short8*)(&As[rt*16 + l15][kc*32 + quad*8]);
            #pragma unroll
            for (int t = 0; t < 4; ++t){
                short8 bfr = *(const short8*)(W2 + (size_t)((ct2 + t)*16 + l15)*H + kc*32 + quad*8);
                o2[t] = __builtin_amdgcn_mfma_f32_16x16x32_bf16(a, bfr, o2[t], 0, 0, 0);
            }
        }
        __syncthreads();
        #pragma unroll
        for (int t = 0; t < 4; ++t){
            int cg = (ct2 + t)*16 + l15;
            #pragma unroll
            for (int r = 0; r < 4; ++r)
                As[rt*16 + quad*4 + r][cg] = f2bf(o2[t][r] + bias2[cg]);
        }
        __syncthreads();
    }
    if (g < NN){
        if (NOUT == 16){
            // head-major K/V for attention: dest = [(hp)*NN + node]*32 + (qq&1)*16 elems
            size_t kb = ((size_t)(qq >> 1)*NN + (size_t)g)*32 + (size_t)(qq & 1)*16;
            ((uint4*)(out0 + kb))[0] = *(const uint4*)&As[node][qq*16];
            ((uint4*)(out0 + kb))[1] = *(const uint4*)&As[node][qq*16 + 8];
            ((uint4*)(out1 + kb))[0] = *(const uint4*)&Bs[node][qq*16];
            ((uint4*)(out1 + kb))[1] = *(const uint4*)&Bs[node][qq*16 + 8];
        } else {
            uint4* op = (uint4*)(out0 + (size_t)g*H + qq*16);
            const uint4* sp = (const uint4*)&As[node][qq*16];
            op[0] = sp[0]; op[1] = sp[1];
        }
    }
}

// ========== conv0: gather padded-64 bf16 rows + MFMA GEMM (K=64) ==========
__global__ __launch_bounds__(256, 8) void k_conv0b(
    const ushort_t* __restrict__ x,   // [NN][64] bf16
    const int* __restrict__ row_st, const int* __restrict__ srcs,
    const float* __restrict__ ces, const float* __restrict__ selfc,
    const ushort_t* __restrict__ W,   // [128][64]
    const float* __restrict__ bias,
    ushort_t* __restrict__ out)
{
    __shared__ ushort_t As[32][136];
    const int tid = threadIdx.x;
    const int node = tid >> 3, qq = tid & 7;   // 8 cols (1 uint4) each
    const int g = blockIdx.x*32 + node;
    float acc[8];
    #pragma unroll
    for (int i = 0; i < 8; ++i) acc[i] = 0.f;
    if (g < NN){
        const uint4* xr = (const uint4*)(x + (size_t)g*64 + qq*8);
        float sc = selfc[g];
        fma8(acc, xr[0], sc);
        int e = row_st[g], e1 = row_st[g+1];
        int sA = 0, sB = 0; float cA = 0.f, cB = 0.f;
        if (e < e1){ sA = srcs[e]; cA = ces[e]; }
        if (e + 1 < e1){ sB = srcs[e+1]; cB = ces[e+1]; }
        while (e + 2 <= e1){
            int sA2 = 0, sB2 = 0; float cA2 = 0.f, cB2 = 0.f;
            if (e + 2 < e1){ sA2 = srcs[e+2]; cA2 = ces[e+2]; }
            if (e + 3 < e1){ sB2 = srcs[e+3]; cB2 = ces[e+3]; }
            uint4 a0 = *(const uint4*)(x + (size_t)sA*64 + qq*8);
            uint4 c0 = *(const uint4*)(x + (size_t)sB*64 + qq*8);
            fma8(acc, a0, cA);
            fma8(acc, c0, cB);
            sA = sA2; sB = sB2; cA = cA2; cB = cB2;
            e += 2;
        }
        if (e < e1){
            uint4 a0 = *(const uint4*)(x + (size_t)sA*64 + qq*8);
            fma8(acc, a0, cA);
        }
    }
    {
        uint_t* dst = (uint_t*)&As[node][qq*8];
        #pragma unroll
        for (int i = 0; i < 4; ++i)
            dst[i] = (uint_t)f2bf(acc[2*i]) | ((uint_t)f2bf(acc[2*i+1]) << 16);
    }
    __syncthreads();
    const int w = tid >> 6, lane = tid & 63, l15 = lane & 15, quad = lane >> 4;
    const int rt = w & 1;
    const int ct0 = (w >> 1) * 4;
    float4v o[4];
    #pragma unroll
    for (int t = 0; t < 4; ++t) o[t] = (float4v)0.f;
    #pragma unroll
    for (int kc = 0; kc < 2; ++kc){
        short8 a = *(const short8*)(&As[rt*16 + l15][kc*32 + quad*8]);
        #pragma unroll
        for (int t = 0; t < 4; ++t){
            short8 bfr = *(const short8*)(W + (size_t)((ct0 + t)*16 + l15)*64 + kc*32 + quad*8);
            o[t] = __builtin_amdgcn_mfma_f32_16x16x32_bf16(a, bfr, o[t], 0, 0, 0);
        }
    }
    __syncthreads();
    #pragma unroll
    for (int t = 0; t < 4; ++t){
        int cg = (ct0 + t)*16 + l15;
        #pragma unroll
        for (int r = 0; r < 4; ++r)
            As[rt*16 + quad*4 + r][cg] = f2bf(fmaxf(o[t][r] + bias[cg], 0.f));
    }
    __syncthreads();
    if (g < NN){
        uint4* op = (uint4*)(out + (size_t)g*H + qq*16);
        const uint4* sp = (const uint4*)&As[node][qq*16];
        op[0] = sp[0]; op[1] = sp[1];
    }
}

// ========== MFMA flash attention ==========
// HM=1: K,V are head-major [(hp)*NN + b*NK + key]*32 elems (64B records, 2 heads x 16)
template<int NK, int HM>
__global__ __launch_bounds__(256) void k_attn_mfma(
    const ushort_t* __restrict__ Q, int qbs,
    const ushort_t* __restrict__ K, const ushort_t* __restrict__ V,
    ushort_t* __restrict__ out, int nq)
{
    constexpr int NKT = (NK + 15) / 16;
    constexpr int NKC = (NK + 31) / 32;
    __shared__ ushort_t Ks[2][208][24];
    __shared__ ushort_t Vs[2][16][232];
    __shared__ ushort_t Ps[4][16][232];
    int b = blockIdx.x >> 2, hp = blockIdx.x & 3;
    int h0 = hp*2;
    int tid = threadIdx.x;
    {
        uint_t* p = (uint_t*)&Ps[0][0][0];
        for (int i = tid; i < 4*16*232/2; i += 256) p[i] = 0;
    }
    const ushort_t* Kb = HM ? (K + ((size_t)hp*NB + b)*NK*32)
                            : (K + (size_t)b*NK*H + h0*16);
    for (int idx = tid; idx < NK*8; idx += 256){
        int key = idx >> 3, p = idx & 7;
        int hh = p >> 2, dl = (p & 3)*4;
        const uint_t* src = HM ? (const uint_t*)(Kb + (size_t)key*32 + hh*16 + dl)
                               : (const uint_t*)(Kb + (size_t)key*H + hh*16 + dl);
        uint_t* d = (uint_t*)&Ks[hh][key][dl];
        d[0] = src[0]; d[1] = src[1];
    }
    const ushort_t* Vb = HM ? (V + ((size_t)hp*NB + b)*NK*32)
                            : (V + (size_t)b*NK*H + h0*16);
    for (int idx = tid; idx < NK*8; idx += 256){
        int key = idx >> 3, p = idx & 7;
        int hh = p >> 2, dl = (p & 3)*4;
        const ushort_t* src = HM ? (Vb + (size_t)key*32 + hh*16 + dl)
                                 : (Vb + (size_t)key*H + hh*16 + dl);
        Vs[hh][dl+0][key] = src[0];
        Vs[hh][dl+1][key] = src[1];
        Vs[hh][dl+2][key] = src[2];
        Vs[hh][dl+3][key] = src[3];
    }
    for (int idx = tid; idx < 2*16*(232-NK); idx += 256){
        int key = NK + idx % (232-NK), r = idx / (232-NK);
        Vs[r>>4][r&15][key] = 0;
    }
    __syncthreads();

    int w = tid >> 6, lane = tid & 63;
    int hh = w >> 1, half = w & 1;
    int h = h0 + hh;
    int l15 = lane & 15, quad = lane >> 4;
    bool klow = (quad < 2);
    int nqt = (nq + 15) >> 4;
    int split = (nqt + 1) >> 1;
    int qt0 = half ? split : 0;
    int qt1 = half ? nqt : split;
    for (int qt = qt0; qt < qt1; ++qt){
        int qr = qt*16 + l15; if (qr > nq-1) qr = nq-1;
        short8 av = *(const short8*)(Q + (size_t)b*qbs + (size_t)qr*H + h*16 + (quad & 1)*8);
        short8 zero8 = (short8)0;
        short8 afrag = klow ? av : zero8;
        float4v s[NKT];
        #pragma unroll
        for (int kt = 0; kt < NKT; ++kt){
            short8 bv = *(const short8*)(&Ks[hh][kt*16 + l15][(quad & 1)*8]);
            short8 bfrag = klow ? bv : zero8;
            s[kt] = __builtin_amdgcn_mfma_f32_16x16x32_bf16(afrag, bfrag, (float4v)0.f, 0, 0, 0);
        }
        float mx[4] = {-1e30f, -1e30f, -1e30f, -1e30f};
        #pragma unroll
        for (int kt = 0; kt < NKT; ++kt){
            if (kt*16 + l15 >= NK){ s[kt][0]=-1e30f; s[kt][1]=-1e30f; s[kt][2]=-1e30f; s[kt][3]=-1e30f; }
            #pragma unroll
            for (int r = 0; r < 4; ++r) mx[r] = fmaxf(mx[r], s[kt][r]);
        }
        #pragma unroll
        for (int off = 1; off < 16; off <<= 1){
            #pragma unroll
            for (int r = 0; r < 4; ++r) mx[r] = fmaxf(mx[r], __shfl_xor(mx[r], off));
        }
        float sum[4] = {0.f, 0.f, 0.f, 0.f};
        #pragma unroll
        for (int kt = 0; kt < NKT; ++kt){
            #pragma unroll
            for (int r = 0; r < 4; ++r){
                float e = __expf((s[kt][r] - mx[r]) * SCALE);
                sum[r] += e;
                Ps[w][quad*4 + r][kt*16 + l15] = f2bf(e);
            }
        }
        #pragma unroll
        for (int off = 1; off < 16; off <<= 1){
            #pragma unroll
            for (int r = 0; r < 4; ++r) sum[r] += __shfl_xor(sum[r], off);
        }
        float4v o = (float4v)0.f;
        #pragma unroll
        for (int kc = 0; kc < NKC; ++kc){
            short8 pa = *(const short8*)(&Ps[w][l15][kc*32 + quad*8]);
            short8 vb = *(const short8*)(&Vs[hh][l15][kc*32 + quad*8]);
            o = __builtin_amdgcn_mfma_f32_16x16x32_bf16(pa, vb, o, 0, 0, 0);
        }
        #pragma unroll
        for (int r = 0; r < 4; ++r){
            int row = qt*16 + quad*4 + r;
            if (row < nq){
                float qv = bf2f(Q[(size_t)b*qbs + (size_t)row*H + h*16 + l15]);
                out[((size_t)b*nq + row)*H + h*16 + l15] = f2bf(qv + o[r] / sum[r]);
            }
        }
    }
}

// ========== fused tail: GMPool_I (1-seed attention) + p2fo residual + lin2 + head MLP ==========
// one block per graph, 256 threads
__global__ __launch_bounds__(256) void k_pma2_final(
    const ushort_t* __restrict__ q2,      // [128] bf16 (shared by all graphs)
    const ushort_t* __restrict__ K,       // [NB][75][128] bf16
    const ushort_t* __restrict__ V,       // [NB][75][128] bf16
    const ushort_t* __restrict__ p2foW,   // [128][128] bf16
    const float* __restrict__ p2fob,
    const ushort_t* __restrict__ lin2W,   // [128][128] bf16
    const float* __restrict__ lin2b,
    const float* __restrict__ hergv,      // [128] fp32
    const float* __restrict__ hoW, const float* __restrict__ hob,
    const float* __restrict__ fcW, const float* __restrict__ fcb,
    const float* __restrict__ sW,  const float* __restrict__ sb,
    float* __restrict__ outp)
{
    int b = blockIdx.x, t = threadIdx.x;
    __shared__ float sc[8][76];
    __shared__ float sumh[8];
    __shared__ ushort_t xa[128];
    __shared__ ushort_t xb3[128];
    __shared__ float tt[128];
    __shared__ float v256[256];
    __shared__ float red[128];

    const ushort_t* Kb = K + (size_t)b*NS*H;
    const ushort_t* Vb = V + (size_t)b*NS*H;

    // scores: head h = t>>5, keys strided by 32 lanes
    {
        int h = t >> 5, l32 = t & 31;
        const ushort_t* qr = q2 + h*16;
        for (int k = l32; k < NS; k += 32){
            const ushort_t* kr = Kb + (size_t)k*H + h*16;
            float s = 0.f;
            #pragma unroll
            for (int d = 0; d < 16; ++d) s += bf2f(qr[d]) * bf2f(kr[d]);
            sc[h][k] = s;
        }
    }
    __syncthreads();
    // softmax per head: 16 lanes per head (threads 0..127)
    if (t < 128){
        int hh = t >> 4, i = t & 15;
        float mx = -1e30f;
        for (int k = i; k < NS; k += 16) mx = fmaxf(mx, sc[hh][k]);
        #pragma unroll
        for (int off = 1; off < 16; off <<= 1) mx = fmaxf(mx, __shfl_xor(mx, off));
        float sm = 0.f;
        for (int k = i; k < NS; k += 16){
            float e = __expf((sc[hh][k] - mx) * SCALE);
            sc[hh][k] = e;
            sm += e;
        }
        #pragma unroll
        for (int off = 1; off < 16; off <<= 1) sm += __shfl_xor(sm, off);
        if (i == 0) sumh[hh] = sm;
    }
    __syncthreads();
    // attn out per dim + residual q: xa = f2bf(q + o/sum)
    if (t < 128){
        int hh = t >> 4;
        float o = 0.f;
        for (int k = 0; k < NS; ++k) o += sc[hh][k] * bf2f(Vb[(size_t)k*H + t]);
        xa[t] = f2bf(bf2f(q2[t]) + o / sumh[hh]);
    }
    __syncthreads();
    // xb3 = f2bf(xa + relu(xa @ p2fo^T + b))
    if (t < 128){
        float a = 0.f;
        const ushort_t* wr = p2foW + (size_t)t*H;
        for (int k = 0; k < H; ++k) a += bf2f(xa[k]) * bf2f(wr[k]);
        xb3[t] = f2bf(fmaxf(a + p2fob[t], 0.f) + bf2f(xa[t]));
    }
    __syncthreads();
    // l2 = xb3 @ lin2^T + b (fp32) ; v256 = concat(l2, herg)
    if (t < 128){
        float a = 0.f;
        const ushort_t* wr = lin2W + (size_t)t*H;
        for (int k = 0; k < H; ++k) a += bf2f(xb3[k]) * bf2f(wr[k]);
        v256[t] = a + lin2b[t];
        v256[128 + t] = hergv[t];
    }
    __syncthreads();
    if (t < 128){
        float acc = 0.f;
        const float* wr = hoW + (size_t)t*256;
        for (int k = 0; k < 256; ++k) acc += v256[k] * wr[k];
        tt[t] = fmaxf(acc + hob[t], 0.f);
    }
    __syncthreads();
    if (t < 128){
        float acc = 0.f;
        const float* wr = fcW + (size_t)t*128;
        for (int k = 0; k < 128; ++k) acc += tt[k] * wr[k];
        float uv = fmaxf(acc + fcb[t], 0.f);
        red[t] = uv * sW[t];
    }
    __syncthreads();
    for (int s = 64; s > 0; s >>= 1){
        if (t < s) red[t] += red[t + s];
        __syncthreads();
    }
    if (t == 0){
        float logit = red[0] + sb[0];
        outp[b] = 1.f / (1.f + expf(-logit));
    }
}

extern "C" void kernel_launch(void* const* d_in, const int* in_sizes, int n_in,
                              void* d_out, int out_size, void* d_ws, size_t ws_size,
                              hipStream_t stream)
{
    (void)in_sizes; (void)n_in; (void)out_size; (void)ws_size;
    const float* herg_em = (const float*)d_in[0];
    const float* x_in    = (const float*)d_in[1];
    const float* convW[4] = {(const float*)d_in[4], (const float*)d_in[6], (const float*)d_in[8], (const float*)d_in[10]};
    const float* convB[4] = {(const float*)d_in[5], (const float*)d_in[7], (const float*)d_in[9], (const float*)d_in[11]};
    const float* lin1W = (const float*)d_in[12]; const float* lin1b = (const float*)d_in[13];
    const float* lin2W = (const float*)d_in[14]; const float* lin2b = (const float*)d_in[15];
    const float* S1    = (const float*)d_in[16];
    const float* p1fqW = (const float*)d_in[17]; const float* p1fqb = (const float*)d_in[18];
    const float* p1kW  = (const float*)d_in[19]; const float* p1kb  = (const float*)d_in[20];
    const float* p1vW  = (const float*)d_in[21]; const float* p1vb  = (const float*)d_in[22];
    const float* p1foW = (const float*)d_in[23]; const float* p1fob = (const float*)d_in[24];
    const float* sfqW  = (const float*)d_in[25]; const float* sfqb  = (const float*)d_in[26];
    const float* skW   = (const float*)d_in[27]; const float* skb   = (const float*)d_in[28];
    const float* svW   = (const float*)d_in[29]; const float* svb   = (const float*)d_in[30];
    const float* sfoW  = (const float*)d_in[31]; const float* sfob  = (const float*)d_in[32];
    const float* p2fqW = (const float*)d_in[33]; const float* p2fqb = (const float*)d_in[34];
    const float* p2kW  = (const float*)d_in[35]; const float* p2kb  = (const float*)d_in[36];
    const float* p2vW  = (const float*)d_in[37]; const float* p2vb  = (const float*)d_in[38];
    const float* p2foW = (const float*)d_in[39]; const float* p2fob = (const float*)d_in[40];
    const float* S2    = (const float*)d_in[41];
    const float* hlW   = (const float*)d_in[42]; const float* hlb   = (const float*)d_in[43];
    const float* hoW   = (const float*)d_in[44]; const float* hob   = (const float*)d_in[45];
    const float* fcW   = (const float*)d_in[46]; const float* fcb   = (const float*)d_in[47];
    const float* sW    = (const float*)d_in[48]; const float* sb    = (const float*)d_in[49];
    const int*  ei    = (const int*)d_in[50];
    const int*  esrc  = ei;
    const int*  edst  = ei + NE;
    float* outp = (float*)d_out;

    // -------- workspace layout (byte offsets, 16B-aligned) --------
    char* WS = (char*)d_ws;
    int*   counts = (int*)(WS + 0);
    int*   cursor = (int*)(WS + 400384);
    int*   row_st = (int*)(WS + 800768);
    int*   bSums  = (int*)(WS + 1201152);
    int*   bOff   = (int*)(WS + 1203200);
    float* dinv   = (float*)(WS + 1205248);
    float* selfc  = (float*)(WS + 1605632);
    int*   srcs_s = (int*)(WS + 2005632);
    float* ce_s   = (float*)(WS + 3605632);
    ushort_t* wbf = (ushort_t*)(WS + 5205632); // 17*16384
    ushort_t* w0bf= (ushort_t*)(WS + 5762688);
    ushort_t* s1bf= (ushort_t*)(WS + 5779072);
    ushort_t* s2bf= (ushort_t*)(WS + 5798272);
    ushort_t* q0  = (ushort_t*)(WS + 5798528);
    ushort_t* q2  = (ushort_t*)(WS + 5817728);
    float* hergv  = (float*)(WS + 5817984);
    ushort_t* xb64= (ushort_t*)(WS + 6074496); // NN*64 bf16 padded raw x
    ushort_t* b0  = (ushort_t*)(WS + 18874496);// NN*128
    ushort_t* b1  = (ushort_t*)(WS + 44474496);
    ushort_t* b2  = (ushort_t*)(WS + 70074496);
    ushort_t* xA  = (ushort_t*)(WS + 95674496);   // 37504*128
    ushort_t* xB  = (ushort_t*)(WS + 105275520);
    ushort_t* xQ  = (ushort_t*)(WS + 114876544);
    ushort_t* xK  = (ushort_t*)(WS + 124477568);
    ushort_t* xV  = (ushort_t*)(WS + 134078592);

    const int gN   = (NN + 255)/256;       // 391
    const int gE   = (NE + 255)/256;       // 1563
    const int gC   = (NN + 31)/32;         // 3125
    const int gXb  = (NB*NS + 63)/64;      // 586

    // ---- merged weight/input conversions + counts zeroing (1 launch, FIRST) ----
    CvtArgs ca;
    ca.w[0]=convW[1]; ca.w[1]=convW[2]; ca.w[2]=convW[3]; ca.w[3]=lin1W; ca.w[4]=lin2W;
    ca.w[5]=p1kW; ca.w[6]=p1vW; ca.w[7]=p1foW;
    ca.w[8]=sfqW; ca.w[9]=skW; ca.w[10]=svW; ca.w[11]=sfoW;
    ca.w[12]=p2kW; ca.w[13]=p2vW; ca.w[14]=p2foW; ca.w[15]=p1fqW; ca.w[16]=p2fqW;
    ca.w0 = convW[0]; ca.s1 = S1; ca.s2 = S2; ca.x37 = x_in;
    const int cvtTotal = CVT_W + CVT_W0 + CVT_S1 + CVT_S2 + CVT_X;
    k_cvt_all<<<(cvtTotal + 255)/256, 256, 0, stream>>>(ca, wbf, w0bf, s1bf, s2bf, xb64, counts);

    // ---- CSR build ----
    k_hist  <<<gE, 256, 0, stream>>>(counts, edst, NE);
    k_scan1 <<<gN, 256, 0, stream>>>(counts, row_st, bSums, dinv, selfc, NN);
    k_scan2 <<<1, 512, 0, stream>>>(bSums, bOff, gN);
    k_scan3 <<<gN, 256, 0, stream>>>(row_st, cursor, bOff, NN, NE);
    k_fillcsr<<<gE, 256, 0, stream>>>(esrc, edst, dinv, cursor, srcs_s, ce_s, NE);

    // ---- seed-Q projections + hERG (1 launch, 4 blocks) ----
    k_seedq<<<4, 256, 0, stream>>>(s1bf, s2bf, wbf + (size_t)15*16384, p1fqb,
                                   wbf + (size_t)16*16384, p2fqb, q0, q2,
                                   herg_em, hlW, hlb, hergv);

    // ---- conv0 (fused gather64 + GEMM) -> b0 ----
    k_conv0b<<<gC, 256, 0, stream>>>(xb64, row_st, srcs_s, ce_s, selfc, w0bf, convB[0], b0);
    // ---- conv1, conv2 ----
    k_conv_fused3<8,1,0,8><<<gC, 256, 0, stream>>>(b0, row_st, srcs_s, ce_s, selfc,
        wbf + (size_t)0*16384, convB[1], nullptr, nullptr, nullptr, b1, nullptr);
    k_conv_fused3<8,1,0,8><<<gC, 256, 0, stream>>>(b1, row_st, srcs_s, ce_s, selfc,
        wbf + (size_t)1*16384, convB[2], nullptr, nullptr, nullptr, b0, nullptr);
    // ---- conv3 + lin1 fused -> hx in b1 ----
    k_conv_fused3<8,1,1,8><<<gC, 256, 0, stream>>>(b0, row_st, srcs_s, ce_s, selfc,
        wbf + (size_t)2*16384, convB[3], nullptr, wbf + (size_t)3*16384, lin1b, b1, nullptr);
    // ---- pma1 K,V: fused shared-gather + dual GEMM, HEAD-MAJOR out (K->b2, V->b0) ----
    k_conv_fused3<16,0,0,4><<<gC, 256, 0, stream>>>(b1, row_st, srcs_s, ce_s, selfc,
        wbf + (size_t)5*16384, p1kb, p1vb, nullptr, nullptr, b2, b0);
    // ---- GMPool_G attention (head-major K/V) -> xA ----
    k_attn_mfma<200,1><<<NB*4, 256, 0, stream>>>(q0, 0, b2, b0, xA, NS);
    // ---- fused: xb1 = xA + relu(xA@p1fo+b); then SAB Q,K,V ----
    gemm_fo_then<3><<<gXb, 256, 0, stream>>>(xA, NB*NS, wbf + (size_t)7*16384, p1fob,
        wbf + (size_t)8*16384, sfqb, skb, svb, xQ, xK, xV, nullptr);
    // ---- SAB attention -> xB ----
    k_attn_mfma<75,0><<<NB*4, 256, 0, stream>>>(xQ, NS*H, xK, xV, xB, NS);
    // ---- fused: xb2 = xB + relu(xB@sfo+b); then PMA2 K,V ----
    gemm_fo_then<2><<<gXb, 256, 0, stream>>>(xB, NB*NS, wbf + (size_t)11*16384, sfob,
        wbf + (size_t)12*16384, p2kb, p2vb, nullptr, xK, xV, nullptr, nullptr);
    // ---- fused tail: GMPool_I + p2fo + lin2 + head MLP -> out ----
    k_pma2_final<<<NB, 256, 0, stream>>>(q2, xK, xV,
        wbf + (size_t)14*16384, p2fob, wbf + (size_t)4*16384, lin2b,
        hergv, hoW, hob, fcW, fcb, sW, sb, outp);
}

// Round 9
// 731.699 us; speedup vs baseline: 2.1854x; 1.0549x over previous
//
#include <hip/hip_runtime.h>
#include <hip/hip_bf16.h>

typedef unsigned short ushort_t;
typedef unsigned int uint_t;
typedef __attribute__((ext_vector_type(8))) short short8;
typedef __attribute__((ext_vector_type(4))) float float4v;

static constexpr int NN  = 100000;   // nodes
static constexpr int NE  = 400000;   // edges
static constexpr int NB  = 500;      // graphs
static constexpr int NS  = 75;       // seeds
static constexpr int H   = 128;
static constexpr float SCALE = 0.08838834764831845f; // 1/sqrt(128)

union U32 { uint_t u; float f; };
__device__ __forceinline__ float bf2f(ushort_t b){ U32 t; t.u = ((uint_t)b) << 16; return t.f; }
__device__ __forceinline__ ushort_t f2bf(float f){
    U32 t; t.f = f;
    uint_t r = t.u + 0x7fffu + ((t.u >> 16) & 1u);   // RNE
    return (ushort_t)(r >> 16);
}
__device__ __forceinline__ void fma8(float* a, uint4 u, float c){
    a[0] += c * bf2f((ushort_t)(u.x & 0xffff)); a[1] += c * bf2f((ushort_t)(u.x >> 16));
    a[2] += c * bf2f((ushort_t)(u.y & 0xffff)); a[3] += c * bf2f((ushort_t)(u.y >> 16));
    a[4] += c * bf2f((ushort_t)(u.z & 0xffff)); a[5] += c * bf2f((ushort_t)(u.z >> 16));
    a[6] += c * bf2f((ushort_t)(u.w & 0xffff)); a[7] += c * bf2f((ushort_t)(u.w >> 16));
}

// ================= CSR build =================
__global__ void k_hist(int* counts, const int* __restrict__ dst, int e){
    int i = blockIdx.x*256 + threadIdx.x;
    if (i < e) atomicAdd(&counts[dst[i]], 1);
}
// scan + degree norms fused
__global__ __launch_bounds__(256) void k_scan1(const int* __restrict__ counts,
    int* __restrict__ row_start, int* __restrict__ blockSums,
    float* __restrict__ dinv, float* __restrict__ selfc, int n){
    __shared__ int s[256];
    int t = threadIdx.x, i = blockIdx.x*256 + t;
    int v = (i < n) ? counts[i] : 0;
    s[t] = v; __syncthreads();
    #pragma unroll
    for (int off = 1; off < 256; off <<= 1){
        int add = (t >= off) ? s[t-off] : 0;
        __syncthreads();
        s[t] += add;
        __syncthreads();
    }
    if (i < n){
        row_start[i] = s[t] - v;
        float r = rsqrtf(1.f + (float)v);
        dinv[i] = r; selfc[i] = r*r;
    }
    if (t == 255) blockSums[blockIdx.x] = s[255];
}
__global__ __launch_bounds__(512) void k_scan2(const int* __restrict__ blockSums,
    int* __restrict__ blockOff, int nb){
    __shared__ int s[512];
    int t = threadIdx.x;
    int v = (t < nb) ? blockSums[t] : 0;
    s[t] = v; __syncthreads();
    #pragma unroll
    for (int off = 1; off < 512; off <<= 1){
        int add = (t >= off) ? s[t-off] : 0;
        __syncthreads();
        s[t] += add;
        __syncthreads();
    }
    blockOff[t] = s[t] - v;
}
__global__ void k_scan3(int* __restrict__ row_start, int* __restrict__ cursor,
                        const int* __restrict__ blockOff, int n, int total){
    int i = blockIdx.x*256 + threadIdx.x;
    if (i < n){
        int v = row_start[i] + blockOff[i >> 8];
        row_start[i] = v; cursor[i] = v;
    }
    if (i == 0) row_start[n] = total;
}
__global__ void k_fillcsr(const int* __restrict__ src, const int* __restrict__ dst,
    const float* __restrict__ dinv, int* cursor,
    int* __restrict__ srcs_s, float* __restrict__ ce_s, int e){
    int i = blockIdx.x*256 + threadIdx.x;
    if (i < e){
        int d = dst[i], s = src[i];
        int p = atomicAdd(&cursor[d], 1);
        srcs_s[p] = s;
        ce_s[p] = dinv[s] * dinv[d];
    }
}

// ================= merged conversions (+ counts zeroing) =================
struct CvtArgs { const float* w[17]; const float* w0; const float* s1; const float* s2; const float* x37; };
static constexpr int CVT_W   = 17*16384;
static constexpr int CVT_W0  = 8192;
static constexpr int CVT_S1  = 9600;
static constexpr int CVT_S2  = 128;
static constexpr int CVT_X   = NN*64;
__global__ void k_cvt_all(CvtArgs a, ushort_t* __restrict__ wbf, ushort_t* __restrict__ w0bf,
                          ushort_t* __restrict__ s1bf, ushort_t* __restrict__ s2bf,
                          ushort_t* __restrict__ xb64, int* __restrict__ counts){
    int i = blockIdx.x*256 + threadIdx.x;
    if (i < NN) counts[i] = 0;                       // folded k_zero_i
    if (i < CVT_W){ int idx = i >> 14, off = i & 16383; wbf[i] = f2bf(a.w[idx][off]); return; }
    i -= CVT_W;
    if (i < CVT_W0){ int r = i >> 6, c = i & 63; w0bf[i] = (c < 37) ? f2bf(a.w0[r*37 + c]) : (ushort_t)0; return; }
    i -= CVT_W0;
    if (i < CVT_S1){ s1bf[i] = f2bf(a.s1[i]); return; }
    i -= CVT_S1;
    if (i < CVT_S2){ s2bf[i] = f2bf(a.s2[i]); return; }
    i -= CVT_S2;
    if (i < CVT_X){ int r = i >> 6, c = i & 63; xb64[i] = (c < 37) ? f2bf(a.x37[(size_t)r*37 + c]) : (ushort_t)0; return; }
}

// ========== seed-Q projections + hERG fused ==========
__global__ __launch_bounds__(256) void k_seedq(
    const ushort_t* __restrict__ s1bf, const ushort_t* __restrict__ s2bf,
    const ushort_t* __restrict__ W1, const float* __restrict__ bias1,
    const ushort_t* __restrict__ W2q, const float* __restrict__ bias2,
    ushort_t* __restrict__ q0, ushort_t* __restrict__ q2,
    const float* __restrict__ hem, const float* __restrict__ hlW,
    const float* __restrict__ hlb, float* __restrict__ hergv)
{
    int blk = blockIdx.x;
    int tid  = threadIdx.x;
    if (blk == 3){
        __shared__ float e[1280];
        for (int i = tid; i < 1280; i += 256) e[i] = hem[i];
        __syncthreads();
        if (tid < 128){
            float acc = 0.f;
            for (int k = 0; k < 1280; ++k) acc += e[k] * hlW[(size_t)tid*1280 + k];
            hergv[tid] = fmaxf(acc + hlb[tid], 0.f);
        }
        return;
    }
    const ushort_t* x = (blk < 2) ? s1bf : s2bf;
    const ushort_t* W = (blk < 2) ? W1 : W2q;
    const float* bias = (blk < 2) ? bias1 : bias2;
    ushort_t* out = (blk < 2) ? q0 : q2;
    int M = (blk < 2) ? NS : 1;
    int base = (blk < 2) ? blk*64 : 0;
    int wid  = tid >> 6;
    int lane = tid & 63;
    int l15  = lane & 15, quad = lane >> 4;
    int row0 = base + wid*16;
    int ar   = row0 + l15; if (ar > M-1) ar = M-1;
    const short* xr = (const short*)(x + (size_t)ar*H) + quad*8;
    float4v acc[8];
    #pragma unroll
    for (int i = 0; i < 8; ++i) acc[i] = (float4v)0.f;
    #pragma unroll
    for (int kc = 0; kc < 4; ++kc){
        short8 a = *(const short8*)(xr + kc*32);
        #pragma unroll
        for (int nt = 0; nt < 8; ++nt){
            short8 b = *(const short8*)((const short*)(W + (size_t)(nt*16 + l15)*H) + kc*32 + quad*8);
            acc[nt] = __builtin_amdgcn_mfma_f32_16x16x32_bf16(a, b, acc[nt], 0, 0, 0);
        }
    }
    #pragma unroll
    for (int nt = 0; nt < 8; ++nt){
        int c = nt*16 + l15;
        float bv = bias[c];
        #pragma unroll
        for (int reg = 0; reg < 4; ++reg){
            int r = row0 + quad*4 + reg;
            if (r >= M) continue;
            out[(size_t)r*H + c] = f2bf(acc[nt][reg] + bv);
        }
    }
}

// ========== fused gather + MFMA GEMM v3 (2-edge unroll + index prefetch) ==========
// NOUT==16 writes K/V head-major: record = 32 elems (64B) per (head-pair, node)
template<int NOUT, int RELU, int STAGE2, int MINW>
__global__ __launch_bounds__(256, MINW) void k_conv_fused3(
    const ushort_t* __restrict__ x,
    const int* __restrict__ row_st, const int* __restrict__ srcs,
    const float* __restrict__ ces, const float* __restrict__ selfc,
    const ushort_t* __restrict__ W, const float* __restrict__ bias0,
    const float* __restrict__ bias1,
    const ushort_t* __restrict__ W2, const float* __restrict__ bias2,
    ushort_t* __restrict__ out0, ushort_t* __restrict__ out1)
{
    __shared__ ushort_t As[32][136];
    __shared__ ushort_t Bs[(NOUT==16)?32:1][(NOUT==16)?136:1];
    const int tid = threadIdx.x;
    const int node = tid >> 3, qq = tid & 7;   // 8 threads/node, 16 cols each
    const int g = blockIdx.x*32 + node;
    float acc[16];
    #pragma unroll
    for (int i = 0; i < 16; ++i) acc[i] = 0.f;
    if (g < NN){
        const uint4* xr = (const uint4*)(x + (size_t)g*H + qq*16);
        float sc = selfc[g];
        uint4 u0 = xr[0], u1 = xr[1];
        fma8(acc+0, u0, sc); fma8(acc+8, u1, sc);
        int e = row_st[g], e1 = row_st[g+1];
        int sA = 0, sB = 0; float cA = 0.f, cB = 0.f;
        if (e < e1){ sA = srcs[e]; cA = ces[e]; }
        if (e + 1 < e1){ sB = srcs[e+1]; cB = ces[e+1]; }
        while (e + 2 <= e1){
            int sA2 = 0, sB2 = 0; float cA2 = 0.f, cB2 = 0.f;
            if (e + 2 < e1){ sA2 = srcs[e+2]; cA2 = ces[e+2]; }
            if (e + 3 < e1){ sB2 = srcs[e+3]; cB2 = ces[e+3]; }
            const uint4* pa = (const uint4*)(x + (size_t)sA*H + qq*16);
            const uint4* pb = (const uint4*)(x + (size_t)sB*H + qq*16);
            uint4 a0 = pa[0], a1 = pa[1];
            uint4 c0 = pb[0], c1 = pb[1];
            fma8(acc+0, a0, cA); fma8(acc+8, a1, cA);
            fma8(acc+0, c0, cB); fma8(acc+8, c1, cB);
            sA = sA2; sB = sB2; cA = cA2; cB = cB2;
            e += 2;
        }
        if (e < e1){
            const uint4* pa = (const uint4*)(x + (size_t)sA*H + qq*16);
            uint4 a0 = pa[0], a1 = pa[1];
            fma8(acc+0, a0, cA); fma8(acc+8, a1, cA);
        }
    }
    {
        uint_t* dst = (uint_t*)&As[node][qq*16];
        #pragma unroll
        for (int i = 0; i < 8; ++i)
            dst[i] = (uint_t)f2bf(acc[2*i]) | ((uint_t)f2bf(acc[2*i+1]) << 16);
    }
    __syncthreads();
    const int w = tid >> 6, lane = tid & 63, l15 = lane & 15, quad = lane >> 4;
    const int rt = w & 1;                  // row tile (16 rows)
    constexpr int NT = NOUT/2;             // col tiles per wave
    const int ct0 = (w >> 1) * NT;
    float4v o[NT];
    #pragma unroll
    for (int t = 0; t < NT; ++t) o[t] = (float4v)0.f;
    #pragma unroll
    for (int kc = 0; kc < 4; ++kc){
        short8 a = *(const short8*)(&As[rt*16 + l15][kc*32 + quad*8]);
        #pragma unroll
        for (int t = 0; t < NT; ++t){
            short8 bfr = *(const short8*)(W + (size_t)((ct0 + t)*16 + l15)*H + kc*32 + quad*8);
            o[t] = __builtin_amdgcn_mfma_f32_16x16x32_bf16(a, bfr, o[t], 0, 0, 0);
        }
    }
    __syncthreads();
    #pragma unroll
    for (int t = 0; t < NT; ++t){
        int cg = (ct0 + t)*16 + l15;
        #pragma unroll
        for (int r = 0; r < 4; ++r){
            float v;
            if (NOUT == 8 || cg < 128){
                v = o[t][r] + bias0[cg];
                if (RELU) v = fmaxf(v, 0.f);
                As[rt*16 + quad*4 + r][cg] = f2bf(v);
            } else {
                v = o[t][r] + bias1[cg - 128];
                if (RELU) v = fmaxf(v, 0.f);
                Bs[rt*16 + quad*4 + r][cg - 128] = f2bf(v);
            }
        }
    }
    __syncthreads();
    if (STAGE2){
        float4v o2[4];
        #pragma unroll
        for (int t = 0; t < 4; ++t) o2[t] = (float4v)0.f;
        const int ct2 = (w >> 1) * 4;
        #pragma unroll
        for (int kc = 0; kc < 4; ++kc){
            short8 a = *(const short8*)(&As[rt*16 + l15][kc*32 + quad*8]);
            #pragma unroll
            for (int t = 0; t < 4; ++t){
                short8 bfr = *(const short8*)(W2 + (size_t)((ct2 + t)*16 + l15)*H + kc*32 + quad*8);
                o2[t] = __builtin_amdgcn_mfma_f32_16x16x32_bf16(a, bfr, o2[t], 0, 0, 0);
            }
        }
        __syncthreads();
        #pragma unroll
        for (int t = 0; t < 4; ++t){
            int cg = (ct2 + t)*16 + l15;
            #pragma unroll
            for (int r = 0; r < 4; ++r)
                As[rt*16 + quad*4 + r][cg] = f2bf(o2[t][r] + bias2[cg]);
        }
        __syncthreads();
    }
    if (g < NN){
        if (NOUT == 16){
            // head-major K/V for attention: dest = [(hp)*NN + node]*32 + (qq&1)*16 elems
            size_t kb = ((size_t)(qq >> 1)*NN + (size_t)g)*32 + (size_t)(qq & 1)*16;
            ((uint4*)(out0 + kb))[0] = *(const uint4*)&As[node][qq*16];
            ((uint4*)(out0 + kb))[1] = *(const uint4*)&As[node][qq*16 + 8];
            ((uint4*)(out1 + kb))[0] = *(const uint4*)&Bs[node][qq*16];
            ((uint4*)(out1 + kb))[1] = *(const uint4*)&Bs[node][qq*16 + 8];
        } else {
            uint4* op = (uint4*)(out0 + (size_t)g*H + qq*16);
            const uint4* sp = (const uint4*)&As[node][qq*16];
            op[0] = sp[0]; op[1] = sp[1];
        }
    }
}

// ========== conv0: gather padded-64 bf16 rows + MFMA GEMM (K=64) ==========
__global__ __launch_bounds__(256, 8) void k_conv0b(
    const ushort_t* __restrict__ x,   // [NN][64] bf16
    const int* __restrict__ row_st, const int* __restrict__ srcs,
    const float* __restrict__ ces, const float* __restrict__ selfc,
    const ushort_t* __restrict__ W,   // [128][64]
    const float* __restrict__ bias,
    ushort_t* __restrict__ out)
{
    __shared__ ushort_t As[32][136];
    const int tid = threadIdx.x;
    const int node = tid >> 3, qq = tid & 7;   // 8 cols (1 uint4) each
    const int g = blockIdx.x*32 + node;
    float acc[8];
    #pragma unroll
    for (int i = 0; i < 8; ++i) acc[i] = 0.f;
    if (g < NN){
        const uint4* xr = (const uint4*)(x + (size_t)g*64 + qq*8);
        float sc = selfc[g];
        fma8(acc, xr[0], sc);
        int e = row_st[g], e1 = row_st[g+1];
        int sA = 0, sB = 0; float cA = 0.f, cB = 0.f;
        if (e < e1){ sA = srcs[e]; cA = ces[e]; }
        if (e + 1 < e1){ sB = srcs[e+1]; cB = ces[e+1]; }
        while (e + 2 <= e1){
            int sA2 = 0, sB2 = 0; float cA2 = 0.f, cB2 = 0.f;
            if (e + 2 < e1){ sA2 = srcs[e+2]; cA2 = ces[e+2]; }
            if (e + 3 < e1){ sB2 = srcs[e+3]; cB2 = ces[e+3]; }
            uint4 a0 = *(const uint4*)(x + (size_t)sA*64 + qq*8);
            uint4 c0 = *(const uint4*)(x + (size_t)sB*64 + qq*8);
            fma8(acc, a0, cA);
            fma8(acc, c0, cB);
            sA = sA2; sB = sB2; cA = cA2; cB = cB2;
            e += 2;
        }
        if (e < e1){
            uint4 a0 = *(const uint4*)(x + (size_t)sA*64 + qq*8);
            fma8(acc, a0, cA);
        }
    }
    {
        uint_t* dst = (uint_t*)&As[node][qq*8];
        #pragma unroll
        for (int i = 0; i < 4; ++i)
            dst[i] = (uint_t)f2bf(acc[2*i]) | ((uint_t)f2bf(acc[2*i+1]) << 16);
    }
    __syncthreads();
    const int w = tid >> 6, lane = tid & 63, l15 = lane & 15, quad = lane >> 4;
    const int rt = w & 1;
    const int ct0 = (w >> 1) * 4;
    float4v o[4];
    #pragma unroll
    for (int t = 0; t < 4; ++t) o[t] = (float4v)0.f;
    #pragma unroll
    for (int kc = 0; kc < 2; ++kc){
        short8 a = *(const short8*)(&As[rt*16 + l15][kc*32 + quad*8]);
        #pragma unroll
        for (int t = 0; t < 4; ++t){
            short8 bfr = *(const short8*)(W + (size_t)((ct0 + t)*16 + l15)*64 + kc*32 + quad*8);
            o[t] = __builtin_amdgcn_mfma_f32_16x16x32_bf16(a, bfr, o[t], 0, 0, 0);
        }
    }
    __syncthreads();
    #pragma unroll
    for (int t = 0; t < 4; ++t){
        int cg = (ct0 + t)*16 + l15;
        #pragma unroll
        for (int r = 0; r < 4; ++r)
            As[rt*16 + quad*4 + r][cg] = f2bf(fmaxf(o[t][r] + bias[cg], 0.f));
    }
    __syncthreads();
    if (g < NN){
        uint4* op = (uint4*)(out + (size_t)g*H + qq*16);
        const uint4* sp = (const uint4*)&As[node][qq*16];
        op[0] = sp[0]; op[1] = sp[1];
    }
}

// ========== MFMA flash attention (GMPool_G, head-major K/V) ==========
template<int NK, int HM>
__global__ __launch_bounds__(256) void k_attn_mfma(
    const ushort_t* __restrict__ Q, int qbs,
    const ushort_t* __restrict__ K, const ushort_t* __restrict__ V,
    ushort_t* __restrict__ out, int nq)
{
    constexpr int NKT = (NK + 15) / 16;
    constexpr int NKC = (NK + 31) / 32;
    __shared__ ushort_t Ks[2][208][24];
    __shared__ ushort_t Vs[2][16][232];
    __shared__ ushort_t Ps[4][16][232];
    int b = blockIdx.x >> 2, hp = blockIdx.x & 3;
    int h0 = hp*2;
    int tid = threadIdx.x;
    {
        uint_t* p = (uint_t*)&Ps[0][0][0];
        for (int i = tid; i < 4*16*232/2; i += 256) p[i] = 0;
    }
    const ushort_t* Kb = HM ? (K + ((size_t)hp*NB + b)*NK*32)
                            : (K + (size_t)b*NK*H + h0*16);
    for (int idx = tid; idx < NK*8; idx += 256){
        int key = idx >> 3, p = idx & 7;
        int hh = p >> 2, dl = (p & 3)*4;
        const uint_t* src = HM ? (const uint_t*)(Kb + (size_t)key*32 + hh*16 + dl)
                               : (const uint_t*)(Kb + (size_t)key*H + hh*16 + dl);
        uint_t* d = (uint_t*)&Ks[hh][key][dl];
        d[0] = src[0]; d[1] = src[1];
    }
    const ushort_t* Vb = HM ? (V + ((size_t)hp*NB + b)*NK*32)
                            : (V + (size_t)b*NK*H + h0*16);
    for (int idx = tid; idx < NK*8; idx += 256){
        int key = idx >> 3, p = idx & 7;
        int hh = p >> 2, dl = (p & 3)*4;
        const ushort_t* src = HM ? (Vb + (size_t)key*32 + hh*16 + dl)
                                 : (Vb + (size_t)key*H + hh*16 + dl);
        Vs[hh][dl+0][key] = src[0];
        Vs[hh][dl+1][key] = src[1];
        Vs[hh][dl+2][key] = src[2];
        Vs[hh][dl+3][key] = src[3];
    }
    for (int idx = tid; idx < 2*16*(232-NK); idx += 256){
        int key = NK + idx % (232-NK), r = idx / (232-NK);
        Vs[r>>4][r&15][key] = 0;
    }
    __syncthreads();

    int w = tid >> 6, lane = tid & 63;
    int hh = w >> 1, half = w & 1;
    int h = h0 + hh;
    int l15 = lane & 15, quad = lane >> 4;
    bool klow = (quad < 2);
    int nqt = (nq + 15) >> 4;
    int split = (nqt + 1) >> 1;
    int qt0 = half ? split : 0;
    int qt1 = half ? nqt : split;
    for (int qt = qt0; qt < qt1; ++qt){
        int qr = qt*16 + l15; if (qr > nq-1) qr = nq-1;
        short8 av = *(const short8*)(Q + (size_t)b*qbs + (size_t)qr*H + h*16 + (quad & 1)*8);
        short8 zero8 = (short8)0;
        short8 afrag = klow ? av : zero8;
        float4v s[NKT];
        #pragma unroll
        for (int kt = 0; kt < NKT; ++kt){
            short8 bv = *(const short8*)(&Ks[hh][kt*16 + l15][(quad & 1)*8]);
            short8 bfrag = klow ? bv : zero8;
            s[kt] = __builtin_amdgcn_mfma_f32_16x16x32_bf16(afrag, bfrag, (float4v)0.f, 0, 0, 0);
        }
        float mx[4] = {-1e30f, -1e30f, -1e30f, -1e30f};
        #pragma unroll
        for (int kt = 0; kt < NKT; ++kt){
            if (kt*16 + l15 >= NK){ s[kt][0]=-1e30f; s[kt][1]=-1e30f; s[kt][2]=-1e30f; s[kt][3]=-1e30f; }
            #pragma unroll
            for (int r = 0; r < 4; ++r) mx[r] = fmaxf(mx[r], s[kt][r]);
        }
        #pragma unroll
        for (int off = 1; off < 16; off <<= 1){
            #pragma unroll
            for (int r = 0; r < 4; ++r) mx[r] = fmaxf(mx[r], __shfl_xor(mx[r], off));
        }
        float sum[4] = {0.f, 0.f, 0.f, 0.f};
        #pragma unroll
        for (int kt = 0; kt < NKT; ++kt){
            #pragma unroll
            for (int r = 0; r < 4; ++r){
                float e = __expf((s[kt][r] - mx[r]) * SCALE);
                sum[r] += e;
                Ps[w][quad*4 + r][kt*16 + l15] = f2bf(e);
            }
        }
        #pragma unroll
        for (int off = 1; off < 16; off <<= 1){
            #pragma unroll
            for (int r = 0; r < 4; ++r) sum[r] += __shfl_xor(sum[r], off);
        }
        float4v o = (float4v)0.f;
        #pragma unroll
        for (int kc = 0; kc < NKC; ++kc){
            short8 pa = *(const short8*)(&Ps[w][l15][kc*32 + quad*8]);
            short8 vb = *(const short8*)(&Vs[hh][l15][kc*32 + quad*8]);
            o = __builtin_amdgcn_mfma_f32_16x16x32_bf16(pa, vb, o, 0, 0, 0);
        }
        #pragma unroll
        for (int r = 0; r < 4; ++r){
            int row = qt*16 + quad*4 + r;
            if (row < nq){
                float qv = bf2f(Q[(size_t)b*qbs + (size_t)row*H + h*16 + l15]);
                out[((size_t)b*nq + row)*H + h*16 + l15] = f2bf(qv + o[r] / sum[r]);
            }
        }
    }
}

// ========== per-graph tail: p1fo rFF + SAB (proj+attn+rFF) + PMA2 + head MLP ==========
// one block per graph (500 blocks), 4 waves, ~105 KB LDS (1 block/CU)
struct TailArgs {
    const ushort_t* xA; const ushort_t* q2;
    const ushort_t* p1foW; const float* p1fob;
    const ushort_t* sfqW;  const float* sfqb;
    const ushort_t* skW;   const float* skb;
    const ushort_t* svW;   const float* svb;
    const ushort_t* sfoW;  const float* sfob;
    const ushort_t* p2kW;  const float* p2kb;
    const ushort_t* p2vW;  const float* p2vb;
    const ushort_t* p2foW; const float* p2fob;
    const ushort_t* lin2W; const float* lin2b;
    const float* hergv;
    const float* hoW; const float* hob;
    const float* fcW; const float* fcb;
    const float* sW;  const float* sb;
    float* outp;
};

__global__ __launch_bounds__(256, 1) void k_graph_tail(TailArgs a){
    __shared__ ushort_t bufQ[80*136];      // xA-in / SAB Q / SAB out / PMA2 V
    __shared__ ushort_t bufX[80*136];      // xb1 / xb2
    __shared__ ushort_t bufK[80*136];      // SAB K / PMA2 K
    __shared__ ushort_t vt[8*16*104];      // SAB V transposed per head
    __shared__ ushort_t ps[4*16*104];      // per-wave P; later tail scratch
    const int b = blockIdx.x, tid = threadIdx.x;
    const int w = tid >> 6, lane = tid & 63, l15 = lane & 15, quad = lane >> 4;

    // P0: zero vt/ps; load xA rows for this graph
    for (int i = tid; i < 8*16*104/2; i += 256) ((uint_t*)vt)[i] = 0u;
    for (int i = tid; i < 4*16*104/2; i += 256) ((uint_t*)ps)[i] = 0u;
    {
        const ushort_t* xg = a.xA + (size_t)b*NS*H;
        for (int i = tid; i < NS*16; i += 256){
            int row = i >> 4, q = i & 15;
            *(uint4*)(bufQ + row*136 + q*8) = *(const uint4*)(xg + (size_t)row*H + q*8);
        }
    }
    __syncthreads();

    // P1: bufX = xA + relu(xA @ p1foW^T + p1fob)    (rows >=75 garbage, masked later)
    for (int job = w; job < 40; job += 4){
        int rt = job >> 3, ct = job & 7;
        float4v o = (float4v)0.f;
        #pragma unroll
        for (int kc = 0; kc < 4; ++kc){
            short8 av = *(const short8*)(bufQ + (rt*16 + l15)*136 + kc*32 + quad*8);
            short8 bv = *(const short8*)((const short*)(a.p1foW + (size_t)(ct*16 + l15)*H) + kc*32 + quad*8);
            o = __builtin_amdgcn_mfma_f32_16x16x32_bf16(av, bv, o, 0, 0, 0);
        }
        int c = ct*16 + l15; float bb = a.p1fob[c];
        #pragma unroll
        for (int r = 0; r < 4; ++r){
            int row = rt*16 + quad*4 + r;
            bufX[row*136 + c] = f2bf(fmaxf(o[r] + bb, 0.f) + bf2f(bufQ[row*136 + c]));
        }
    }
    __syncthreads();

    // P2: SAB projections from bufX: Q->bufQ, K->bufK, V->vt (transposed, key<75)
    for (int job = w; job < 40; job += 4){
        int rt = job >> 3, ct = job & 7;
        float4v o = (float4v)0.f;
        #pragma unroll
        for (int kc = 0; kc < 4; ++kc){
            short8 av = *(const short8*)(bufX + (rt*16 + l15)*136 + kc*32 + quad*8);
            short8 bv = *(const short8*)((const short*)(a.sfqW + (size_t)(ct*16 + l15)*H) + kc*32 + quad*8);
            o = __builtin_amdgcn_mfma_f32_16x16x32_bf16(av, bv, o, 0, 0, 0);
        }
        int c = ct*16 + l15; float bb = a.sfqb[c];
        #pragma unroll
        for (int r = 0; r < 4; ++r)
            bufQ[(rt*16 + quad*4 + r)*136 + c] = f2bf(o[r] + bb);
    }
    for (int job = w; job < 40; job += 4){
        int rt = job >> 3, ct = job & 7;
        float4v o = (float4v)0.f;
        #pragma unroll
        for (int kc = 0; kc < 4; ++kc){
            short8 av = *(const short8*)(bufX + (rt*16 + l15)*136 + kc*32 + quad*8);
            short8 bv = *(const short8*)((const short*)(a.skW + (size_t)(ct*16 + l15)*H) + kc*32 + quad*8);
            o = __builtin_amdgcn_mfma_f32_16x16x32_bf16(av, bv, o, 0, 0, 0);
        }
        int c = ct*16 + l15; float bb = a.skb[c];
        #pragma unroll
        for (int r = 0; r < 4; ++r)
            bufK[(rt*16 + quad*4 + r)*136 + c] = f2bf(o[r] + bb);
    }
    for (int job = w; job < 40; job += 4){
        int rt = job >> 3, ct = job & 7;
        float4v o = (float4v)0.f;
        #pragma unroll
        for (int kc = 0; kc < 4; ++kc){
            short8 av = *(const short8*)(bufX + (rt*16 + l15)*136 + kc*32 + quad*8);
            short8 bv = *(const short8*)((const short*)(a.svW + (size_t)(ct*16 + l15)*H) + kc*32 + quad*8);
            o = __builtin_amdgcn_mfma_f32_16x16x32_bf16(av, bv, o, 0, 0, 0);
        }
        int c = ct*16 + l15; float bb = a.svb[c];
        #pragma unroll
        for (int r = 0; r < 4; ++r){
            int key = rt*16 + quad*4 + r;
            if (key < NS) vt[c*104 + key] = f2bf(o[r] + bb);   // c = head*16 + dim
        }
    }
    __syncthreads();

    // P3: SAB attention: wave w handles heads 2w, 2w+1; out (Q+O) overwrites bufQ
    {
        short8 zero8 = (short8)0;
        bool klow = (quad < 2);
        for (int hh = 0; hh < 2; ++hh){
            int h = w*2 + hh;
            for (int qt = 0; qt < 5; ++qt){
                short8 av = *(const short8*)(bufQ + (qt*16 + l15)*136 + h*16 + (quad & 1)*8);
                short8 afrag = klow ? av : zero8;
                float4v s[5];
                #pragma unroll
                for (int kt = 0; kt < 5; ++kt){
                    short8 bv = *(const short8*)(bufK + (kt*16 + l15)*136 + h*16 + (quad & 1)*8);
                    short8 bfrag = klow ? bv : zero8;
                    s[kt] = __builtin_amdgcn_mfma_f32_16x16x32_bf16(afrag, bfrag, (float4v)0.f, 0, 0, 0);
                }
                float mx[4] = {-1e30f, -1e30f, -1e30f, -1e30f};
                #pragma unroll
                for (int kt = 0; kt < 5; ++kt){
                    if (kt*16 + l15 >= NS){ s[kt][0]=-1e30f; s[kt][1]=-1e30f; s[kt][2]=-1e30f; s[kt][3]=-1e30f; }
                    #pragma unroll
                    for (int r = 0; r < 4; ++r) mx[r] = fmaxf(mx[r], s[kt][r]);
                }
                #pragma unroll
                for (int off = 1; off < 16; off <<= 1){
                    #pragma unroll
                    for (int r = 0; r < 4; ++r) mx[r] = fmaxf(mx[r], __shfl_xor(mx[r], off));
                }
                float sum[4] = {0.f, 0.f, 0.f, 0.f};
                #pragma unroll
                for (int kt = 0; kt < 5; ++kt){
                    #pragma unroll
                    for (int r = 0; r < 4; ++r){
                        float e = __expf((s[kt][r] - mx[r]) * SCALE);
                        sum[r] += e;
                        ps[w*1664 + (quad*4 + r)*104 + kt*16 + l15] = f2bf(e);
                    }
                }
                #pragma unroll
                for (int off = 1; off < 16; off <<= 1){
                    #pragma unroll
                    for (int r = 0; r < 4; ++r) sum[r] += __shfl_xor(sum[r], off);
                }
                float4v o = (float4v)0.f;
                #pragma unroll
                for (int kc = 0; kc < 3; ++kc){
                    short8 pa = *(const short8*)(ps + w*1664 + l15*104 + kc*32 + quad*8);
                    short8 vb = *(const short8*)(vt + (h*16 + l15)*104 + kc*32 + quad*8);
                    o = __builtin_amdgcn_mfma_f32_16x16x32_bf16(pa, vb, o, 0, 0, 0);
                }
                #pragma unroll
                for (int r = 0; r < 4; ++r){
                    int row = qt*16 + quad*4 + r;
                    if (row < NS){
                        float qv = bf2f(bufQ[row*136 + h*16 + l15]);
                        bufQ[row*136 + h*16 + l15] = f2bf(qv + o[r] / sum[r]);
                    }
                }
            }
        }
    }
    __syncthreads();

    // P4: xb2 = out + relu(out @ sfoW^T + b) -> bufX
    for (int job = w; job < 40; job += 4){
        int rt = job >> 3, ct = job & 7;
        float4v o = (float4v)0.f;
        #pragma unroll
        for (int kc = 0; kc < 4; ++kc){
            short8 av = *(const short8*)(bufQ + (rt*16 + l15)*136 + kc*32 + quad*8);
            short8 bv = *(const short8*)((const short*)(a.sfoW + (size_t)(ct*16 + l15)*H) + kc*32 + quad*8);
            o = __builtin_amdgcn_mfma_f32_16x16x32_bf16(av, bv, o, 0, 0, 0);
        }
        int c = ct*16 + l15; float bb = a.sfob[c];
        #pragma unroll
        for (int r = 0; r < 4; ++r){
            int row = rt*16 + quad*4 + r;
            bufX[row*136 + c] = f2bf(fmaxf(o[r] + bb, 0.f) + bf2f(bufQ[row*136 + c]));
        }
    }
    __syncthreads();

    // P5: PMA2 K -> bufK, V -> bufQ (plain [key][dim])
    for (int job = w; job < 40; job += 4){
        int rt = job >> 3, ct = job & 7;
        float4v o = (float4v)0.f;
        #pragma unroll
        for (int kc = 0; kc < 4; ++kc){
            short8 av = *(const short8*)(bufX + (rt*16 + l15)*136 + kc*32 + quad*8);
            short8 bv = *(const short8*)((const short*)(a.p2kW + (size_t)(ct*16 + l15)*H) + kc*32 + quad*8);
            o = __builtin_amdgcn_mfma_f32_16x16x32_bf16(av, bv, o, 0, 0, 0);
        }
        int c = ct*16 + l15; float bb = a.p2kb[c];
        #pragma unroll
        for (int r = 0; r < 4; ++r)
            bufK[(rt*16 + quad*4 + r)*136 + c] = f2bf(o[r] + bb);
    }
    for (int job = w; job < 40; job += 4){
        int rt = job >> 3, ct = job & 7;
        float4v o = (float4v)0.f;
        #pragma unroll
        for (int kc = 0; kc < 4; ++kc){
            short8 av = *(const short8*)(bufX + (rt*16 + l15)*136 + kc*32 + quad*8);
            short8 bv = *(const short8*)((const short*)(a.p2vW + (size_t)(ct*16 + l15)*H) + kc*32 + quad*8);
            o = __builtin_amdgcn_mfma_f32_16x16x32_bf16(av, bv, o, 0, 0, 0);
        }
        int c = ct*16 + l15; float bb = a.p2vb[c];
        #pragma unroll
        for (int r = 0; r < 4; ++r)
            bufQ[(rt*16 + quad*4 + r)*136 + c] = f2bf(o[r] + bb);
    }
    __syncthreads();

    // P6: 1-seed attention + p2fo residual + lin2 + head MLP (tail scratch aliased over ps)
    {
        int t = tid;
        char* sb8 = (char*)ps;
        float* sc       = (float*)sb8;              // 8*76 floats
        float* sumh     = (float*)(sb8 + 2432);     // 8
        ushort_t* xa    = (ushort_t*)(sb8 + 2464);  // 128
        ushort_t* xb3   = (ushort_t*)(sb8 + 2720);  // 128
        float* tt       = (float*)(sb8 + 2976);     // 128
        float* v256     = (float*)(sb8 + 3488);     // 256
        float* red      = (float*)(sb8 + 4512);     // 128
        {
            int h = t >> 5, l32 = t & 31;
            const ushort_t* qr = a.q2 + h*16;
            for (int k = l32; k < NS; k += 32){
                float s = 0.f;
                #pragma unroll
                for (int d = 0; d < 16; ++d) s += bf2f(qr[d]) * bf2f(bufK[k*136 + h*16 + d]);
                sc[h*76 + k] = s;
            }
        }
        __syncthreads();
        if (t < 128){
            int hh = t >> 4, i = t & 15;
            float mx = -1e30f;
            for (int k = i; k < NS; k += 16) mx = fmaxf(mx, sc[hh*76 + k]);
            #pragma unroll
            for (int off = 1; off < 16; off <<= 1) mx = fmaxf(mx, __shfl_xor(mx, off));
            float sm = 0.f;
            for (int k = i; k < NS; k += 16){
                float e = __expf((sc[hh*76 + k] - mx) * SCALE);
                sc[hh*76 + k] = e;
                sm += e;
            }
            #pragma unroll
            for (int off = 1; off < 16; off <<= 1) sm += __shfl_xor(sm, off);
            if (i == 0) sumh[hh] = sm;
        }
        __syncthreads();
        if (t < 128){
            int hh = t >> 4;
            float o = 0.f;
            for (int k = 0; k < NS; ++k) o += sc[hh*76 + k] * bf2f(bufQ[k*136 + t]);
            xa[t] = f2bf(bf2f(a.q2[t]) + o / sumh[hh]);
        }
        __syncthreads();
        if (t < 128){
            float acc = 0.f;
            const ushort_t* wr = a.p2foW + (size_t)t*H;
            for (int k = 0; k < H; ++k) acc += bf2f(xa[k]) * bf2f(wr[k]);
            xb3[t] = f2bf(fmaxf(acc + a.p2fob[t], 0.f) + bf2f(xa[t]));
        }
        __syncthreads();
        if (t < 128){
            float acc = 0.f;
            const ushort_t* wr = a.lin2W + (size_t)t*H;
            for (int k = 0; k < H; ++k) acc += bf2f(xb3[k]) * bf2f(wr[k]);
            v256[t] = acc + a.lin2b[t];
            v256[128 + t] = a.hergv[t];
        }
        __syncthreads();
        if (t < 128){
            float acc = 0.f;
            const float* wr = a.hoW + (size_t)t*256;
            for (int k = 0; k < 256; ++k) acc += v256[k] * wr[k];
            tt[t] = fmaxf(acc + a.hob[t], 0.f);
        }
        __syncthreads();
        if (t < 128){
            float acc = 0.f;
            const float* wr = a.fcW + (size_t)t*128;
            for (int k = 0; k < 128; ++k) acc += tt[k] * wr[k];
            float uv = fmaxf(acc + a.fcb[t], 0.f);
            red[t] = uv * a.sW[t];
        }
        __syncthreads();
        for (int s = 64; s > 0; s >>= 1){
            if (t < s) red[t] += red[t + s];
            __syncthreads();
        }
        if (t == 0){
            float logit = red[0] + a.sb[0];
            a.outp[b] = 1.f / (1.f + expf(-logit));
        }
    }
}

extern "C" void kernel_launch(void* const* d_in, const int* in_sizes, int n_in,
                              void* d_out, int out_size, void* d_ws, size_t ws_size,
                              hipStream_t stream)
{
    (void)in_sizes; (void)n_in; (void)out_size; (void)ws_size;
    const float* herg_em = (const float*)d_in[0];
    const float* x_in    = (const float*)d_in[1];
    const float* convW[4] = {(const float*)d_in[4], (const float*)d_in[6], (const float*)d_in[8], (const float*)d_in[10]};
    const float* convB[4] = {(const float*)d_in[5], (const float*)d_in[7], (const float*)d_in[9], (const float*)d_in[11]};
    const float* lin1W = (const float*)d_in[12]; const float* lin1b = (const float*)d_in[13];
    const float* lin2W = (const float*)d_in[14]; const float* lin2b = (const float*)d_in[15];
    const float* S1    = (const float*)d_in[16];
    const float* p1fqW = (const float*)d_in[17]; const float* p1fqb = (const float*)d_in[18];
    const float* p1kW  = (const float*)d_in[19]; const float* p1kb  = (const float*)d_in[20];
    const float* p1vW  = (const float*)d_in[21]; const float* p1vb  = (const float*)d_in[22];
    const float* p1foW = (const float*)d_in[23]; const float* p1fob = (const float*)d_in[24];
    const float* sfqW  = (const float*)d_in[25]; const float* sfqb  = (const float*)d_in[26];
    const float* skW   = (const float*)d_in[27]; const float* skb   = (const float*)d_in[28];
    const float* svW   = (const float*)d_in[29]; const float* svb   = (const float*)d_in[30];
    const float* sfoW  = (const float*)d_in[31]; const float* sfob  = (const float*)d_in[32];
    const float* p2fqW = (const float*)d_in[33]; const float* p2fqb = (const float*)d_in[34];
    const float* p2kW  = (const float*)d_in[35]; const float* p2kb  = (const float*)d_in[36];
    const float* p2vW  = (const float*)d_in[37]; const float* p2vb  = (const float*)d_in[38];
    const float* p2foW = (const float*)d_in[39]; const float* p2fob = (const float*)d_in[40];
    const float* S2    = (const float*)d_in[41];
    const float* hlW   = (const float*)d_in[42]; const float* hlb   = (const float*)d_in[43];
    const float* hoW   = (const float*)d_in[44]; const float* hob   = (const float*)d_in[45];
    const float* fcW   = (const float*)d_in[46]; const float* fcb   = (const float*)d_in[47];
    const float* sW    = (const float*)d_in[48]; const float* sb    = (const float*)d_in[49];
    const int*  ei    = (const int*)d_in[50];
    const int*  esrc  = ei;
    const int*  edst  = ei + NE;
    float* outp = (float*)d_out;

    // -------- workspace layout (byte offsets, 16B-aligned) --------
    char* WS = (char*)d_ws;
    int*   counts = (int*)(WS + 0);
    int*   cursor = (int*)(WS + 400384);
    int*   row_st = (int*)(WS + 800768);
    int*   bSums  = (int*)(WS + 1201152);
    int*   bOff   = (int*)(WS + 1203200);
    float* dinv   = (float*)(WS + 1205248);
    float* selfc  = (float*)(WS + 1605632);
    int*   srcs_s = (int*)(WS + 2005632);
    float* ce_s   = (float*)(WS + 3605632);
    ushort_t* wbf = (ushort_t*)(WS + 5205632); // 17*16384
    ushort_t* w0bf= (ushort_t*)(WS + 5762688);
    ushort_t* s1bf= (ushort_t*)(WS + 5779072);
    ushort_t* s2bf= (ushort_t*)(WS + 5798272);
    ushort_t* q0  = (ushort_t*)(WS + 5798528);
    ushort_t* q2  = (ushort_t*)(WS + 5817728);
    float* hergv  = (float*)(WS + 5817984);
    ushort_t* xb64= (ushort_t*)(WS + 6074496); // NN*64 bf16 padded raw x
    ushort_t* b0  = (ushort_t*)(WS + 18874496);// NN*128
    ushort_t* b1  = (ushort_t*)(WS + 44474496);
    ushort_t* b2  = (ushort_t*)(WS + 70074496);
    ushort_t* xA  = (ushort_t*)(WS + 95674496);   // 37504*128

    const int gN   = (NN + 255)/256;       // 391
    const int gE   = (NE + 255)/256;       // 1563
    const int gC   = (NN + 31)/32;         // 3125

    // ---- merged weight/input conversions + counts zeroing (1 launch, FIRST) ----
    CvtArgs ca;
    ca.w[0]=convW[1]; ca.w[1]=convW[2]; ca.w[2]=convW[3]; ca.w[3]=lin1W; ca.w[4]=lin2W;
    ca.w[5]=p1kW; ca.w[6]=p1vW; ca.w[7]=p1foW;
    ca.w[8]=sfqW; ca.w[9]=skW; ca.w[10]=svW; ca.w[11]=sfoW;
    ca.w[12]=p2kW; ca.w[13]=p2vW; ca.w[14]=p2foW; ca.w[15]=p1fqW; ca.w[16]=p2fqW;
    ca.w0 = convW[0]; ca.s1 = S1; ca.s2 = S2; ca.x37 = x_in;
    const int cvtTotal = CVT_W + CVT_W0 + CVT_S1 + CVT_S2 + CVT_X;
    k_cvt_all<<<(cvtTotal + 255)/256, 256, 0, stream>>>(ca, wbf, w0bf, s1bf, s2bf, xb64, counts);

    // ---- CSR build ----
    k_hist  <<<gE, 256, 0, stream>>>(counts, edst, NE);
    k_scan1 <<<gN, 256, 0, stream>>>(counts, row_st, bSums, dinv, selfc, NN);
    k_scan2 <<<1, 512, 0, stream>>>(bSums, bOff, gN);
    k_scan3 <<<gN, 256, 0, stream>>>(row_st, cursor, bOff, NN, NE);
    k_fillcsr<<<gE, 256, 0, stream>>>(esrc, edst, dinv, cursor, srcs_s, ce_s, NE);

    // ---- seed-Q projections + hERG (1 launch, 4 blocks) ----
    k_seedq<<<4, 256, 0, stream>>>(s1bf, s2bf, wbf + (size_t)15*16384, p1fqb,
                                   wbf + (size_t)16*16384, p2fqb, q0, q2,
                                   herg_em, hlW, hlb, hergv);

    // ---- conv0 (fused gather64 + GEMM) -> b0 ----
    k_conv0b<<<gC, 256, 0, stream>>>(xb64, row_st, srcs_s, ce_s, selfc, w0bf, convB[0], b0);
    // ---- conv1, conv2 ----
    k_conv_fused3<8,1,0,8><<<gC, 256, 0, stream>>>(b0, row_st, srcs_s, ce_s, selfc,
        wbf + (size_t)0*16384, convB[1], nullptr, nullptr, nullptr, b1, nullptr);
    k_conv_fused3<8,1,0,8><<<gC, 256, 0, stream>>>(b1, row_st, srcs_s, ce_s, selfc,
        wbf + (size_t)1*16384, convB[2], nullptr, nullptr, nullptr, b0, nullptr);
    // ---- conv3 + lin1 fused -> hx in b1 ----
    k_conv_fused3<8,1,1,8><<<gC, 256, 0, stream>>>(b0, row_st, srcs_s, ce_s, selfc,
        wbf + (size_t)2*16384, convB[3], nullptr, wbf + (size_t)3*16384, lin1b, b1, nullptr);
    // ---- pma1 K,V: fused shared-gather + dual GEMM, HEAD-MAJOR out (K->b2, V->b0) ----
    k_conv_fused3<16,0,0,4><<<gC, 256, 0, stream>>>(b1, row_st, srcs_s, ce_s, selfc,
        wbf + (size_t)5*16384, p1kb, p1vb, nullptr, nullptr, b2, b0);
    // ---- GMPool_G attention (head-major K/V) -> xA ----
    k_attn_mfma<200,1><<<NB*4, 256, 0, stream>>>(q0, 0, b2, b0, xA, NS);

    // ---- per-graph tail: p1fo rFF + SAB + PMA2 + head MLP -> out (1 launch) ----
    TailArgs ta;
    ta.xA = xA; ta.q2 = q2;
    ta.p1foW = wbf + (size_t)7*16384;  ta.p1fob = p1fob;
    ta.sfqW  = wbf + (size_t)8*16384;  ta.sfqb  = sfqb;
    ta.skW   = wbf + (size_t)9*16384;  ta.skb   = skb;
    ta.svW   = wbf + (size_t)10*16384; ta.svb   = svb;
    ta.sfoW  = wbf + (size_t)11*16384; ta.sfob  = sfob;
    ta.p2kW  = wbf + (size_t)12*16384; ta.p2kb  = p2kb;
    ta.p2vW  = wbf + (size_t)13*16384; ta.p2vb  = p2vb;
    ta.p2foW = wbf + (size_t)14*16384; ta.p2fob = p2fob;
    ta.lin2W = wbf + (size_t)4*16384;  ta.lin2b = lin2b;
    ta.hergv = hergv;
    ta.hoW = hoW; ta.hob = hob;
    ta.fcW = fcW; ta.fcb = fcb;
    ta.sW = sW; ta.sb = sb;
    ta.outp = outp;
    k_graph_tail<<<NB, 256, 0, stream>>>(ta);
}

// Round 10
// 693.631 us; speedup vs baseline: 2.3054x; 1.0549x over previous
//
#include <hip/hip_runtime.h>
#include <hip/hip_bf16.h>

typedef unsigned short ushort_t;
typedef unsigned int uint_t;
typedef __attribute__((ext_vector_type(8))) short short8;
typedef __attribute__((ext_vector_type(4))) float float4v;

static constexpr int NN  = 100000;   // nodes
static constexpr int NE  = 400000;   // edges
static constexpr int NB  = 500;      // graphs
static constexpr int NS  = 75;       // seeds
static constexpr int H   = 128;
static constexpr float SCALE = 0.08838834764831845f; // 1/sqrt(128)

union U32 { uint_t u; float f; };
__device__ __forceinline__ float bf2f(ushort_t b){ U32 t; t.u = ((uint_t)b) << 16; return t.f; }
__device__ __forceinline__ ushort_t f2bf(float f){
    U32 t; t.f = f;
    uint_t r = t.u + 0x7fffu + ((t.u >> 16) & 1u);   // RNE
    return (ushort_t)(r >> 16);
}
__device__ __forceinline__ void fma8(float* a, uint4 u, float c){
    a[0] += c * bf2f((ushort_t)(u.x & 0xffff)); a[1] += c * bf2f((ushort_t)(u.x >> 16));
    a[2] += c * bf2f((ushort_t)(u.y & 0xffff)); a[3] += c * bf2f((ushort_t)(u.y >> 16));
    a[4] += c * bf2f((ushort_t)(u.z & 0xffff)); a[5] += c * bf2f((ushort_t)(u.z >> 16));
    a[6] += c * bf2f((ushort_t)(u.w & 0xffff)); a[7] += c * bf2f((ushort_t)(u.w >> 16));
}

// ================= CSR build =================
__global__ void k_hist(int* counts, const int* __restrict__ dst, int e){
    int i = blockIdx.x*256 + threadIdx.x;
    if (i < e) atomicAdd(&counts[dst[i]], 1);
}
// scan + degree norms fused
__global__ __launch_bounds__(256) void k_scan1(const int* __restrict__ counts,
    int* __restrict__ row_start, int* __restrict__ blockSums,
    float* __restrict__ dinv, float* __restrict__ selfc, int n){
    __shared__ int s[256];
    int t = threadIdx.x, i = blockIdx.x*256 + t;
    int v = (i < n) ? counts[i] : 0;
    s[t] = v; __syncthreads();
    #pragma unroll
    for (int off = 1; off < 256; off <<= 1){
        int add = (t >= off) ? s[t-off] : 0;
        __syncthreads();
        s[t] += add;
        __syncthreads();
    }
    if (i < n){
        row_start[i] = s[t] - v;
        float r = rsqrtf(1.f + (float)v);
        dinv[i] = r; selfc[i] = r*r;
    }
    if (t == 255) blockSums[blockIdx.x] = s[255];
}
__global__ __launch_bounds__(512) void k_scan2(const int* __restrict__ blockSums,
    int* __restrict__ blockOff, int nb){
    __shared__ int s[512];
    int t = threadIdx.x;
    int v = (t < nb) ? blockSums[t] : 0;
    s[t] = v; __syncthreads();
    #pragma unroll
    for (int off = 1; off < 512; off <<= 1){
        int add = (t >= off) ? s[t-off] : 0;
        __syncthreads();
        s[t] += add;
        __syncthreads();
    }
    blockOff[t] = s[t] - v;
}
__global__ void k_scan3(int* __restrict__ row_start, int* __restrict__ cursor,
                        const int* __restrict__ blockOff, int n, int total){
    int i = blockIdx.x*256 + threadIdx.x;
    if (i < n){
        int v = row_start[i] + blockOff[i >> 8];
        row_start[i] = v; cursor[i] = v;
    }
    if (i == 0) row_start[n] = total;
}
__global__ void k_fillcsr(const int* __restrict__ src, const int* __restrict__ dst,
    const float* __restrict__ dinv, int* cursor,
    int* __restrict__ srcs_s, float* __restrict__ ce_s, int e){
    int i = blockIdx.x*256 + threadIdx.x;
    if (i < e){
        int d = dst[i], s = src[i];
        int p = atomicAdd(&cursor[d], 1);
        srcs_s[p] = s;
        ce_s[p] = dinv[s] * dinv[d];
    }
}

// ================= merged conversions (+ counts zeroing) =================
struct CvtArgs { const float* w[17]; const float* w0; const float* s1; const float* s2; const float* x37; };
static constexpr int CVT_W   = 17*16384;
static constexpr int CVT_W0  = 8192;
static constexpr int CVT_S1  = 9600;
static constexpr int CVT_S2  = 128;
static constexpr int CVT_X   = NN*64;
__global__ void k_cvt_all(CvtArgs a, ushort_t* __restrict__ wbf, ushort_t* __restrict__ w0bf,
                          ushort_t* __restrict__ s1bf, ushort_t* __restrict__ s2bf,
                          ushort_t* __restrict__ xb64, int* __restrict__ counts){
    int i = blockIdx.x*256 + threadIdx.x;
    if (i < NN) counts[i] = 0;                       // folded k_zero_i
    if (i < CVT_W){ int idx = i >> 14, off = i & 16383; wbf[i] = f2bf(a.w[idx][off]); return; }
    i -= CVT_W;
    if (i < CVT_W0){ int r = i >> 6, c = i & 63; w0bf[i] = (c < 37) ? f2bf(a.w0[r*37 + c]) : (ushort_t)0; return; }
    i -= CVT_W0;
    if (i < CVT_S1){ s1bf[i] = f2bf(a.s1[i]); return; }
    i -= CVT_S1;
    if (i < CVT_S2){ s2bf[i] = f2bf(a.s2[i]); return; }
    i -= CVT_S2;
    if (i < CVT_X){ int r = i >> 6, c = i & 63; xb64[i] = (c < 37) ? f2bf(a.x37[(size_t)r*37 + c]) : (ushort_t)0; return; }
}

// ========== seed-Q projections + hERG fused ==========
__global__ __launch_bounds__(256) void k_seedq(
    const ushort_t* __restrict__ s1bf, const ushort_t* __restrict__ s2bf,
    const ushort_t* __restrict__ W1, const float* __restrict__ bias1,
    const ushort_t* __restrict__ W2q, const float* __restrict__ bias2,
    ushort_t* __restrict__ q0, ushort_t* __restrict__ q2,
    const float* __restrict__ hem, const float* __restrict__ hlW,
    const float* __restrict__ hlb, float* __restrict__ hergv)
{
    int blk = blockIdx.x;
    int tid  = threadIdx.x;
    if (blk == 3){
        __shared__ float e[1280];
        for (int i = tid; i < 1280; i += 256) e[i] = hem[i];
        __syncthreads();
        if (tid < 128){
            float acc = 0.f;
            for (int k = 0; k < 1280; ++k) acc += e[k] * hlW[(size_t)tid*1280 + k];
            hergv[tid] = fmaxf(acc + hlb[tid], 0.f);
        }
        return;
    }
    const ushort_t* x = (blk < 2) ? s1bf : s2bf;
    const ushort_t* W = (blk < 2) ? W1 : W2q;
    const float* bias = (blk < 2) ? bias1 : bias2;
    ushort_t* out = (blk < 2) ? q0 : q2;
    int M = (blk < 2) ? NS : 1;
    int base = (blk < 2) ? blk*64 : 0;
    int wid  = tid >> 6;
    int lane = tid & 63;
    int l15  = lane & 15, quad = lane >> 4;
    int row0 = base + wid*16;
    int ar   = row0 + l15; if (ar > M-1) ar = M-1;
    const short* xr = (const short*)(x + (size_t)ar*H) + quad*8;
    float4v acc[8];
    #pragma unroll
    for (int i = 0; i < 8; ++i) acc[i] = (float4v)0.f;
    #pragma unroll
    for (int kc = 0; kc < 4; ++kc){
        short8 a = *(const short8*)(xr + kc*32);
        #pragma unroll
        for (int nt = 0; nt < 8; ++nt){
            short8 b = *(const short8*)((const short*)(W + (size_t)(nt*16 + l15)*H) + kc*32 + quad*8);
            acc[nt] = __builtin_amdgcn_mfma_f32_16x16x32_bf16(a, b, acc[nt], 0, 0, 0);
        }
    }
    #pragma unroll
    for (int nt = 0; nt < 8; ++nt){
        int c = nt*16 + l15;
        float bv = bias[c];
        #pragma unroll
        for (int reg = 0; reg < 4; ++reg){
            int r = row0 + quad*4 + reg;
            if (r >= M) continue;
            out[(size_t)r*H + c] = f2bf(acc[nt][reg] + bv);
        }
    }
}

// ========== fused gather + MFMA GEMM v3 (2-edge unroll + index prefetch) ==========
// NOUT==16 writes K/V head-major: record = 32 elems (64B) per (head-pair, node)
template<int NOUT, int RELU, int STAGE2, int MINW>
__global__ __launch_bounds__(256, MINW) void k_conv_fused3(
    const ushort_t* __restrict__ x,
    const int* __restrict__ row_st, const int* __restrict__ srcs,
    const float* __restrict__ ces, const float* __restrict__ selfc,
    const ushort_t* __restrict__ W, const float* __restrict__ bias0,
    const float* __restrict__ bias1,
    const ushort_t* __restrict__ W2, const float* __restrict__ bias2,
    ushort_t* __restrict__ out0, ushort_t* __restrict__ out1)
{
    __shared__ ushort_t As[32][136];
    __shared__ ushort_t Bs[(NOUT==16)?32:1][(NOUT==16)?136:1];
    const int tid = threadIdx.x;
    const int node = tid >> 3, qq = tid & 7;   // 8 threads/node, 16 cols each
    const int g = blockIdx.x*32 + node;
    float acc[16];
    #pragma unroll
    for (int i = 0; i < 16; ++i) acc[i] = 0.f;
    if (g < NN){
        const uint4* xr = (const uint4*)(x + (size_t)g*H + qq*16);
        float sc = selfc[g];
        uint4 u0 = xr[0], u1 = xr[1];
        fma8(acc+0, u0, sc); fma8(acc+8, u1, sc);
        int e = row_st[g], e1 = row_st[g+1];
        int sA = 0, sB = 0; float cA = 0.f, cB = 0.f;
        if (e < e1){ sA = srcs[e]; cA = ces[e]; }
        if (e + 1 < e1){ sB = srcs[e+1]; cB = ces[e+1]; }
        while (e + 2 <= e1){
            int sA2 = 0, sB2 = 0; float cA2 = 0.f, cB2 = 0.f;
            if (e + 2 < e1){ sA2 = srcs[e+2]; cA2 = ces[e+2]; }
            if (e + 3 < e1){ sB2 = srcs[e+3]; cB2 = ces[e+3]; }
            const uint4* pa = (const uint4*)(x + (size_t)sA*H + qq*16);
            const uint4* pb = (const uint4*)(x + (size_t)sB*H + qq*16);
            uint4 a0 = pa[0], a1 = pa[1];
            uint4 c0 = pb[0], c1 = pb[1];
            fma8(acc+0, a0, cA); fma8(acc+8, a1, cA);
            fma8(acc+0, c0, cB); fma8(acc+8, c1, cB);
            sA = sA2; sB = sB2; cA = cA2; cB = cB2;
            e += 2;
        }
        if (e < e1){
            const uint4* pa = (const uint4*)(x + (size_t)sA*H + qq*16);
            uint4 a0 = pa[0], a1 = pa[1];
            fma8(acc+0, a0, cA); fma8(acc+8, a1, cA);
        }
    }
    {
        uint_t* dst = (uint_t*)&As[node][qq*16];
        #pragma unroll
        for (int i = 0; i < 8; ++i)
            dst[i] = (uint_t)f2bf(acc[2*i]) | ((uint_t)f2bf(acc[2*i+1]) << 16);
    }
    __syncthreads();
    const int w = tid >> 6, lane = tid & 63, l15 = lane & 15, quad = lane >> 4;
    const int rt = w & 1;                  // row tile (16 rows)
    constexpr int NT = NOUT/2;             // col tiles per wave
    const int ct0 = (w >> 1) * NT;
    float4v o[NT];
    #pragma unroll
    for (int t = 0; t < NT; ++t) o[t] = (float4v)0.f;
    #pragma unroll
    for (int kc = 0; kc < 4; ++kc){
        short8 a = *(const short8*)(&As[rt*16 + l15][kc*32 + quad*8]);
        #pragma unroll
        for (int t = 0; t < NT; ++t){
            short8 bfr = *(const short8*)(W + (size_t)((ct0 + t)*16 + l15)*H + kc*32 + quad*8);
            o[t] = __builtin_amdgcn_mfma_f32_16x16x32_bf16(a, bfr, o[t], 0, 0, 0);
        }
    }
    __syncthreads();
    #pragma unroll
    for (int t = 0; t < NT; ++t){
        int cg = (ct0 + t)*16 + l15;
        #pragma unroll
        for (int r = 0; r < 4; ++r){
            float v;
            if (NOUT == 8 || cg < 128){
                v = o[t][r] + bias0[cg];
                if (RELU) v = fmaxf(v, 0.f);
                As[rt*16 + quad*4 + r][cg] = f2bf(v);
            } else {
                v = o[t][r] + bias1[cg - 128];
                if (RELU) v = fmaxf(v, 0.f);
                Bs[rt*16 + quad*4 + r][cg - 128] = f2bf(v);
            }
        }
    }
    __syncthreads();
    if (STAGE2){
        float4v o2[4];
        #pragma unroll
        for (int t = 0; t < 4; ++t) o2[t] = (float4v)0.f;
        const int ct2 = (w >> 1) * 4;
        #pragma unroll
        for (int kc = 0; kc < 4; ++kc){
            short8 a = *(const short8*)(&As[rt*16 + l15][kc*32 + quad*8]);
            #pragma unroll
            for (int t = 0; t < 4; ++t){
                short8 bfr = *(const short8*)(W2 + (size_t)((ct2 + t)*16 + l15)*H + kc*32 + quad*8);
                o2[t] = __builtin_amdgcn_mfma_f32_16x16x32_bf16(a, bfr, o2[t], 0, 0, 0);
            }
        }
        __syncthreads();
        #pragma unroll
        for (int t = 0; t < 4; ++t){
            int cg = (ct2 + t)*16 + l15;
            #pragma unroll
            for (int r = 0; r < 4; ++r)
                As[rt*16 + quad*4 + r][cg] = f2bf(o2[t][r] + bias2[cg]);
        }
        __syncthreads();
    }
    if (g < NN){
        if (NOUT == 16){
            size_t kb = ((size_t)(qq >> 1)*NN + (size_t)g)*32 + (size_t)(qq & 1)*16;
            ((uint4*)(out0 + kb))[0] = *(const uint4*)&As[node][qq*16];
            ((uint4*)(out0 + kb))[1] = *(const uint4*)&As[node][qq*16 + 8];
            ((uint4*)(out1 + kb))[0] = *(const uint4*)&Bs[node][qq*16];
            ((uint4*)(out1 + kb))[1] = *(const uint4*)&Bs[node][qq*16 + 8];
        } else {
            uint4* op = (uint4*)(out0 + (size_t)g*H + qq*16);
            const uint4* sp = (const uint4*)&As[node][qq*16];
            op[0] = sp[0]; op[1] = sp[1];
        }
    }
}

// ========== conv0: gather padded-64 bf16 rows + MFMA GEMM (K=64) ==========
__global__ __launch_bounds__(256, 8) void k_conv0b(
    const ushort_t* __restrict__ x,   // [NN][64] bf16
    const int* __restrict__ row_st, const int* __restrict__ srcs,
    const float* __restrict__ ces, const float* __restrict__ selfc,
    const ushort_t* __restrict__ W,   // [128][64]
    const float* __restrict__ bias,
    ushort_t* __restrict__ out)
{
    __shared__ ushort_t As[32][136];
    const int tid = threadIdx.x;
    const int node = tid >> 3, qq = tid & 7;   // 8 cols (1 uint4) each
    const int g = blockIdx.x*32 + node;
    float acc[8];
    #pragma unroll
    for (int i = 0; i < 8; ++i) acc[i] = 0.f;
    if (g < NN){
        const uint4* xr = (const uint4*)(x + (size_t)g*64 + qq*8);
        float sc = selfc[g];
        fma8(acc, xr[0], sc);
        int e = row_st[g], e1 = row_st[g+1];
        int sA = 0, sB = 0; float cA = 0.f, cB = 0.f;
        if (e < e1){ sA = srcs[e]; cA = ces[e]; }
        if (e + 1 < e1){ sB = srcs[e+1]; cB = ces[e+1]; }
        while (e + 2 <= e1){
            int sA2 = 0, sB2 = 0; float cA2 = 0.f, cB2 = 0.f;
            if (e + 2 < e1){ sA2 = srcs[e+2]; cA2 = ces[e+2]; }
            if (e + 3 < e1){ sB2 = srcs[e+3]; cB2 = ces[e+3]; }
            uint4 a0 = *(const uint4*)(x + (size_t)sA*64 + qq*8);
            uint4 c0 = *(const uint4*)(x + (size_t)sB*64 + qq*8);
            fma8(acc, a0, cA);
            fma8(acc, c0, cB);
            sA = sA2; sB = sB2; cA = cA2; cB = cB2;
            e += 2;
        }
        if (e < e1){
            uint4 a0 = *(const uint4*)(x + (size_t)sA*64 + qq*8);
            fma8(acc, a0, cA);
        }
    }
    {
        uint_t* dst = (uint_t*)&As[node][qq*8];
        #pragma unroll
        for (int i = 0; i < 4; ++i)
            dst[i] = (uint_t)f2bf(acc[2*i]) | ((uint_t)f2bf(acc[2*i+1]) << 16);
    }
    __syncthreads();
    const int w = tid >> 6, lane = tid & 63, l15 = lane & 15, quad = lane >> 4;
    const int rt = w & 1;
    const int ct0 = (w >> 1) * 4;
    float4v o[4];
    #pragma unroll
    for (int t = 0; t < 4; ++t) o[t] = (float4v)0.f;
    #pragma unroll
    for (int kc = 0; kc < 2; ++kc){
        short8 a = *(const short8*)(&As[rt*16 + l15][kc*32 + quad*8]);
        #pragma unroll
        for (int t = 0; t < 4; ++t){
            short8 bfr = *(const short8*)(W + (size_t)((ct0 + t)*16 + l15)*64 + kc*32 + quad*8);
            o[t] = __builtin_amdgcn_mfma_f32_16x16x32_bf16(a, bfr, o[t], 0, 0, 0);
        }
    }
    __syncthreads();
    #pragma unroll
    for (int t = 0; t < 4; ++t){
        int cg = (ct0 + t)*16 + l15;
        #pragma unroll
        for (int r = 0; r < 4; ++r)
            As[rt*16 + quad*4 + r][cg] = f2bf(fmaxf(o[t][r] + bias[cg], 0.f));
    }
    __syncthreads();
    if (g < NN){
        uint4* op = (uint4*)(out + (size_t)g*H + qq*16);
        const uint4* sp = (const uint4*)&As[node][qq*16];
        op[0] = sp[0]; op[1] = sp[1];
    }
}

// ========== MFMA flash attention (GMPool_G, head-major K/V) ==========
template<int NK, int HM>
__global__ __launch_bounds__(256) void k_attn_mfma(
    const ushort_t* __restrict__ Q, int qbs,
    const ushort_t* __restrict__ K, const ushort_t* __restrict__ V,
    ushort_t* __restrict__ out, int nq)
{
    constexpr int NKT = (NK + 15) / 16;
    constexpr int NKC = (NK + 31) / 32;
    __shared__ ushort_t Ks[2][208][24];
    __shared__ ushort_t Vs[2][16][232];
    __shared__ ushort_t Ps[4][16][232];
    int b = blockIdx.x >> 2, hp = blockIdx.x & 3;
    int h0 = hp*2;
    int tid = threadIdx.x;
    {
        uint_t* p = (uint_t*)&Ps[0][0][0];
        for (int i = tid; i < 4*16*232/2; i += 256) p[i] = 0;
    }
    const ushort_t* Kb = HM ? (K + ((size_t)hp*NB + b)*NK*32)
                            : (K + (size_t)b*NK*H + h0*16);
    for (int idx = tid; idx < NK*8; idx += 256){
        int key = idx >> 3, p = idx & 7;
        int hh = p >> 2, dl = (p & 3)*4;
        const uint_t* src = HM ? (const uint_t*)(Kb + (size_t)key*32 + hh*16 + dl)
                               : (const uint_t*)(Kb + (size_t)key*H + hh*16 + dl);
        uint_t* d = (uint_t*)&Ks[hh][key][dl];
        d[0] = src[0]; d[1] = src[1];
    }
    const ushort_t* Vb = HM ? (V + ((size_t)hp*NB + b)*NK*32)
                            : (V + (size_t)b*NK*H + h0*16);
    for (int idx = tid; idx < NK*8; idx += 256){
        int key = idx >> 3, p = idx & 7;
        int hh = p >> 2, dl = (p & 3)*4;
        const ushort_t* src = HM ? (Vb + (size_t)key*32 + hh*16 + dl)
                                 : (Vb + (size_t)key*H + hh*16 + dl);
        Vs[hh][dl+0][key] = src[0];
        Vs[hh][dl+1][key] = src[1];
        Vs[hh][dl+2][key] = src[2];
        Vs[hh][dl+3][key] = src[3];
    }
    for (int idx = tid; idx < 2*16*(232-NK); idx += 256){
        int key = NK + idx % (232-NK), r = idx / (232-NK);
        Vs[r>>4][r&15][key] = 0;
    }
    __syncthreads();

    int w = tid >> 6, lane = tid & 63;
    int hh = w >> 1, half = w & 1;
    int h = h0 + hh;
    int l15 = lane & 15, quad = lane >> 4;
    bool klow = (quad < 2);
    int nqt = (nq + 15) >> 4;
    int split = (nqt + 1) >> 1;
    int qt0 = half ? split : 0;
    int qt1 = half ? nqt : split;
    for (int qt = qt0; qt < qt1; ++qt){
        int qr = qt*16 + l15; if (qr > nq-1) qr = nq-1;
        short8 av = *(const short8*)(Q + (size_t)b*qbs + (size_t)qr*H + h*16 + (quad & 1)*8);
        short8 zero8 = (short8)0;
        short8 afrag = klow ? av : zero8;
        float4v s[NKT];
        #pragma unroll
        for (int kt = 0; kt < NKT; ++kt){
            short8 bv = *(const short8*)(&Ks[hh][kt*16 + l15][(quad & 1)*8]);
            short8 bfrag = klow ? bv : zero8;
            s[kt] = __builtin_amdgcn_mfma_f32_16x16x32_bf16(afrag, bfrag, (float4v)0.f, 0, 0, 0);
        }
        float mx[4] = {-1e30f, -1e30f, -1e30f, -1e30f};
        #pragma unroll
        for (int kt = 0; kt < NKT; ++kt){
            if (kt*16 + l15 >= NK){ s[kt][0]=-1e30f; s[kt][1]=-1e30f; s[kt][2]=-1e30f; s[kt][3]=-1e30f; }
            #pragma unroll
            for (int r = 0; r < 4; ++r) mx[r] = fmaxf(mx[r], s[kt][r]);
        }
        #pragma unroll
        for (int off = 1; off < 16; off <<= 1){
            #pragma unroll
            for (int r = 0; r < 4; ++r) mx[r] = fmaxf(mx[r], __shfl_xor(mx[r], off));
        }
        float sum[4] = {0.f, 0.f, 0.f, 0.f};
        #pragma unroll
        for (int kt = 0; kt < NKT; ++kt){
            #pragma unroll
            for (int r = 0; r < 4; ++r){
                float e = __expf((s[kt][r] - mx[r]) * SCALE);
                sum[r] += e;
                Ps[w][quad*4 + r][kt*16 + l15] = f2bf(e);
            }
        }
        #pragma unroll
        for (int off = 1; off < 16; off <<= 1){
            #pragma unroll
            for (int r = 0; r < 4; ++r) sum[r] += __shfl_xor(sum[r], off);
        }
        float4v o = (float4v)0.f;
        #pragma unroll
        for (int kc = 0; kc < NKC; ++kc){
            short8 pa = *(const short8*)(&Ps[w][l15][kc*32 + quad*8]);
            short8 vb = *(const short8*)(&Vs[hh][l15][kc*32 + quad*8]);
            o = __builtin_amdgcn_mfma_f32_16x16x32_bf16(pa, vb, o, 0, 0, 0);
        }
        #pragma unroll
        for (int r = 0; r < 4; ++r){
            int row = qt*16 + quad*4 + r;
            if (row < nq){
                float qv = bf2f(Q[(size_t)b*qbs + (size_t)row*H + h*16 + l15]);
                out[((size_t)b*nq + row)*H + h*16 + l15] = f2bf(qv + o[r] / sum[r]);
            }
        }
    }
}

// ========== per-graph tail v2: p1fo rFF + SAB + PMA2 + head MLP, 2 blocks/CU ==========
// LDS: bufA [83][136] (xA->xb1 in-place; later xb2; junk rows host ps w0/w1; P6 scratch)
//      bufB [80][136] (SAB Q -> attn-out -> PMA2 V; junk rows host ps w2)
//      bufC [80][136] (SAB K -> PMA2 K; junk rows host ps w3)
//      vt4  [64][104] (SAB V^T, 4 heads per pass)                     total ~77.6 KB
struct TailArgs {
    const ushort_t* xA; const ushort_t* q2;
    const ushort_t* p1foW; const float* p1fob;
    const ushort_t* sfqW;  const float* sfqb;
    const ushort_t* skW;   const float* skb;
    const ushort_t* svW;   const float* svb;
    const ushort_t* sfoW;  const float* sfob;
    const ushort_t* p2kW;  const float* p2kb;
    const ushort_t* p2vW;  const float* p2vb;
    const ushort_t* p2foW; const float* p2fob;
    const ushort_t* lin2W; const float* lin2b;
    const float* hergv;
    const float* hoW; const float* hob;
    const float* fcW; const float* fcb;
    const float* sW;  const float* sb;
    float* outp;
};

__global__ __launch_bounds__(256, 2) void k_graph_tail(TailArgs a){
    __shared__ ushort_t bufA[83*136];
    __shared__ ushort_t bufB[80*136];
    __shared__ ushort_t bufC[80*136];
    __shared__ ushort_t vt4[64*104];
    const int b = blockIdx.x, tid = threadIdx.x;
    const int w = tid >> 6, lane = tid & 63, l15 = lane & 15, quad = lane >> 4;
    // per-wave P staging (16x32 bf16) in mask-protected junk rows (>=75)
    ushort_t* psw = (w == 0) ? bufA + 10200 :
                    (w == 1) ? bufA + 10712 :
                    (w == 2) ? bufB + 10200 : bufC + 10200;

    // P0: zero vt4; load xA rows for this graph into bufA
    for (int i = tid; i < 64*104/2; i += 256) ((uint_t*)vt4)[i] = 0u;
    {
        const ushort_t* xg = a.xA + (size_t)b*NS*H;
        for (int i = tid; i < NS*16; i += 256){
            int row = i >> 4, q = i & 15;
            *(uint4*)(bufA + row*136 + q*8) = *(const uint4*)(xg + (size_t)row*H + q*8);
        }
    }
    __syncthreads();

    // P1: bufA = xA + relu(xA @ p1foW^T + b) IN-PLACE (per-wave rt, reg-buffered)
    for (int rt = w; rt < 5; rt += 4){
        float4v o[8];
        #pragma unroll
        for (int i = 0; i < 8; ++i) o[i] = (float4v)0.f;
        #pragma unroll
        for (int kc = 0; kc < 4; ++kc){
            short8 av = *(const short8*)(bufA + (rt*16 + l15)*136 + kc*32 + quad*8);
            #pragma unroll
            for (int ct = 0; ct < 8; ++ct){
                short8 bv = *(const short8*)((const short*)(a.p1foW + (size_t)(ct*16 + l15)*H) + kc*32 + quad*8);
                o[ct] = __builtin_amdgcn_mfma_f32_16x16x32_bf16(av, bv, o[ct], 0, 0, 0);
            }
        }
        #pragma unroll
        for (int ct = 0; ct < 8; ++ct){
            int c = ct*16 + l15; float bb = a.p1fob[c];
            #pragma unroll
            for (int r = 0; r < 4; ++r){
                int row = rt*16 + quad*4 + r;
                float res = bf2f(bufA[row*136 + c]);
                bufA[row*136 + c] = f2bf(fmaxf(o[ct][r] + bb, 0.f) + res);
            }
        }
    }
    __syncthreads();

    // P2: SAB projections from bufA: Q->bufB, K->bufC
    for (int job = w; job < 40; job += 4){
        int rt = job >> 3, ct = job & 7;
        float4v o = (float4v)0.f;
        #pragma unroll
        for (int kc = 0; kc < 4; ++kc){
            short8 av = *(const short8*)(bufA + (rt*16 + l15)*136 + kc*32 + quad*8);
            short8 bv = *(const short8*)((const short*)(a.sfqW + (size_t)(ct*16 + l15)*H) + kc*32 + quad*8);
            o = __builtin_amdgcn_mfma_f32_16x16x32_bf16(av, bv, o, 0, 0, 0);
        }
        int c = ct*16 + l15; float bb = a.sfqb[c];
        #pragma unroll
        for (int r = 0; r < 4; ++r)
            bufB[(rt*16 + quad*4 + r)*136 + c] = f2bf(o[r] + bb);
    }
    for (int job = w; job < 40; job += 4){
        int rt = job >> 3, ct = job & 7;
        float4v o = (float4v)0.f;
        #pragma unroll
        for (int kc = 0; kc < 4; ++kc){
            short8 av = *(const short8*)(bufA + (rt*16 + l15)*136 + kc*32 + quad*8);
            short8 bv = *(const short8*)((const short*)(a.skW + (size_t)(ct*16 + l15)*H) + kc*32 + quad*8);
            o = __builtin_amdgcn_mfma_f32_16x16x32_bf16(av, bv, o, 0, 0, 0);
        }
        int c = ct*16 + l15; float bb = a.skb[c];
        #pragma unroll
        for (int r = 0; r < 4; ++r)
            bufC[(rt*16 + quad*4 + r)*136 + c] = f2bf(o[r] + bb);
    }
    __syncthreads();

    // P3: SAB attention, two 4-head passes (V-proj into vt4, attn in-place on bufB)
    for (int pass = 0; pass < 2; ++pass){
        int hbase = pass*4;
        // V-projection heads hbase..hbase+3 from bufA
        for (int job = w; job < 20; job += 4){
            int rt = job >> 2, ctl = job & 3;
            int ct = hbase + ctl;
            float4v o = (float4v)0.f;
            #pragma unroll
            for (int kc = 0; kc < 4; ++kc){
                short8 av = *(const short8*)(bufA + (rt*16 + l15)*136 + kc*32 + quad*8);
                short8 bv = *(const short8*)((const short*)(a.svW + (size_t)(ct*16 + l15)*H) + kc*32 + quad*8);
                o = __builtin_amdgcn_mfma_f32_16x16x32_bf16(av, bv, o, 0, 0, 0);
            }
            int c = ct*16 + l15; float bb = a.svb[c];
            #pragma unroll
            for (int r = 0; r < 4; ++r){
                int key = rt*16 + quad*4 + r;
                if (key < NS) vt4[(ctl*16 + l15)*104 + key] = f2bf(o[r] + bb);
            }
        }
        __syncthreads();
        // attention: wave w handles head hbase+w (local head w in vt4)
        {
            int hl = w, h = hbase + w;
            short8 zero8 = (short8)0;
            bool klow = (quad < 2);
            for (int qt = 0; qt < 5; ++qt){
                short8 av = *(const short8*)(bufB + (qt*16 + l15)*136 + h*16 + (quad & 1)*8);
                short8 afrag = klow ? av : zero8;
                float4v s[5];
                #pragma unroll
                for (int kt = 0; kt < 5; ++kt){
                    short8 bv = *(const short8*)(bufC + (kt*16 + l15)*136 + h*16 + (quad & 1)*8);
                    short8 bfrag = klow ? bv : zero8;
                    s[kt] = __builtin_amdgcn_mfma_f32_16x16x32_bf16(afrag, bfrag, (float4v)0.f, 0, 0, 0);
                }
                float mx[4] = {-1e30f, -1e30f, -1e30f, -1e30f};
                #pragma unroll
                for (int kt = 0; kt < 5; ++kt){
                    if (kt*16 + l15 >= NS){ s[kt][0]=-1e30f; s[kt][1]=-1e30f; s[kt][2]=-1e30f; s[kt][3]=-1e30f; }
                    #pragma unroll
                    for (int r = 0; r < 4; ++r) mx[r] = fmaxf(mx[r], s[kt][r]);
                }
                #pragma unroll
                for (int off = 1; off < 16; off <<= 1){
                    #pragma unroll
                    for (int r = 0; r < 4; ++r) mx[r] = fmaxf(mx[r], __shfl_xor(mx[r], off));
                }
                float sum[4] = {0.f, 0.f, 0.f, 0.f};
                float4v o = (float4v)0.f;
                #pragma unroll
                for (int kc = 0; kc < 3; ++kc){
                    #pragma unroll
                    for (int t2 = 0; t2 < 2; ++t2){
                        int kt = kc*2 + t2;
                        #pragma unroll
                        for (int r = 0; r < 4; ++r){
                            float e = 0.f;
                            if (kt < 5){ e = __expf((s[kt][r] - mx[r]) * SCALE); sum[r] += e; }
                            psw[(quad*4 + r)*32 + t2*16 + l15] = f2bf(e);
                        }
                    }
                    short8 pa = *(const short8*)(psw + l15*32 + quad*8);
                    short8 vb = *(const short8*)(vt4 + (hl*16 + l15)*104 + kc*32 + quad*8);
                    o = __builtin_amdgcn_mfma_f32_16x16x32_bf16(pa, vb, o, 0, 0, 0);
                }
                #pragma unroll
                for (int off = 1; off < 16; off <<= 1){
                    #pragma unroll
                    for (int r = 0; r < 4; ++r) sum[r] += __shfl_xor(sum[r], off);
                }
                #pragma unroll
                for (int r = 0; r < 4; ++r){
                    int row = qt*16 + quad*4 + r;
                    if (row < NS){
                        float qv = bf2f(bufB[row*136 + h*16 + l15]);
                        bufB[row*136 + h*16 + l15] = f2bf(qv + o[r] / sum[r]);
                    }
                }
            }
        }
        __syncthreads();
    }

    // P4: xb2 = attnout(bufB) + relu(attnout @ sfoW^T + b) -> bufA (xb1 dead)
    for (int job = w; job < 40; job += 4){
        int rt = job >> 3, ct = job & 7;
        float4v o = (float4v)0.f;
        #pragma unroll
        for (int kc = 0; kc < 4; ++kc){
            short8 av = *(const short8*)(bufB + (rt*16 + l15)*136 + kc*32 + quad*8);
            short8 bv = *(const short8*)((const short*)(a.sfoW + (size_t)(ct*16 + l15)*H) + kc*32 + quad*8);
            o = __builtin_amdgcn_mfma_f32_16x16x32_bf16(av, bv, o, 0, 0, 0);
        }
        int c = ct*16 + l15; float bb = a.sfob[c];
        #pragma unroll
        for (int r = 0; r < 4; ++r){
            int row = rt*16 + quad*4 + r;
            bufA[row*136 + c] = f2bf(fmaxf(o[r] + bb, 0.f) + bf2f(bufB[row*136 + c]));
        }
    }
    __syncthreads();

    // P5: PMA2 K -> bufC, V -> bufB (from bufA = xb2)
    for (int job = w; job < 40; job += 4){
        int rt = job >> 3, ct = job & 7;
        float4v o = (float4v)0.f;
        #pragma unroll
        for (int kc = 0; kc < 4; ++kc){
            short8 av = *(const short8*)(bufA + (rt*16 + l15)*136 + kc*32 + quad*8);
            short8 bv = *(const short8*)((const short*)(a.p2kW + (size_t)(ct*16 + l15)*H) + kc*32 + quad*8);
            o = __builtin_amdgcn_mfma_f32_16x16x32_bf16(av, bv, o, 0, 0, 0);
        }
        int c = ct*16 + l15; float bb = a.p2kb[c];
        #pragma unroll
        for (int r = 0; r < 4; ++r)
            bufC[(rt*16 + quad*4 + r)*136 + c] = f2bf(o[r] + bb);
    }
    for (int job = w; job < 40; job += 4){
        int rt = job >> 3, ct = job & 7;
        float4v o = (float4v)0.f;
        #pragma unroll
        for (int kc = 0; kc < 4; ++kc){
            short8 av = *(const short8*)(bufA + (rt*16 + l15)*136 + kc*32 + quad*8);
            short8 bv = *(const short8*)((const short*)(a.p2vW + (size_t)(ct*16 + l15)*H) + kc*32 + quad*8);
            o = __builtin_amdgcn_mfma_f32_16x16x32_bf16(av, bv, o, 0, 0, 0);
        }
        int c = ct*16 + l15; float bb = a.p2vb[c];
        #pragma unroll
        for (int r = 0; r < 4; ++r)
            bufB[(rt*16 + quad*4 + r)*136 + c] = f2bf(o[r] + bb);
    }
    __syncthreads();

    // P6: 1-seed attention + p2fo residual + lin2 + head MLP (scratch aliases bufA)
    {
        int t = tid;
        char* sb8 = (char*)bufA;
        float* sc       = (float*)sb8;              // 8*76 floats
        float* sumh     = (float*)(sb8 + 2432);     // 8
        ushort_t* xa    = (ushort_t*)(sb8 + 2464);  // 128
        ushort_t* xb3   = (ushort_t*)(sb8 + 2720);  // 128
        float* tt       = (float*)(sb8 + 2976);     // 128
        float* v256     = (float*)(sb8 + 3488);     // 256
        float* red      = (float*)(sb8 + 4512);     // 128
        {
            int h = t >> 5, l32 = t & 31;
            const ushort_t* qr = a.q2 + h*16;
            for (int k = l32; k < NS; k += 32){
                float s = 0.f;
                #pragma unroll
                for (int d = 0; d < 16; ++d) s += bf2f(qr[d]) * bf2f(bufC[k*136 + h*16 + d]);
                sc[h*76 + k] = s;
            }
        }
        __syncthreads();
        if (t < 128){
            int hh = t >> 4, i = t & 15;
            float mx = -1e30f;
            for (int k = i; k < NS; k += 16) mx = fmaxf(mx, sc[hh*76 + k]);
            #pragma unroll
            for (int off = 1; off < 16; off <<= 1) mx = fmaxf(mx, __shfl_xor(mx, off));
            float sm = 0.f;
            for (int k = i; k < NS; k += 16){
                float e = __expf((sc[hh*76 + k] - mx) * SCALE);
                sc[hh*76 + k] = e;
                sm += e;
            }
            #pragma unroll
            for (int off = 1; off < 16; off <<= 1) sm += __shfl_xor(sm, off);
            if (i == 0) sumh[hh] = sm;
        }
        __syncthreads();
        if (t < 128){
            int hh = t >> 4;
            float o = 0.f;
            for (int k = 0; k < NS; ++k) o += sc[hh*76 + k] * bf2f(bufB[k*136 + t]);
            xa[t] = f2bf(bf2f(a.q2[t]) + o / sumh[hh]);
        }
        __syncthreads();
        if (t < 128){
            float acc = 0.f;
            const ushort_t* wr = a.p2foW + (size_t)t*H;
            for (int k = 0; k < H; ++k) acc += bf2f(xa[k]) * bf2f(wr[k]);
            xb3[t] = f2bf(fmaxf(acc + a.p2fob[t], 0.f) + bf2f(xa[t]));
        }
        __syncthreads();
        if (t < 128){
            float acc = 0.f;
            const ushort_t* wr = a.lin2W + (size_t)t*H;
            for (int k = 0; k < H; ++k) acc += bf2f(xb3[k]) * bf2f(wr[k]);
            v256[t] = acc + a.lin2b[t];
            v256[128 + t] = a.hergv[t];
        }
        __syncthreads();
        if (t < 128){
            float acc = 0.f;
            const float* wr = a.hoW + (size_t)t*256;
            for (int k = 0; k < 256; ++k) acc += v256[k] * wr[k];
            tt[t] = fmaxf(acc + a.hob[t], 0.f);
        }
        __syncthreads();
        if (t < 128){
            float acc = 0.f;
            const float* wr = a.fcW + (size_t)t*128;
            for (int k = 0; k < 128; ++k) acc += tt[k] * wr[k];
            float uv = fmaxf(acc + a.fcb[t], 0.f);
            red[t] = uv * a.sW[t];
        }
        __syncthreads();
        for (int s = 64; s > 0; s >>= 1){
            if (t < s) red[t] += red[t + s];
            __syncthreads();
        }
        if (t == 0){
            float logit = red[0] + a.sb[0];
            a.outp[b] = 1.f / (1.f + expf(-logit));
        }
    }
}

extern "C" void kernel_launch(void* const* d_in, const int* in_sizes, int n_in,
                              void* d_out, int out_size, void* d_ws, size_t ws_size,
                              hipStream_t stream)
{
    (void)in_sizes; (void)n_in; (void)out_size; (void)ws_size;
    const float* herg_em = (const float*)d_in[0];
    const float* x_in    = (const float*)d_in[1];
    const float* convW[4] = {(const float*)d_in[4], (const float*)d_in[6], (const float*)d_in[8], (const float*)d_in[10]};
    const float* convB[4] = {(const float*)d_in[5], (const float*)d_in[7], (const float*)d_in[9], (const float*)d_in[11]};
    const float* lin1W = (const float*)d_in[12]; const float* lin1b = (const float*)d_in[13];
    const float* lin2W = (const float*)d_in[14]; const float* lin2b = (const float*)d_in[15];
    const float* S1    = (const float*)d_in[16];
    const float* p1fqW = (const float*)d_in[17]; const float* p1fqb = (const float*)d_in[18];
    const float* p1kW  = (const float*)d_in[19]; const float* p1kb  = (const float*)d_in[20];
    const float* p1vW  = (const float*)d_in[21]; const float* p1vb  = (const float*)d_in[22];
    const float* p1foW = (const float*)d_in[23]; const float* p1fob = (const float*)d_in[24];
    const float* sfqW  = (const float*)d_in[25]; const float* sfqb  = (const float*)d_in[26];
    const float* skW   = (const float*)d_in[27]; const float* skb   = (const float*)d_in[28];
    const float* svW   = (const float*)d_in[29]; const float* svb   = (const float*)d_in[30];
    const float* sfoW  = (const float*)d_in[31]; const float* sfob  = (const float*)d_in[32];
    const float* p2fqW = (const float*)d_in[33]; const float* p2fqb = (const float*)d_in[34];
    const float* p2kW  = (const float*)d_in[35]; const float* p2kb  = (const float*)d_in[36];
    const float* p2vW  = (const float*)d_in[37]; const float* p2vb  = (const float*)d_in[38];
    const float* p2foW = (const float*)d_in[39]; const float* p2fob = (const float*)d_in[40];
    const float* S2    = (const float*)d_in[41];
    const float* hlW   = (const float*)d_in[42]; const float* hlb   = (const float*)d_in[43];
    const float* hoW   = (const float*)d_in[44]; const float* hob   = (const float*)d_in[45];
    const float* fcW   = (const float*)d_in[46]; const float* fcb   = (const float*)d_in[47];
    const float* sW    = (const float*)d_in[48]; const float* sb    = (const float*)d_in[49];
    const int*  ei    = (const int*)d_in[50];
    const int*  esrc  = ei;
    const int*  edst  = ei + NE;
    float* outp = (float*)d_out;

    // -------- workspace layout (byte offsets, 16B-aligned) --------
    char* WS = (char*)d_ws;
    int*   counts = (int*)(WS + 0);
    int*   cursor = (int*)(WS + 400384);
    int*   row_st = (int*)(WS + 800768);
    int*   bSums  = (int*)(WS + 1201152);
    int*   bOff   = (int*)(WS + 1203200);
    float* dinv   = (float*)(WS + 1205248);
    float* selfc  = (float*)(WS + 1605632);
    int*   srcs_s = (int*)(WS + 2005632);
    float* ce_s   = (float*)(WS + 3605632);
    ushort_t* wbf = (ushort_t*)(WS + 5205632); // 17*16384
    ushort_t* w0bf= (ushort_t*)(WS + 5762688);
    ushort_t* s1bf= (ushort_t*)(WS + 5779072);
    ushort_t* s2bf= (ushort_t*)(WS + 5798272);
    ushort_t* q0  = (ushort_t*)(WS + 5798528);
    ushort_t* q2  = (ushort_t*)(WS + 5817728);
    float* hergv  = (float*)(WS + 5817984);
    ushort_t* xb64= (ushort_t*)(WS + 6074496); // NN*64 bf16 padded raw x
    ushort_t* b0  = (ushort_t*)(WS + 18874496);// NN*128
    ushort_t* b1  = (ushort_t*)(WS + 44474496);
    ushort_t* b2  = (ushort_t*)(WS + 70074496);
    ushort_t* xA  = (ushort_t*)(WS + 95674496);   // 37504*128

    const int gN   = (NN + 255)/256;       // 391
    const int gE   = (NE + 255)/256;       // 1563
    const int gC   = (NN + 31)/32;         // 3125

    // ---- merged weight/input conversions + counts zeroing (1 launch, FIRST) ----
    CvtArgs ca;
    ca.w[0]=convW[1]; ca.w[1]=convW[2]; ca.w[2]=convW[3]; ca.w[3]=lin1W; ca.w[4]=lin2W;
    ca.w[5]=p1kW; ca.w[6]=p1vW; ca.w[7]=p1foW;
    ca.w[8]=sfqW; ca.w[9]=skW; ca.w[10]=svW; ca.w[11]=sfoW;
    ca.w[12]=p2kW; ca.w[13]=p2vW; ca.w[14]=p2foW; ca.w[15]=p1fqW; ca.w[16]=p2fqW;
    ca.w0 = convW[0]; ca.s1 = S1; ca.s2 = S2; ca.x37 = x_in;
    const int cvtTotal = CVT_W + CVT_W0 + CVT_S1 + CVT_S2 + CVT_X;
    k_cvt_all<<<(cvtTotal + 255)/256, 256, 0, stream>>>(ca, wbf, w0bf, s1bf, s2bf, xb64, counts);

    // ---- CSR build ----
    k_hist  <<<gE, 256, 0, stream>>>(counts, edst, NE);
    k_scan1 <<<gN, 256, 0, stream>>>(counts, row_st, bSums, dinv, selfc, NN);
    k_scan2 <<<1, 512, 0, stream>>>(bSums, bOff, gN);
    k_scan3 <<<gN, 256, 0, stream>>>(row_st, cursor, bOff, NN, NE);
    k_fillcsr<<<gE, 256, 0, stream>>>(esrc, edst, dinv, cursor, srcs_s, ce_s, NE);

    // ---- seed-Q projections + hERG (1 launch, 4 blocks) ----
    k_seedq<<<4, 256, 0, stream>>>(s1bf, s2bf, wbf + (size_t)15*16384, p1fqb,
                                   wbf + (size_t)16*16384, p2fqb, q0, q2,
                                   herg_em, hlW, hlb, hergv);

    // ---- conv0 (fused gather64 + GEMM) -> b0 ----
    k_conv0b<<<gC, 256, 0, stream>>>(xb64, row_st, srcs_s, ce_s, selfc, w0bf, convB[0], b0);
    // ---- conv1, conv2 ----
    k_conv_fused3<8,1,0,8><<<gC, 256, 0, stream>>>(b0, row_st, srcs_s, ce_s, selfc,
        wbf + (size_t)0*16384, convB[1], nullptr, nullptr, nullptr, b1, nullptr);
    k_conv_fused3<8,1,0,8><<<gC, 256, 0, stream>>>(b1, row_st, srcs_s, ce_s, selfc,
        wbf + (size_t)1*16384, convB[2], nullptr, nullptr, nullptr, b0, nullptr);
    // ---- conv3 + lin1 fused -> hx in b1 ----
    k_conv_fused3<8,1,1,8><<<gC, 256, 0, stream>>>(b0, row_st, srcs_s, ce_s, selfc,
        wbf + (size_t)2*16384, convB[3], nullptr, wbf + (size_t)3*16384, lin1b, b1, nullptr);
    // ---- pma1 K,V: fused shared-gather + dual GEMM, HEAD-MAJOR out (K->b2, V->b0) ----
    k_conv_fused3<16,0,0,4><<<gC, 256, 0, stream>>>(b1, row_st, srcs_s, ce_s, selfc,
        wbf + (size_t)5*16384, p1kb, p1vb, nullptr, nullptr, b2, b0);
    // ---- GMPool_G attention (head-major K/V) -> xA ----
    k_attn_mfma<200,1><<<NB*4, 256, 0, stream>>>(q0, 0, b2, b0, xA, NS);

    // ---- per-graph tail v2: p1fo rFF + SAB + PMA2 + head MLP -> out (1 launch) ----
    TailArgs ta;
    ta.xA = xA; ta.q2 = q2;
    ta.p1foW = wbf + (size_t)7*16384;  ta.p1fob = p1fob;
    ta.sfqW  = wbf + (size_t)8*16384;  ta.sfqb  = sfqb;
    ta.skW   = wbf + (size_t)9*16384;  ta.skb   = skb;
    ta.svW   = wbf + (size_t)10*16384; ta.svb   = svb;
    ta.sfoW  = wbf + (size_t)11*16384; ta.sfob  = sfob;
    ta.p2kW  = wbf + (size_t)12*16384; ta.p2kb  = p2kb;
    ta.p2vW  = wbf + (size_t)13*16384; ta.p2vb  = p2vb;
    ta.p2foW = wbf + (size_t)14*16384; ta.p2fob = p2fob;
    ta.lin2W = wbf + (size_t)4*16384;  ta.lin2b = lin2b;
    ta.hergv = hergv;
    ta.hoW = hoW; ta.hob = hob;
    ta.fcW = fcW; ta.fcb = fcb;
    ta.sW = sW; ta.sb = sb;
    ta.outp = outp;
    k_graph_tail<<<NB, 256, 0, stream>>>(ta);
}

// Round 11
// 655.143 us; speedup vs baseline: 2.4408x; 1.0587x over previous
//
#include <hip/hip_runtime.h>
#include <hip/hip_bf16.h>

typedef unsigned short ushort_t;
typedef unsigned int uint_t;
typedef __attribute__((ext_vector_type(8))) short short8;
typedef __attribute__((ext_vector_type(4))) float float4v;

static constexpr int NN  = 100000;   // nodes
static constexpr int NE  = 400000;   // edges
static constexpr int NB  = 500;      // graphs
static constexpr int NS  = 75;       // seeds
static constexpr int H   = 128;
static constexpr float SCALE = 0.08838834764831845f; // 1/sqrt(128)

union U32 { uint_t u; float f; };
__device__ __forceinline__ float bf2f(ushort_t b){ U32 t; t.u = ((uint_t)b) << 16; return t.f; }
__device__ __forceinline__ ushort_t f2bf(float f){
    U32 t; t.f = f;
    uint_t r = t.u + 0x7fffu + ((t.u >> 16) & 1u);   // RNE
    return (ushort_t)(r >> 16);
}
__device__ __forceinline__ void fma8(float* a, uint4 u, float c){
    a[0] += c * bf2f((ushort_t)(u.x & 0xffff)); a[1] += c * bf2f((ushort_t)(u.x >> 16));
    a[2] += c * bf2f((ushort_t)(u.y & 0xffff)); a[3] += c * bf2f((ushort_t)(u.y >> 16));
    a[4] += c * bf2f((ushort_t)(u.z & 0xffff)); a[5] += c * bf2f((ushort_t)(u.z >> 16));
    a[6] += c * bf2f((ushort_t)(u.w & 0xffff)); a[7] += c * bf2f((ushort_t)(u.w >> 16));
}

// ================= CSR build =================
__global__ void k_hist(int* counts, const int* __restrict__ dst, int e){
    int i = blockIdx.x*256 + threadIdx.x;
    if (i < e) atomicAdd(&counts[dst[i]], 1);
}
// scan + degree norms fused
__global__ __launch_bounds__(256) void k_scan1(const int* __restrict__ counts,
    int* __restrict__ row_start, int* __restrict__ blockSums,
    float* __restrict__ dinv, float* __restrict__ selfc, int n){
    __shared__ int s[256];
    int t = threadIdx.x, i = blockIdx.x*256 + t;
    int v = (i < n) ? counts[i] : 0;
    s[t] = v; __syncthreads();
    #pragma unroll
    for (int off = 1; off < 256; off <<= 1){
        int add = (t >= off) ? s[t-off] : 0;
        __syncthreads();
        s[t] += add;
        __syncthreads();
    }
    if (i < n){
        row_start[i] = s[t] - v;
        float r = rsqrtf(1.f + (float)v);
        dinv[i] = r; selfc[i] = r*r;
    }
    if (t == 255) blockSums[blockIdx.x] = s[255];
}
__global__ void k_scan3(int* __restrict__ row_start, int* __restrict__ cursor,
                        const int* __restrict__ blockOff, int n, int total){
    int i = blockIdx.x*256 + threadIdx.x;
    if (i < n){
        int v = row_start[i] + blockOff[i >> 8];
        row_start[i] = v; cursor[i] = v;
    }
    if (i == 0) row_start[n] = total;
}
__global__ void k_fillcsr(const int* __restrict__ src, const int* __restrict__ dst,
    const float* __restrict__ dinv, int* cursor,
    int* __restrict__ srcs_s, float* __restrict__ ce_s, int e){
    int i = blockIdx.x*256 + threadIdx.x;
    if (i < e){
        int d = dst[i], s = src[i];
        int p = atomicAdd(&cursor[d], 1);
        srcs_s[p] = s;
        ce_s[p] = dinv[s] * dinv[d];
    }
}

// ================= merged conversions (+ counts zeroing) =================
struct CvtArgs { const float* w[17]; const float* w0; const float* s1; const float* s2; const float* x37; };
static constexpr int CVT_W   = 17*16384;
static constexpr int CVT_W0  = 8192;
static constexpr int CVT_S1  = 9600;
static constexpr int CVT_S2  = 128;
static constexpr int CVT_X   = NN*64;
__global__ void k_cvt_all(CvtArgs a, ushort_t* __restrict__ wbf, ushort_t* __restrict__ w0bf,
                          ushort_t* __restrict__ s1bf, ushort_t* __restrict__ s2bf,
                          ushort_t* __restrict__ xb64, int* __restrict__ counts){
    int i = blockIdx.x*256 + threadIdx.x;
    if (i < NN) counts[i] = 0;                       // folded k_zero_i
    if (i < CVT_W){ int idx = i >> 14, off = i & 16383; wbf[i] = f2bf(a.w[idx][off]); return; }
    i -= CVT_W;
    if (i < CVT_W0){ int r = i >> 6, c = i & 63; w0bf[i] = (c < 37) ? f2bf(a.w0[r*37 + c]) : (ushort_t)0; return; }
    i -= CVT_W0;
    if (i < CVT_S1){ s1bf[i] = f2bf(a.s1[i]); return; }
    i -= CVT_S1;
    if (i < CVT_S2){ s2bf[i] = f2bf(a.s2[i]); return; }
    i -= CVT_S2;
    if (i < CVT_X){ int r = i >> 6, c = i & 63; xb64[i] = (c < 37) ? f2bf(a.x37[(size_t)r*37 + c]) : (ushort_t)0; return; }
}

// ========== seed-Q projections + hERG + scan2 fused (5 blocks, 512 thr) ==========
// blocks 0-1: S1@p1fq; block 2: S2@p2fq; block 3: hERG MLP; block 4: scan of block sums
__global__ __launch_bounds__(512) void k_seedq_scan2(
    const ushort_t* __restrict__ s1bf, const ushort_t* __restrict__ s2bf,
    const ushort_t* __restrict__ W1, const float* __restrict__ bias1,
    const ushort_t* __restrict__ W2q, const float* __restrict__ bias2,
    ushort_t* __restrict__ q0, ushort_t* __restrict__ q2,
    const float* __restrict__ hem, const float* __restrict__ hlW,
    const float* __restrict__ hlb, float* __restrict__ hergv,
    const int* __restrict__ blockSums, int* __restrict__ blockOff, int nb)
{
    int blk = blockIdx.x;
    int tid  = threadIdx.x;
    if (blk == 4){
        __shared__ int s[512];
        int t = tid;
        int v = (t < nb) ? blockSums[t] : 0;
        s[t] = v; __syncthreads();
        #pragma unroll
        for (int off = 1; off < 512; off <<= 1){
            int add = (t >= off) ? s[t-off] : 0;
            __syncthreads();
            s[t] += add;
            __syncthreads();
        }
        blockOff[t] = s[t] - v;
        return;
    }
    if (blk == 3){
        __shared__ float e[1280];
        for (int i = tid; i < 1280; i += 512) e[i] = hem[i];
        __syncthreads();
        if (tid < 128){
            float acc = 0.f;
            for (int k = 0; k < 1280; ++k) acc += e[k] * hlW[(size_t)tid*1280 + k];
            hergv[tid] = fmaxf(acc + hlb[tid], 0.f);
        }
        return;
    }
    if (tid >= 256) return;
    const ushort_t* x = (blk < 2) ? s1bf : s2bf;
    const ushort_t* W = (blk < 2) ? W1 : W2q;
    const float* bias = (blk < 2) ? bias1 : bias2;
    ushort_t* out = (blk < 2) ? q0 : q2;
    int M = (blk < 2) ? NS : 1;
    int base = (blk < 2) ? blk*64 : 0;
    int wid  = tid >> 6;
    int lane = tid & 63;
    int l15  = lane & 15, quad = lane >> 4;
    int row0 = base + wid*16;
    int ar   = row0 + l15; if (ar > M-1) ar = M-1;
    const short* xr = (const short*)(x + (size_t)ar*H) + quad*8;
    float4v acc[8];
    #pragma unroll
    for (int i = 0; i < 8; ++i) acc[i] = (float4v)0.f;
    #pragma unroll
    for (int kc = 0; kc < 4; ++kc){
        short8 a = *(const short8*)(xr + kc*32);
        #pragma unroll
        for (int nt = 0; nt < 8; ++nt){
            short8 b = *(const short8*)((const short*)(W + (size_t)(nt*16 + l15)*H) + kc*32 + quad*8);
            acc[nt] = __builtin_amdgcn_mfma_f32_16x16x32_bf16(a, b, acc[nt], 0, 0, 0);
        }
    }
    #pragma unroll
    for (int nt = 0; nt < 8; ++nt){
        int c = nt*16 + l15;
        float bv = bias[c];
        #pragma unroll
        for (int reg = 0; reg < 4; ++reg){
            int r = row0 + quad*4 + reg;
            if (r >= M) continue;
            out[(size_t)r*H + c] = f2bf(acc[nt][reg] + bv);
        }
    }
}

// ========== fused gather + MFMA GEMM v3 (2-edge unroll + index prefetch) ==========
// NOUT==16 writes K/V head-major: record = 32 elems (64B) per (head-pair, node)
template<int NOUT, int RELU, int STAGE2, int MINW>
__global__ __launch_bounds__(256, MINW) void k_conv_fused3(
    const ushort_t* __restrict__ x,
    const int* __restrict__ row_st, const int* __restrict__ srcs,
    const float* __restrict__ ces, const float* __restrict__ selfc,
    const ushort_t* __restrict__ W, const float* __restrict__ bias0,
    const float* __restrict__ bias1,
    const ushort_t* __restrict__ W2, const float* __restrict__ bias2,
    ushort_t* __restrict__ out0, ushort_t* __restrict__ out1)
{
    __shared__ ushort_t As[32][136];
    __shared__ ushort_t Bs[(NOUT==16)?32:1][(NOUT==16)?136:1];
    const int tid = threadIdx.x;
    const int node = tid >> 3, qq = tid & 7;   // 8 threads/node, 16 cols each
    const int g = blockIdx.x*32 + node;
    float acc[16];
    #pragma unroll
    for (int i = 0; i < 16; ++i) acc[i] = 0.f;
    if (g < NN){
        const uint4* xr = (const uint4*)(x + (size_t)g*H + qq*16);
        float sc = selfc[g];
        uint4 u0 = xr[0], u1 = xr[1];
        fma8(acc+0, u0, sc); fma8(acc+8, u1, sc);
        int e = row_st[g], e1 = row_st[g+1];
        int sA = 0, sB = 0; float cA = 0.f, cB = 0.f;
        if (e < e1){ sA = srcs[e]; cA = ces[e]; }
        if (e + 1 < e1){ sB = srcs[e+1]; cB = ces[e+1]; }
        while (e + 2 <= e1){
            int sA2 = 0, sB2 = 0; float cA2 = 0.f, cB2 = 0.f;
            if (e + 2 < e1){ sA2 = srcs[e+2]; cA2 = ces[e+2]; }
            if (e + 3 < e1){ sB2 = srcs[e+3]; cB2 = ces[e+3]; }
            const uint4* pa = (const uint4*)(x + (size_t)sA*H + qq*16);
            const uint4* pb = (const uint4*)(x + (size_t)sB*H + qq*16);
            uint4 a0 = pa[0], a1 = pa[1];
            uint4 c0 = pb[0], c1 = pb[1];
            fma8(acc+0, a0, cA); fma8(acc+8, a1, cA);
            fma8(acc+0, c0, cB); fma8(acc+8, c1, cB);
            sA = sA2; sB = sB2; cA = cA2; cB = cB2;
            e += 2;
        }
        if (e < e1){
            const uint4* pa = (const uint4*)(x + (size_t)sA*H + qq*16);
            uint4 a0 = pa[0], a1 = pa[1];
            fma8(acc+0, a0, cA); fma8(acc+8, a1, cA);
        }
    }
    {
        uint_t* dst = (uint_t*)&As[node][qq*16];
        #pragma unroll
        for (int i = 0; i < 8; ++i)
            dst[i] = (uint_t)f2bf(acc[2*i]) | ((uint_t)f2bf(acc[2*i+1]) << 16);
    }
    __syncthreads();
    const int w = tid >> 6, lane = tid & 63, l15 = lane & 15, quad = lane >> 4;
    const int rt = w & 1;                  // row tile (16 rows)
    constexpr int NT = NOUT/2;             // col tiles per wave
    const int ct0 = (w >> 1) * NT;
    float4v o[NT];
    #pragma unroll
    for (int t = 0; t < NT; ++t) o[t] = (float4v)0.f;
    #pragma unroll
    for (int kc = 0; kc < 4; ++kc){
        short8 a = *(const short8*)(&As[rt*16 + l15][kc*32 + quad*8]);
        #pragma unroll
        for (int t = 0; t < NT; ++t){
            short8 bfr = *(const short8*)(W + (size_t)((ct0 + t)*16 + l15)*H + kc*32 + quad*8);
            o[t] = __builtin_amdgcn_mfma_f32_16x16x32_bf16(a, bfr, o[t], 0, 0, 0);
        }
    }
    __syncthreads();
    #pragma unroll
    for (int t = 0; t < NT; ++t){
        int cg = (ct0 + t)*16 + l15;
        #pragma unroll
        for (int r = 0; r < 4; ++r){
            float v;
            if (NOUT == 8 || cg < 128){
                v = o[t][r] + bias0[cg];
                if (RELU) v = fmaxf(v, 0.f);
                As[rt*16 + quad*4 + r][cg] = f2bf(v);
            } else {
                v = o[t][r] + bias1[cg - 128];
                if (RELU) v = fmaxf(v, 0.f);
                Bs[rt*16 + quad*4 + r][cg - 128] = f2bf(v);
            }
        }
    }
    __syncthreads();
    if (STAGE2){
        float4v o2[4];
        #pragma unroll
        for (int t = 0; t < 4; ++t) o2[t] = (float4v)0.f;
        const int ct2 = (w >> 1) * 4;
        #pragma unroll
        for (int kc = 0; kc < 4; ++kc){
            short8 a = *(const short8*)(&As[rt*16 + l15][kc*32 + quad*8]);
            #pragma unroll
            for (int t = 0; t < 4; ++t){
                short8 bfr = *(const short8*)(W2 + (size_t)((ct2 + t)*16 + l15)*H + kc*32 + quad*8);
                o2[t] = __builtin_amdgcn_mfma_f32_16x16x32_bf16(a, bfr, o2[t], 0, 0, 0);
            }
        }
        __syncthreads();
        #pragma unroll
        for (int t = 0; t < 4; ++t){
            int cg = (ct2 + t)*16 + l15;
            #pragma unroll
            for (int r = 0; r < 4; ++r)
                As[rt*16 + quad*4 + r][cg] = f2bf(o2[t][r] + bias2[cg]);
        }
        __syncthreads();
    }
    if (g < NN){
        if (NOUT == 16){
            size_t kb = ((size_t)(qq >> 1)*NN + (size_t)g)*32 + (size_t)(qq & 1)*16;
            ((uint4*)(out0 + kb))[0] = *(const uint4*)&As[node][qq*16];
            ((uint4*)(out0 + kb))[1] = *(const uint4*)&As[node][qq*16 + 8];
            ((uint4*)(out1 + kb))[0] = *(const uint4*)&Bs[node][qq*16];
            ((uint4*)(out1 + kb))[1] = *(const uint4*)&Bs[node][qq*16 + 8];
        } else {
            uint4* op = (uint4*)(out0 + (size_t)g*H + qq*16);
            const uint4* sp = (const uint4*)&As[node][qq*16];
            op[0] = sp[0]; op[1] = sp[1];
        }
    }
}

// ========== conv0: gather padded-64 bf16 rows + MFMA GEMM (K=64) ==========
__global__ __launch_bounds__(256, 8) void k_conv0b(
    const ushort_t* __restrict__ x,   // [NN][64] bf16
    const int* __restrict__ row_st, const int* __restrict__ srcs,
    const float* __restrict__ ces, const float* __restrict__ selfc,
    const ushort_t* __restrict__ W,   // [128][64]
    const float* __restrict__ bias,
    ushort_t* __restrict__ out)
{
    __shared__ ushort_t As[32][136];
    const int tid = threadIdx.x;
    const int node = tid >> 3, qq = tid & 7;   // 8 cols (1 uint4) each
    const int g = blockIdx.x*32 + node;
    float acc[8];
    #pragma unroll
    for (int i = 0; i < 8; ++i) acc[i] = 0.f;
    if (g < NN){
        const uint4* xr = (const uint4*)(x + (size_t)g*64 + qq*8);
        float sc = selfc[g];
        fma8(acc, xr[0], sc);
        int e = row_st[g], e1 = row_st[g+1];
        int sA = 0, sB = 0; float cA = 0.f, cB = 0.f;
        if (e < e1){ sA = srcs[e]; cA = ces[e]; }
        if (e + 1 < e1){ sB = srcs[e+1]; cB = ces[e+1]; }
        while (e + 2 <= e1){
            int sA2 = 0, sB2 = 0; float cA2 = 0.f, cB2 = 0.f;
            if (e + 2 < e1){ sA2 = srcs[e+2]; cA2 = ces[e+2]; }
            if (e + 3 < e1){ sB2 = srcs[e+3]; cB2 = ces[e+3]; }
            uint4 a0 = *(const uint4*)(x + (size_t)sA*64 + qq*8);
            uint4 c0 = *(const uint4*)(x + (size_t)sB*64 + qq*8);
            fma8(acc, a0, cA);
            fma8(acc, c0, cB);
            sA = sA2; sB = sB2; cA = cA2; cB = cB2;
            e += 2;
        }
        if (e < e1){
            uint4 a0 = *(const uint4*)(x + (size_t)sA*64 + qq*8);
            fma8(acc, a0, cA);
        }
    }
    {
        uint_t* dst = (uint_t*)&As[node][qq*8];
        #pragma unroll
        for (int i = 0; i < 4; ++i)
            dst[i] = (uint_t)f2bf(acc[2*i]) | ((uint_t)f2bf(acc[2*i+1]) << 16);
    }
    __syncthreads();
    const int w = tid >> 6, lane = tid & 63, l15 = lane & 15, quad = lane >> 4;
    const int rt = w & 1;
    const int ct0 = (w >> 1) * 4;
    float4v o[4];
    #pragma unroll
    for (int t = 0; t < 4; ++t) o[t] = (float4v)0.f;
    #pragma unroll
    for (int kc = 0; kc < 2; ++kc){
        short8 a = *(const short8*)(&As[rt*16 + l15][kc*32 + quad*8]);
        #pragma unroll
        for (int t = 0; t < 4; ++t){
            short8 bfr = *(const short8*)(W + (size_t)((ct0 + t)*16 + l15)*64 + kc*32 + quad*8);
            o[t] = __builtin_amdgcn_mfma_f32_16x16x32_bf16(a, bfr, o[t], 0, 0, 0);
        }
    }
    __syncthreads();
    #pragma unroll
    for (int t = 0; t < 4; ++t){
        int cg = (ct0 + t)*16 + l15;
        #pragma unroll
        for (int r = 0; r < 4; ++r)
            As[rt*16 + quad*4 + r][cg] = f2bf(fmaxf(o[t][r] + bias[cg], 0.f));
    }
    __syncthreads();
    if (g < NN){
        uint4* op = (uint4*)(out + (size_t)g*H + qq*16);
        const uint4* sp = (const uint4*)&As[node][qq*16];
        op[0] = sp[0]; op[1] = sp[1];
    }
}

// ========== MFMA flash attention (GMPool_G, head-major K/V) ==========
template<int NK, int HM>
__global__ __launch_bounds__(256) void k_attn_mfma(
    const ushort_t* __restrict__ Q, int qbs,
    const ushort_t* __restrict__ K, const ushort_t* __restrict__ V,
    ushort_t* __restrict__ out, int nq)
{
    constexpr int NKT = (NK + 15) / 16;
    constexpr int NKC = (NK + 31) / 32;
    __shared__ ushort_t Ks[2][208][24];
    __shared__ ushort_t Vs[2][16][232];
    __shared__ ushort_t Ps[4][16][232];
    int b = blockIdx.x >> 2, hp = blockIdx.x & 3;
    int h0 = hp*2;
    int tid = threadIdx.x;
    {
        uint_t* p = (uint_t*)&Ps[0][0][0];
        for (int i = tid; i < 4*16*232/2; i += 256) p[i] = 0;
    }
    const ushort_t* Kb = HM ? (K + ((size_t)hp*NB + b)*NK*32)
                            : (K + (size_t)b*NK*H + h0*16);
    for (int idx = tid; idx < NK*8; idx += 256){
        int key = idx >> 3, p = idx & 7;
        int hh = p >> 2, dl = (p & 3)*4;
        const uint_t* src = HM ? (const uint_t*)(Kb + (size_t)key*32 + hh*16 + dl)
                               : (const uint_t*)(Kb + (size_t)key*H + hh*16 + dl);
        uint_t* d = (uint_t*)&Ks[hh][key][dl];
        d[0] = src[0]; d[1] = src[1];
    }
    const ushort_t* Vb = HM ? (V + ((size_t)hp*NB + b)*NK*32)
                            : (V + (size_t)b*NK*H + h0*16);
    for (int idx = tid; idx < NK*8; idx += 256){
        int key = idx >> 3, p = idx & 7;
        int hh = p >> 2, dl = (p & 3)*4;
        const ushort_t* src = HM ? (Vb + (size_t)key*32 + hh*16 + dl)
                                 : (Vb + (size_t)key*H + hh*16 + dl);
        Vs[hh][dl+0][key] = src[0];
        Vs[hh][dl+1][key] = src[1];
        Vs[hh][dl+2][key] = src[2];
        Vs[hh][dl+3][key] = src[3];
    }
    for (int idx = tid; idx < 2*16*(232-NK); idx += 256){
        int key = NK + idx % (232-NK), r = idx / (232-NK);
        Vs[r>>4][r&15][key] = 0;
    }
    __syncthreads();

    int w = tid >> 6, lane = tid & 63;
    int hh = w >> 1, half = w & 1;
    int h = h0 + hh;
    int l15 = lane & 15, quad = lane >> 4;
    bool klow = (quad < 2);
    int nqt = (nq + 15) >> 4;
    int split = (nqt + 1) >> 1;
    int qt0 = half ? split : 0;
    int qt1 = half ? nqt : split;
    for (int qt = qt0; qt < qt1; ++qt){
        int qr = qt*16 + l15; if (qr > nq-1) qr = nq-1;
        short8 av = *(const short8*)(Q + (size_t)b*qbs + (size_t)qr*H + h*16 + (quad & 1)*8);
        short8 zero8 = (short8)0;
        short8 afrag = klow ? av : zero8;
        float4v s[NKT];
        #pragma unroll
        for (int kt = 0; kt < NKT; ++kt){
            short8 bv = *(const short8*)(&Ks[hh][kt*16 + l15][(quad & 1)*8]);
            short8 bfrag = klow ? bv : zero8;
            s[kt] = __builtin_amdgcn_mfma_f32_16x16x32_bf16(afrag, bfrag, (float4v)0.f, 0, 0, 0);
        }
        float mx[4] = {-1e30f, -1e30f, -1e30f, -1e30f};
        #pragma unroll
        for (int kt = 0; kt < NKT; ++kt){
            if (kt*16 + l15 >= NK){ s[kt][0]=-1e30f; s[kt][1]=-1e30f; s[kt][2]=-1e30f; s[kt][3]=-1e30f; }
            #pragma unroll
            for (int r = 0; r < 4; ++r) mx[r] = fmaxf(mx[r], s[kt][r]);
        }
        #pragma unroll
        for (int off = 1; off < 16; off <<= 1){
            #pragma unroll
            for (int r = 0; r < 4; ++r) mx[r] = fmaxf(mx[r], __shfl_xor(mx[r], off));
        }
        float sum[4] = {0.f, 0.f, 0.f, 0.f};
        #pragma unroll
        for (int kt = 0; kt < NKT; ++kt){
            #pragma unroll
            for (int r = 0; r < 4; ++r){
                float e = __expf((s[kt][r] - mx[r]) * SCALE);
                sum[r] += e;
                Ps[w][quad*4 + r][kt*16 + l15] = f2bf(e);
            }
        }
        #pragma unroll
        for (int off = 1; off < 16; off <<= 1){
            #pragma unroll
            for (int r = 0; r < 4; ++r) sum[r] += __shfl_xor(sum[r], off);
        }
        float4v o = (float4v)0.f;
        #pragma unroll
        for (int kc = 0; kc < NKC; ++kc){
            short8 pa = *(const short8*)(&Ps[w][l15][kc*32 + quad*8]);
            short8 vb = *(const short8*)(&Vs[hh][l15][kc*32 + quad*8]);
            o = __builtin_amdgcn_mfma_f32_16x16x32_bf16(pa, vb, o, 0, 0, 0);
        }
        #pragma unroll
        for (int r = 0; r < 4; ++r){
            int row = qt*16 + quad*4 + r;
            if (row < nq){
                float qv = bf2f(Q[(size_t)b*qbs + (size_t)row*H + h*16 + l15]);
                out[((size_t)b*nq + row)*H + h*16 + l15] = f2bf(qv + o[r] / sum[r]);
            }
        }
    }
}

// ========== per-graph tail v3: 512 threads (8 waves), 2 blocks/CU ==========
struct TailArgs {
    const ushort_t* xA; const ushort_t* q2;
    const ushort_t* p1foW; const float* p1fob;
    const ushort_t* sfqW;  const float* sfqb;
    const ushort_t* skW;   const float* skb;
    const ushort_t* svW;   const float* svb;
    const ushort_t* sfoW;  const float* sfob;
    const ushort_t* p2kW;  const float* p2kb;
    const ushort_t* p2vW;  const float* p2vb;
    const ushort_t* p2foW; const float* p2fob;
    const ushort_t* lin2W; const float* lin2b;
    const float* hergv;
    const float* hoW; const float* hob;
    const float* fcW; const float* fcb;
    const float* sW;  const float* sb;
    float* outp;
};

__global__ __launch_bounds__(512, 4) void k_graph_tail(TailArgs a){
    __shared__ ushort_t bufA[83*136];
    __shared__ ushort_t bufB[80*136];
    __shared__ ushort_t bufC[80*136];
    __shared__ ushort_t vt4[64*104];
    const int b = blockIdx.x, tid = threadIdx.x;
    const int w = tid >> 6, lane = tid & 63, l15 = lane & 15, quad = lane >> 4;
    // per-wave P staging (16x32 bf16) in mask-protected junk rows (>=75); waves 0-3 only
    ushort_t* psw = (w == 0) ? bufA + 10200 :
                    (w == 1) ? bufA + 10712 :
                    (w == 2) ? bufB + 10200 : bufC + 10200;

    // P0: zero vt4; load xA rows for this graph into bufA
    for (int i = tid; i < 64*104/2; i += 512) ((uint_t*)vt4)[i] = 0u;
    {
        const ushort_t* xg = a.xA + (size_t)b*NS*H;
        for (int i = tid; i < NS*16; i += 512){
            int row = i >> 4, q = i & 15;
            *(uint4*)(bufA + row*136 + q*8) = *(const uint4*)(xg + (size_t)row*H + q*8);
        }
    }
    __syncthreads();

    // P1: bufA = xA + relu(xA @ p1foW^T + b) IN-PLACE (per-wave rt, reg-buffered)
    for (int rt = w; rt < 5; rt += 8){
        float4v o[8];
        #pragma unroll
        for (int i = 0; i < 8; ++i) o[i] = (float4v)0.f;
        #pragma unroll
        for (int kc = 0; kc < 4; ++kc){
            short8 av = *(const short8*)(bufA + (rt*16 + l15)*136 + kc*32 + quad*8);
            #pragma unroll
            for (int ct = 0; ct < 8; ++ct){
                short8 bv = *(const short8*)((const short*)(a.p1foW + (size_t)(ct*16 + l15)*H) + kc*32 + quad*8);
                o[ct] = __builtin_amdgcn_mfma_f32_16x16x32_bf16(av, bv, o[ct], 0, 0, 0);
            }
        }
        #pragma unroll
        for (int ct = 0; ct < 8; ++ct){
            int c = ct*16 + l15; float bb = a.p1fob[c];
            #pragma unroll
            for (int r = 0; r < 4; ++r){
                int row = rt*16 + quad*4 + r;
                float res = bf2f(bufA[row*136 + c]);
                bufA[row*136 + c] = f2bf(fmaxf(o[ct][r] + bb, 0.f) + res);
            }
        }
    }
    __syncthreads();

    // P2: SAB projections from bufA: Q->bufB, K->bufC
    for (int job = w; job < 40; job += 8){
        int rt = job >> 3, ct = job & 7;
        float4v o = (float4v)0.f;
        #pragma unroll
        for (int kc = 0; kc < 4; ++kc){
            short8 av = *(const short8*)(bufA + (rt*16 + l15)*136 + kc*32 + quad*8);
            short8 bv = *(const short8*)((const short*)(a.sfqW + (size_t)(ct*16 + l15)*H) + kc*32 + quad*8);
            o = __builtin_amdgcn_mfma_f32_16x16x32_bf16(av, bv, o, 0, 0, 0);
        }
        int c = ct*16 + l15; float bb = a.sfqb[c];
        #pragma unroll
        for (int r = 0; r < 4; ++r)
            bufB[(rt*16 + quad*4 + r)*136 + c] = f2bf(o[r] + bb);
    }
    for (int job = w; job < 40; job += 8){
        int rt = job >> 3, ct = job & 7;
        float4v o = (float4v)0.f;
        #pragma unroll
        for (int kc = 0; kc < 4; ++kc){
            short8 av = *(const short8*)(bufA + (rt*16 + l15)*136 + kc*32 + quad*8);
            short8 bv = *(const short8*)((const short*)(a.skW + (size_t)(ct*16 + l15)*H) + kc*32 + quad*8);
            o = __builtin_amdgcn_mfma_f32_16x16x32_bf16(av, bv, o, 0, 0, 0);
        }
        int c = ct*16 + l15; float bb = a.skb[c];
        #pragma unroll
        for (int r = 0; r < 4; ++r)
            bufC[(rt*16 + quad*4 + r)*136 + c] = f2bf(o[r] + bb);
    }
    __syncthreads();

    // P3: SAB attention, two 4-head passes (V-proj over 8 waves; attn on waves 0-3)
    for (int pass = 0; pass < 2; ++pass){
        int hbase = pass*4;
        for (int job = w; job < 20; job += 8){
            int rt = job >> 2, ctl = job & 3;
            int ct = hbase + ctl;
            float4v o = (float4v)0.f;
            #pragma unroll
            for (int kc = 0; kc < 4; ++kc){
                short8 av = *(const short8*)(bufA + (rt*16 + l15)*136 + kc*32 + quad*8);
                short8 bv = *(const short8*)((const short*)(a.svW + (size_t)(ct*16 + l15)*H) + kc*32 + quad*8);
                o = __builtin_amdgcn_mfma_f32_16x16x32_bf16(av, bv, o, 0, 0, 0);
            }
            int c = ct*16 + l15; float bb = a.svb[c];
            #pragma unroll
            for (int r = 0; r < 4; ++r){
                int key = rt*16 + quad*4 + r;
                if (key < NS) vt4[(ctl*16 + l15)*104 + key] = f2bf(o[r] + bb);
            }
        }
        __syncthreads();
        if (w < 4){
            int hl = w, h = hbase + w;
            short8 zero8 = (short8)0;
            bool klow = (quad < 2);
            for (int qt = 0; qt < 5; ++qt){
                short8 av = *(const short8*)(bufB + (qt*16 + l15)*136 + h*16 + (quad & 1)*8);
                short8 afrag = klow ? av : zero8;
                float4v s[5];
                #pragma unroll
                for (int kt = 0; kt < 5; ++kt){
                    short8 bv = *(const short8*)(bufC + (kt*16 + l15)*136 + h*16 + (quad & 1)*8);
                    short8 bfrag = klow ? bv : zero8;
                    s[kt] = __builtin_amdgcn_mfma_f32_16x16x32_bf16(afrag, bfrag, (float4v)0.f, 0, 0, 0);
                }
                float mx[4] = {-1e30f, -1e30f, -1e30f, -1e30f};
                #pragma unroll
                for (int kt = 0; kt < 5; ++kt){
                    if (kt*16 + l15 >= NS){ s[kt][0]=-1e30f; s[kt][1]=-1e30f; s[kt][2]=-1e30f; s[kt][3]=-1e30f; }
                    #pragma unroll
                    for (int r = 0; r < 4; ++r) mx[r] = fmaxf(mx[r], s[kt][r]);
                }
                #pragma unroll
                for (int off = 1; off < 16; off <<= 1){
                    #pragma unroll
                    for (int r = 0; r < 4; ++r) mx[r] = fmaxf(mx[r], __shfl_xor(mx[r], off));
                }
                float sum[4] = {0.f, 0.f, 0.f, 0.f};
                float4v o = (float4v)0.f;
                #pragma unroll
                for (int kc = 0; kc < 3; ++kc){
                    #pragma unroll
                    for (int t2 = 0; t2 < 2; ++t2){
                        int kt = kc*2 + t2;
                        #pragma unroll
                        for (int r = 0; r < 4; ++r){
                            float e = 0.f;
                            if (kt < 5){ e = __expf((s[kt][r] - mx[r]) * SCALE); sum[r] += e; }
                            psw[(quad*4 + r)*32 + t2*16 + l15] = f2bf(e);
                        }
                    }
                    short8 pa = *(const short8*)(psw + l15*32 + quad*8);
                    short8 vb = *(const short8*)(vt4 + (hl*16 + l15)*104 + kc*32 + quad*8);
                    o = __builtin_amdgcn_mfma_f32_16x16x32_bf16(pa, vb, o, 0, 0, 0);
                }
                #pragma unroll
                for (int off = 1; off < 16; off <<= 1){
                    #pragma unroll
                    for (int r = 0; r < 4; ++r) sum[r] += __shfl_xor(sum[r], off);
                }
                #pragma unroll
                for (int r = 0; r < 4; ++r){
                    int row = qt*16 + quad*4 + r;
                    if (row < NS){
                        float qv = bf2f(bufB[row*136 + h*16 + l15]);
                        bufB[row*136 + h*16 + l15] = f2bf(qv + o[r] / sum[r]);
                    }
                }
            }
        }
        __syncthreads();
    }

    // P4: xb2 = attnout(bufB) + relu(attnout @ sfoW^T + b) -> bufA (xb1 dead)
    for (int job = w; job < 40; job += 8){
        int rt = job >> 3, ct = job & 7;
        float4v o = (float4v)0.f;
        #pragma unroll
        for (int kc = 0; kc < 4; ++kc){
            short8 av = *(const short8*)(bufB + (rt*16 + l15)*136 + kc*32 + quad*8);
            short8 bv = *(const short8*)((const short*)(a.sfoW + (size_t)(ct*16 + l15)*H) + kc*32 + quad*8);
            o = __builtin_amdgcn_mfma_f32_16x16x32_bf16(av, bv, o, 0, 0, 0);
        }
        int c = ct*16 + l15; float bb = a.sfob[c];
        #pragma unroll
        for (int r = 0; r < 4; ++r){
            int row = rt*16 + quad*4 + r;
            bufA[row*136 + c] = f2bf(fmaxf(o[r] + bb, 0.f) + bf2f(bufB[row*136 + c]));
        }
    }
    __syncthreads();

    // P5: PMA2 K -> bufC, V -> bufB (from bufA = xb2)
    for (int job = w; job < 40; job += 8){
        int rt = job >> 3, ct = job & 7;
        float4v o = (float4v)0.f;
        #pragma unroll
        for (int kc = 0; kc < 4; ++kc){
            short8 av = *(const short8*)(bufA + (rt*16 + l15)*136 + kc*32 + quad*8);
            short8 bv = *(const short8*)((const short*)(a.p2kW + (size_t)(ct*16 + l15)*H) + kc*32 + quad*8);
            o = __builtin_amdgcn_mfma_f32_16x16x32_bf16(av, bv, o, 0, 0, 0);
        }
        int c = ct*16 + l15; float bb = a.p2kb[c];
        #pragma unroll
        for (int r = 0; r < 4; ++r)
            bufC[(rt*16 + quad*4 + r)*136 + c] = f2bf(o[r] + bb);
    }
    for (int job = w; job < 40; job += 8){
        int rt = job >> 3, ct = job & 7;
        float4v o = (float4v)0.f;
        #pragma unroll
        for (int kc = 0; kc < 4; ++kc){
            short8 av = *(const short8*)(bufA + (rt*16 + l15)*136 + kc*32 + quad*8);
            short8 bv = *(const short8*)((const short*)(a.p2vW + (size_t)(ct*16 + l15)*H) + kc*32 + quad*8);
            o = __builtin_amdgcn_mfma_f32_16x16x32_bf16(av, bv, o, 0, 0, 0);
        }
        int c = ct*16 + l15; float bb = a.p2vb[c];
        #pragma unroll
        for (int r = 0; r < 4; ++r)
            bufB[(rt*16 + quad*4 + r)*136 + c] = f2bf(o[r] + bb);
    }
    __syncthreads();

    // P6: 1-seed attention + p2fo residual + lin2 + head MLP (scratch aliases bufA)
    {
        int t = tid;
        char* sb8 = (char*)bufA;
        float* sc       = (float*)sb8;              // 8*76 floats
        float* sumh     = (float*)(sb8 + 2432);     // 8
        ushort_t* xa    = (ushort_t*)(sb8 + 2464);  // 128
        ushort_t* xb3   = (ushort_t*)(sb8 + 2720);  // 128
        float* tt       = (float*)(sb8 + 2976);     // 128
        float* v256     = (float*)(sb8 + 3488);     // 256
        float* red      = (float*)(sb8 + 4512);     // 128
        if (t < 256){
            int h = t >> 5, l32 = t & 31;
            const ushort_t* qr = a.q2 + h*16;
            for (int k = l32; k < NS; k += 32){
                float s = 0.f;
                #pragma unroll
                for (int d = 0; d < 16; ++d) s += bf2f(qr[d]) * bf2f(bufC[k*136 + h*16 + d]);
                sc[h*76 + k] = s;
            }
        }
        __syncthreads();
        if (t < 128){
            int hh = t >> 4, i = t & 15;
            float mx = -1e30f;
            for (int k = i; k < NS; k += 16) mx = fmaxf(mx, sc[hh*76 + k]);
            #pragma unroll
            for (int off = 1; off < 16; off <<= 1) mx = fmaxf(mx, __shfl_xor(mx, off));
            float sm = 0.f;
            for (int k = i; k < NS; k += 16){
                float e = __expf((sc[hh*76 + k] - mx) * SCALE);
                sc[hh*76 + k] = e;
                sm += e;
            }
            #pragma unroll
            for (int off = 1; off < 16; off <<= 1) sm += __shfl_xor(sm, off);
            if (i == 0) sumh[hh] = sm;
        }
        __syncthreads();
        if (t < 128){
            int hh = t >> 4;
            float o = 0.f;
            for (int k = 0; k < NS; ++k) o += sc[hh*76 + k] * bf2f(bufB[k*136 + t]);
            xa[t] = f2bf(bf2f(a.q2[t]) + o / sumh[hh]);
        }
        __syncthreads();
        if (t < 128){
            float acc = 0.f;
            const ushort_t* wr = a.p2foW + (size_t)t*H;
            for (int k = 0; k < H; ++k) acc += bf2f(xa[k]) * bf2f(wr[k]);
            xb3[t] = f2bf(fmaxf(acc + a.p2fob[t], 0.f) + bf2f(xa[t]));
        }
        __syncthreads();
        if (t < 128){
            float acc = 0.f;
            const ushort_t* wr = a.lin2W + (size_t)t*H;
            for (int k = 0; k < H; ++k) acc += bf2f(xb3[k]) * bf2f(wr[k]);
            v256[t] = acc + a.lin2b[t];
            v256[128 + t] = a.hergv[t];
        }
        __syncthreads();
        if (t < 128){
            float acc = 0.f;
            const float* wr = a.hoW + (size_t)t*256;
            for (int k = 0; k < 256; ++k) acc += v256[k] * wr[k];
            tt[t] = fmaxf(acc + a.hob[t], 0.f);
        }
        __syncthreads();
        if (t < 128){
            float acc = 0.f;
            const float* wr = a.fcW + (size_t)t*128;
            for (int k = 0; k < 128; ++k) acc += tt[k] * wr[k];
            float uv = fmaxf(acc + a.fcb[t], 0.f);
            red[t] = uv * a.sW[t];
        }
        __syncthreads();
        for (int s = 64; s > 0; s >>= 1){
            if (t < s) red[t] += red[t + s];
            __syncthreads();
        }
        if (t == 0){
            float logit = red[0] + a.sb[0];
            a.outp[b] = 1.f / (1.f + expf(-logit));
        }
    }
}

extern "C" void kernel_launch(void* const* d_in, const int* in_sizes, int n_in,
                              void* d_out, int out_size, void* d_ws, size_t ws_size,
                              hipStream_t stream)
{
    (void)in_sizes; (void)n_in; (void)out_size; (void)ws_size;
    const float* herg_em = (const float*)d_in[0];
    const float* x_in    = (const float*)d_in[1];
    const float* convW[4] = {(const float*)d_in[4], (const float*)d_in[6], (const float*)d_in[8], (const float*)d_in[10]};
    const float* convB[4] = {(const float*)d_in[5], (const float*)d_in[7], (const float*)d_in[9], (const float*)d_in[11]};
    const float* lin1W = (const float*)d_in[12]; const float* lin1b = (const float*)d_in[13];
    const float* lin2W = (const float*)d_in[14]; const float* lin2b = (const float*)d_in[15];
    const float* S1    = (const float*)d_in[16];
    const float* p1fqW = (const float*)d_in[17]; const float* p1fqb = (const float*)d_in[18];
    const float* p1kW  = (const float*)d_in[19]; const float* p1kb  = (const float*)d_in[20];
    const float* p1vW  = (const float*)d_in[21]; const float* p1vb  = (const float*)d_in[22];
    const float* p1foW = (const float*)d_in[23]; const float* p1fob = (const float*)d_in[24];
    const float* sfqW  = (const float*)d_in[25]; const float* sfqb  = (const float*)d_in[26];
    const float* skW   = (const float*)d_in[27]; const float* skb   = (const float*)d_in[28];
    const float* svW   = (const float*)d_in[29]; const float* svb   = (const float*)d_in[30];
    const float* sfoW  = (const float*)d_in[31]; const float* sfob  = (const float*)d_in[32];
    const float* p2fqW = (const float*)d_in[33]; const float* p2fqb = (const float*)d_in[34];
    const float* p2kW  = (const float*)d_in[35]; const float* p2kb  = (const float*)d_in[36];
    const float* p2vW  = (const float*)d_in[37]; const float* p2vb  = (const float*)d_in[38];
    const float* p2foW = (const float*)d_in[39]; const float* p2fob = (const float*)d_in[40];
    const float* S2    = (const float*)d_in[41];
    const float* hlW   = (const float*)d_in[42]; const float* hlb   = (const float*)d_in[43];
    const float* hoW   = (const float*)d_in[44]; const float* hob   = (const float*)d_in[45];
    const float* fcW   = (const float*)d_in[46]; const float* fcb   = (const float*)d_in[47];
    const float* sW    = (const float*)d_in[48]; const float* sb    = (const float*)d_in[49];
    const int*  ei    = (const int*)d_in[50];
    const int*  esrc  = ei;
    const int*  edst  = ei + NE;
    float* outp = (float*)d_out;

    // -------- workspace layout (byte offsets, 16B-aligned) --------
    char* WS = (char*)d_ws;
    int*   counts = (int*)(WS + 0);
    int*   cursor = (int*)(WS + 400384);
    int*   row_st = (int*)(WS + 800768);
    int*   bSums  = (int*)(WS + 1201152);
    int*   bOff   = (int*)(WS + 1203200);
    float* dinv   = (float*)(WS + 1205248);
    float* selfc  = (float*)(WS + 1605632);
    int*   srcs_s = (int*)(WS + 2005632);
    float* ce_s   = (float*)(WS + 3605632);
    ushort_t* wbf = (ushort_t*)(WS + 5205632); // 17*16384
    ushort_t* w0bf= (ushort_t*)(WS + 5762688);
    ushort_t* s1bf= (ushort_t*)(WS + 5779072);
    ushort_t* s2bf= (ushort_t*)(WS + 5798272);
    ushort_t* q0  = (ushort_t*)(WS + 5798528);
    ushort_t* q2  = (ushort_t*)(WS + 5817728);
    float* hergv  = (float*)(WS + 5817984);
    ushort_t* xb64= (ushort_t*)(WS + 6074496); // NN*64 bf16 padded raw x
    ushort_t* b0  = (ushort_t*)(WS + 18874496);// NN*128
    ushort_t* b1  = (ushort_t*)(WS + 44474496);
    ushort_t* b2  = (ushort_t*)(WS + 70074496);
    ushort_t* xA  = (ushort_t*)(WS + 95674496);   // 37504*128

    const int gN   = (NN + 255)/256;       // 391
    const int gE   = (NE + 255)/256;       // 1563
    const int gC   = (NN + 31)/32;         // 3125

    // ---- merged weight/input conversions + counts zeroing (1 launch, FIRST) ----
    CvtArgs ca;
    ca.w[0]=convW[1]; ca.w[1]=convW[2]; ca.w[2]=convW[3]; ca.w[3]=lin1W; ca.w[4]=lin2W;
    ca.w[5]=p1kW; ca.w[6]=p1vW; ca.w[7]=p1foW;
    ca.w[8]=sfqW; ca.w[9]=skW; ca.w[10]=svW; ca.w[11]=sfoW;
    ca.w[12]=p2kW; ca.w[13]=p2vW; ca.w[14]=p2foW; ca.w[15]=p1fqW; ca.w[16]=p2fqW;
    ca.w0 = convW[0]; ca.s1 = S1; ca.s2 = S2; ca.x37 = x_in;
    const int cvtTotal = CVT_W + CVT_W0 + CVT_S1 + CVT_S2 + CVT_X;
    k_cvt_all<<<(cvtTotal + 255)/256, 256, 0, stream>>>(ca, wbf, w0bf, s1bf, s2bf, xb64, counts);

    // ---- CSR build (+ seedQ/hERG/scan2 merged) ----
    k_hist  <<<gE, 256, 0, stream>>>(counts, edst, NE);
    k_scan1 <<<gN, 256, 0, stream>>>(counts, row_st, bSums, dinv, selfc, NN);
    k_seedq_scan2<<<5, 512, 0, stream>>>(s1bf, s2bf, wbf + (size_t)15*16384, p1fqb,
                                   wbf + (size_t)16*16384, p2fqb, q0, q2,
                                   herg_em, hlW, hlb, hergv,
                                   bSums, bOff, gN);
    k_scan3 <<<gN, 256, 0, stream>>>(row_st, cursor, bOff, NN, NE);
    k_fillcsr<<<gE, 256, 0, stream>>>(esrc, edst, dinv, cursor, srcs_s, ce_s, NE);

    // ---- conv0 (fused gather64 + GEMM) -> b0 ----
    k_conv0b<<<gC, 256, 0, stream>>>(xb64, row_st, srcs_s, ce_s, selfc, w0bf, convB[0], b0);
    // ---- conv1, conv2 ----
    k_conv_fused3<8,1,0,8><<<gC, 256, 0, stream>>>(b0, row_st, srcs_s, ce_s, selfc,
        wbf + (size_t)0*16384, convB[1], nullptr, nullptr, nullptr, b1, nullptr);
    k_conv_fused3<8,1,0,8><<<gC, 256, 0, stream>>>(b1, row_st, srcs_s, ce_s, selfc,
        wbf + (size_t)1*16384, convB[2], nullptr, nullptr, nullptr, b0, nullptr);
    // ---- conv3 + lin1 fused -> hx in b1 ----
    k_conv_fused3<8,1,1,8><<<gC, 256, 0, stream>>>(b0, row_st, srcs_s, ce_s, selfc,
        wbf + (size_t)2*16384, convB[3], nullptr, wbf + (size_t)3*16384, lin1b, b1, nullptr);
    // ---- pma1 K,V: fused shared-gather + dual GEMM, HEAD-MAJOR out (K->b2, V->b0) ----
    k_conv_fused3<16,0,0,4><<<gC, 256, 0, stream>>>(b1, row_st, srcs_s, ce_s, selfc,
        wbf + (size_t)5*16384, p1kb, p1vb, nullptr, nullptr, b2, b0);
    // ---- GMPool_G attention (head-major K/V) -> xA ----
    k_attn_mfma<200,1><<<NB*4, 256, 0, stream>>>(q0, 0, b2, b0, xA, NS);

    // ---- per-graph tail v3 (512 threads) ----
    TailArgs ta;
    ta.xA = xA; ta.q2 = q2;
    ta.p1foW = wbf + (size_t)7*16384;  ta.p1fob = p1fob;
    ta.sfqW  = wbf + (size_t)8*16384;  ta.sfqb  = sfqb;
    ta.skW   = wbf + (size_t)9*16384;  ta.skb   = skb;
    ta.svW   = wbf + (size_t)10*16384; ta.svb   = svb;
    ta.sfoW  = wbf + (size_t)11*16384; ta.sfob  = sfob;
    ta.p2kW  = wbf + (size_t)12*16384; ta.p2kb  = p2kb;
    ta.p2vW  = wbf + (size_t)13*16384; ta.p2vb  = p2vb;
    ta.p2foW = wbf + (size_t)14*16384; ta.p2fob = p2fob;
    ta.lin2W = wbf + (size_t)4*16384;  ta.lin2b = lin2b;
    ta.hergv = hergv;
    ta.hoW = hoW; ta.hob = hob;
    ta.fcW = fcW; ta.fcb = fcb;
    ta.sW = sW; ta.sb = sb;
    ta.outp = outp;
    k_graph_tail<<<NB, 512, 0, stream>>>(ta);
}

// Round 12
// 642.812 us; speedup vs baseline: 2.4876x; 1.0192x over previous
//
#include <hip/hip_runtime.h>
#include <hip/hip_bf16.h>

typedef unsigned short ushort_t;
typedef unsigned int uint_t;
typedef __attribute__((ext_vector_type(8))) short short8;
typedef __attribute__((ext_vector_type(4))) float float4v;

static constexpr int NN  = 100000;   // nodes
static constexpr int NE  = 400000;   // edges
static constexpr int NB  = 500;      // graphs
static constexpr int NS  = 75;       // seeds
static constexpr int H   = 128;
static constexpr float SCALE = 0.08838834764831845f; // 1/sqrt(128)

union U32 { uint_t u; float f; };
__device__ __forceinline__ float bf2f(ushort_t b){ U32 t; t.u = ((uint_t)b) << 16; return t.f; }
__device__ __forceinline__ ushort_t f2bf(float f){
    U32 t; t.f = f;
    uint_t r = t.u + 0x7fffu + ((t.u >> 16) & 1u);   // RNE
    return (ushort_t)(r >> 16);
}
__device__ __forceinline__ void fma8(float* a, uint4 u, float c){
    a[0] += c * bf2f((ushort_t)(u.x & 0xffff)); a[1] += c * bf2f((ushort_t)(u.x >> 16));
    a[2] += c * bf2f((ushort_t)(u.y & 0xffff)); a[3] += c * bf2f((ushort_t)(u.y >> 16));
    a[4] += c * bf2f((ushort_t)(u.z & 0xffff)); a[5] += c * bf2f((ushort_t)(u.z >> 16));
    a[6] += c * bf2f((ushort_t)(u.w & 0xffff)); a[7] += c * bf2f((ushort_t)(u.w >> 16));
}

// ================= CSR build =================
__global__ void k_hist(int* counts, const int* __restrict__ dst, int e){
    int i = blockIdx.x*256 + threadIdx.x;
    if (i < e) atomicAdd(&counts[dst[i]], 1);
}
// scan + degree norms fused
__global__ __launch_bounds__(256) void k_scan1(const int* __restrict__ counts,
    int* __restrict__ row_start, int* __restrict__ blockSums,
    float* __restrict__ dinv, float* __restrict__ selfc, int n){
    __shared__ int s[256];
    int t = threadIdx.x, i = blockIdx.x*256 + t;
    int v = (i < n) ? counts[i] : 0;
    s[t] = v; __syncthreads();
    #pragma unroll
    for (int off = 1; off < 256; off <<= 1){
        int add = (t >= off) ? s[t-off] : 0;
        __syncthreads();
        s[t] += add;
        __syncthreads();
    }
    if (i < n){
        row_start[i] = s[t] - v;
        float r = rsqrtf(1.f + (float)v);
        dinv[i] = r; selfc[i] = r*r;
    }
    if (t == 255) blockSums[blockIdx.x] = s[255];
}
__global__ void k_scan3(int* __restrict__ row_start, int* __restrict__ cursor,
                        const int* __restrict__ blockOff, int n, int total){
    int i = blockIdx.x*256 + threadIdx.x;
    if (i < n){
        int v = row_start[i] + blockOff[i >> 8];
        row_start[i] = v; cursor[i] = v;
    }
    if (i == 0) row_start[n] = total;
}
__global__ void k_fillcsr(const int* __restrict__ src, const int* __restrict__ dst,
    const float* __restrict__ dinv, int* cursor,
    int* __restrict__ srcs_s, float* __restrict__ ce_s, int e){
    int i = blockIdx.x*256 + threadIdx.x;
    if (i < e){
        int d = dst[i], s = src[i];
        int p = atomicAdd(&cursor[d], 1);
        srcs_s[p] = s;
        ce_s[p] = dinv[s] * dinv[d];
    }
}

// ================= merged conversions (+ counts zeroing) =================
struct CvtArgs { const float* w[17]; const float* w0; const float* s1; const float* s2; const float* x37; };
static constexpr int CVT_W   = 17*16384;
static constexpr int CVT_W0  = 8192;
static constexpr int CVT_S1  = 9600;
static constexpr int CVT_S2  = 128;
static constexpr int CVT_X   = NN*64;
__global__ void k_cvt_all(CvtArgs a, ushort_t* __restrict__ wbf, ushort_t* __restrict__ w0bf,
                          ushort_t* __restrict__ s1bf, ushort_t* __restrict__ s2bf,
                          ushort_t* __restrict__ xb64, int* __restrict__ counts){
    int i = blockIdx.x*256 + threadIdx.x;
    if (i < NN) counts[i] = 0;                       // folded k_zero_i
    if (i < CVT_W){ int idx = i >> 14, off = i & 16383; wbf[i] = f2bf(a.w[idx][off]); return; }
    i -= CVT_W;
    if (i < CVT_W0){ int r = i >> 6, c = i & 63; w0bf[i] = (c < 37) ? f2bf(a.w0[r*37 + c]) : (ushort_t)0; return; }
    i -= CVT_W0;
    if (i < CVT_S1){ s1bf[i] = f2bf(a.s1[i]); return; }
    i -= CVT_S1;
    if (i < CVT_S2){ s2bf[i] = f2bf(a.s2[i]); return; }
    i -= CVT_S2;
    if (i < CVT_X){ int r = i >> 6, c = i & 63; xb64[i] = (c < 37) ? f2bf(a.x37[(size_t)r*37 + c]) : (ushort_t)0; return; }
}

// ========== seed-Q projections + hERG + scan2 fused (5 blocks, 512 thr) ==========
__global__ __launch_bounds__(512) void k_seedq_scan2(
    const ushort_t* __restrict__ s1bf, const ushort_t* __restrict__ s2bf,
    const ushort_t* __restrict__ W1, const float* __restrict__ bias1,
    const ushort_t* __restrict__ W2q, const float* __restrict__ bias2,
    ushort_t* __restrict__ q0, ushort_t* __restrict__ q2,
    const float* __restrict__ hem, const float* __restrict__ hlW,
    const float* __restrict__ hlb, float* __restrict__ hergv,
    const int* __restrict__ blockSums, int* __restrict__ blockOff, int nb)
{
    int blk = blockIdx.x;
    int tid  = threadIdx.x;
    if (blk == 4){
        __shared__ int s[512];
        int t = tid;
        int v = (t < nb) ? blockSums[t] : 0;
        s[t] = v; __syncthreads();
        #pragma unroll
        for (int off = 1; off < 512; off <<= 1){
            int add = (t >= off) ? s[t-off] : 0;
            __syncthreads();
            s[t] += add;
            __syncthreads();
        }
        blockOff[t] = s[t] - v;
        return;
    }
    if (blk == 3){
        __shared__ float e[1280];
        for (int i = tid; i < 1280; i += 512) e[i] = hem[i];
        __syncthreads();
        if (tid < 128){
            float acc = 0.f;
            for (int k = 0; k < 1280; ++k) acc += e[k] * hlW[(size_t)tid*1280 + k];
            hergv[tid] = fmaxf(acc + hlb[tid], 0.f);
        }
        return;
    }
    if (tid >= 256) return;
    const ushort_t* x = (blk < 2) ? s1bf : s2bf;
    const ushort_t* W = (blk < 2) ? W1 : W2q;
    const float* bias = (blk < 2) ? bias1 : bias2;
    ushort_t* out = (blk < 2) ? q0 : q2;
    int M = (blk < 2) ? NS : 1;
    int base = (blk < 2) ? blk*64 : 0;
    int wid  = tid >> 6;
    int lane = tid & 63;
    int l15  = lane & 15, quad = lane >> 4;
    int row0 = base + wid*16;
    int ar   = row0 + l15; if (ar > M-1) ar = M-1;
    const short* xr = (const short*)(x + (size_t)ar*H) + quad*8;
    float4v acc[8];
    #pragma unroll
    for (int i = 0; i < 8; ++i) acc[i] = (float4v)0.f;
    #pragma unroll
    for (int kc = 0; kc < 4; ++kc){
        short8 a = *(const short8*)(xr + kc*32);
        #pragma unroll
        for (int nt = 0; nt < 8; ++nt){
            short8 b = *(const short8*)((const short*)(W + (size_t)(nt*16 + l15)*H) + kc*32 + quad*8);
            acc[nt] = __builtin_amdgcn_mfma_f32_16x16x32_bf16(a, b, acc[nt], 0, 0, 0);
        }
    }
    #pragma unroll
    for (int nt = 0; nt < 8; ++nt){
        int c = nt*16 + l15;
        float bv = bias[c];
        #pragma unroll
        for (int reg = 0; reg < 4; ++reg){
            int r = row0 + quad*4 + reg;
            if (r >= M) continue;
            out[(size_t)r*H + c] = f2bf(acc[nt][reg] + bv);
        }
    }
}

// ========== fused gather + MFMA GEMM v3 (2-edge unroll + index prefetch) ==========
// NOUT==16 writes K/V head-major: record = 32 elems (64B) per (head-pair, node)
template<int NOUT, int RELU, int STAGE2, int MINW>
__global__ __launch_bounds__(256, MINW) void k_conv_fused3(
    const ushort_t* __restrict__ x,
    const int* __restrict__ row_st, const int* __restrict__ srcs,
    const float* __restrict__ ces, const float* __restrict__ selfc,
    const ushort_t* __restrict__ W, const float* __restrict__ bias0,
    const float* __restrict__ bias1,
    const ushort_t* __restrict__ W2, const float* __restrict__ bias2,
    ushort_t* __restrict__ out0, ushort_t* __restrict__ out1)
{
    __shared__ ushort_t As[32][136];
    __shared__ ushort_t Bs[(NOUT==16)?32:1][(NOUT==16)?136:1];
    const int tid = threadIdx.x;
    const int node = tid >> 3, qq = tid & 7;   // 8 threads/node, 16 cols each
    const int g = blockIdx.x*32 + node;
    float acc[16];
    #pragma unroll
    for (int i = 0; i < 16; ++i) acc[i] = 0.f;
    if (g < NN){
        const uint4* xr = (const uint4*)(x + (size_t)g*H + qq*16);
        float sc = selfc[g];
        uint4 u0 = xr[0], u1 = xr[1];
        fma8(acc+0, u0, sc); fma8(acc+8, u1, sc);
        int e = row_st[g], e1 = row_st[g+1];
        int sA = 0, sB = 0; float cA = 0.f, cB = 0.f;
        if (e < e1){ sA = srcs[e]; cA = ces[e]; }
        if (e + 1 < e1){ sB = srcs[e+1]; cB = ces[e+1]; }
        while (e + 2 <= e1){
            int sA2 = 0, sB2 = 0; float cA2 = 0.f, cB2 = 0.f;
            if (e + 2 < e1){ sA2 = srcs[e+2]; cA2 = ces[e+2]; }
            if (e + 3 < e1){ sB2 = srcs[e+3]; cB2 = ces[e+3]; }
            const uint4* pa = (const uint4*)(x + (size_t)sA*H + qq*16);
            const uint4* pb = (const uint4*)(x + (size_t)sB*H + qq*16);
            uint4 a0 = pa[0], a1 = pa[1];
            uint4 c0 = pb[0], c1 = pb[1];
            fma8(acc+0, a0, cA); fma8(acc+8, a1, cA);
            fma8(acc+0, c0, cB); fma8(acc+8, c1, cB);
            sA = sA2; sB = sB2; cA = cA2; cB = cB2;
            e += 2;
        }
        if (e < e1){
            const uint4* pa = (const uint4*)(x + (size_t)sA*H + qq*16);
            uint4 a0 = pa[0], a1 = pa[1];
            fma8(acc+0, a0, cA); fma8(acc+8, a1, cA);
        }
    }
    {
        uint_t* dst = (uint_t*)&As[node][qq*16];
        #pragma unroll
        for (int i = 0; i < 8; ++i)
            dst[i] = (uint_t)f2bf(acc[2*i]) | ((uint_t)f2bf(acc[2*i+1]) << 16);
    }
    __syncthreads();
    const int w = tid >> 6, lane = tid & 63, l15 = lane & 15, quad = lane >> 4;
    const int rt = w & 1;                  // row tile (16 rows)
    constexpr int NT = NOUT/2;             // col tiles per wave
    const int ct0 = (w >> 1) * NT;
    float4v o[NT];
    #pragma unroll
    for (int t = 0; t < NT; ++t) o[t] = (float4v)0.f;
    #pragma unroll
    for (int kc = 0; kc < 4; ++kc){
        short8 a = *(const short8*)(&As[rt*16 + l15][kc*32 + quad*8]);
        #pragma unroll
        for (int t = 0; t < NT; ++t){
            short8 bfr = *(const short8*)(W + (size_t)((ct0 + t)*16 + l15)*H + kc*32 + quad*8);
            o[t] = __builtin_amdgcn_mfma_f32_16x16x32_bf16(a, bfr, o[t], 0, 0, 0);
        }
    }
    __syncthreads();
    #pragma unroll
    for (int t = 0; t < NT; ++t){
        int cg = (ct0 + t)*16 + l15;
        #pragma unroll
        for (int r = 0; r < 4; ++r){
            float v;
            if (NOUT == 8 || cg < 128){
                v = o[t][r] + bias0[cg];
                if (RELU) v = fmaxf(v, 0.f);
                As[rt*16 + quad*4 + r][cg] = f2bf(v);
            } else {
                v = o[t][r] + bias1[cg - 128];
                if (RELU) v = fmaxf(v, 0.f);
                Bs[rt*16 + quad*4 + r][cg - 128] = f2bf(v);
            }
        }
    }
    __syncthreads();
    if (STAGE2){
        float4v o2[4];
        #pragma unroll
        for (int t = 0; t < 4; ++t) o2[t] = (float4v)0.f;
        const int ct2 = (w >> 1) * 4;
        #pragma unroll
        for (int kc = 0; kc < 4; ++kc){
            short8 a = *(const short8*)(&As[rt*16 + l15][kc*32 + quad*8]);
            #pragma unroll
            for (int t = 0; t < 4; ++t){
                short8 bfr = *(const short8*)(W2 + (size_t)((ct2 + t)*16 + l15)*H + kc*32 + quad*8);
                o2[t] = __builtin_amdgcn_mfma_f32_16x16x32_bf16(a, bfr, o2[t], 0, 0, 0);
            }
        }
        __syncthreads();
        #pragma unroll
        for (int t = 0; t < 4; ++t){
            int cg = (ct2 + t)*16 + l15;
            #pragma unroll
            for (int r = 0; r < 4; ++r)
                As[rt*16 + quad*4 + r][cg] = f2bf(o2[t][r] + bias2[cg]);
        }
        __syncthreads();
    }
    if (g < NN){
        if (NOUT == 16){
            size_t kb = ((size_t)(qq >> 1)*NN + (size_t)g)*32 + (size_t)(qq & 1)*16;
            ((uint4*)(out0 + kb))[0] = *(const uint4*)&As[node][qq*16];
            ((uint4*)(out0 + kb))[1] = *(const uint4*)&As[node][qq*16 + 8];
            ((uint4*)(out1 + kb))[0] = *(const uint4*)&Bs[node][qq*16];
            ((uint4*)(out1 + kb))[1] = *(const uint4*)&Bs[node][qq*16 + 8];
        } else {
            uint4* op = (uint4*)(out0 + (size_t)g*H + qq*16);
            const uint4* sp = (const uint4*)&As[node][qq*16];
            op[0] = sp[0]; op[1] = sp[1];
        }
    }
}

// ========== conv0: gather padded-64 bf16 rows + MFMA GEMM (K=64) ==========
__global__ __launch_bounds__(256, 8) void k_conv0b(
    const ushort_t* __restrict__ x,   // [NN][64] bf16
    const int* __restrict__ row_st, const int* __restrict__ srcs,
    const float* __restrict__ ces, const float* __restrict__ selfc,
    const ushort_t* __restrict__ W,   // [128][64]
    const float* __restrict__ bias,
    ushort_t* __restrict__ out)
{
    __shared__ ushort_t As[32][136];
    const int tid = threadIdx.x;
    const int node = tid >> 3, qq = tid & 7;   // 8 cols (1 uint4) each
    const int g = blockIdx.x*32 + node;
    float acc[8];
    #pragma unroll
    for (int i = 0; i < 8; ++i) acc[i] = 0.f;
    if (g < NN){
        const uint4* xr = (const uint4*)(x + (size_t)g*64 + qq*8);
        float sc = selfc[g];
        fma8(acc, xr[0], sc);
        int e = row_st[g], e1 = row_st[g+1];
        int sA = 0, sB = 0; float cA = 0.f, cB = 0.f;
        if (e < e1){ sA = srcs[e]; cA = ces[e]; }
        if (e + 1 < e1){ sB = srcs[e+1]; cB = ces[e+1]; }
        while (e + 2 <= e1){
            int sA2 = 0, sB2 = 0; float cA2 = 0.f, cB2 = 0.f;
            if (e + 2 < e1){ sA2 = srcs[e+2]; cA2 = ces[e+2]; }
            if (e + 3 < e1){ sB2 = srcs[e+3]; cB2 = ces[e+3]; }
            uint4 a0 = *(const uint4*)(x + (size_t)sA*64 + qq*8);
            uint4 c0 = *(const uint4*)(x + (size_t)sB*64 + qq*8);
            fma8(acc, a0, cA);
            fma8(acc, c0, cB);
            sA = sA2; sB = sB2; cA = cA2; cB = cB2;
            e += 2;
        }
        if (e < e1){
            uint4 a0 = *(const uint4*)(x + (size_t)sA*64 + qq*8);
            fma8(acc, a0, cA);
        }
    }
    {
        uint_t* dst = (uint_t*)&As[node][qq*8];
        #pragma unroll
        for (int i = 0; i < 4; ++i)
            dst[i] = (uint_t)f2bf(acc[2*i]) | ((uint_t)f2bf(acc[2*i+1]) << 16);
    }
    __syncthreads();
    const int w = tid >> 6, lane = tid & 63, l15 = lane & 15, quad = lane >> 4;
    const int rt = w & 1;
    const int ct0 = (w >> 1) * 4;
    float4v o[4];
    #pragma unroll
    for (int t = 0; t < 4; ++t) o[t] = (float4v)0.f;
    #pragma unroll
    for (int kc = 0; kc < 2; ++kc){
        short8 a = *(const short8*)(&As[rt*16 + l15][kc*32 + quad*8]);
        #pragma unroll
        for (int t = 0; t < 4; ++t){
            short8 bfr = *(const short8*)(W + (size_t)((ct0 + t)*16 + l15)*64 + kc*32 + quad*8);
            o[t] = __builtin_amdgcn_mfma_f32_16x16x32_bf16(a, bfr, o[t], 0, 0, 0);
        }
    }
    __syncthreads();
    #pragma unroll
    for (int t = 0; t < 4; ++t){
        int cg = (ct0 + t)*16 + l15;
        #pragma unroll
        for (int r = 0; r < 4; ++r)
            As[rt*16 + quad*4 + r][cg] = f2bf(fmaxf(o[t][r] + bias[cg], 0.f));
    }
    __syncthreads();
    if (g < NN){
        uint4* op = (uint4*)(out + (size_t)g*H + qq*16);
        const uint4* sp = (const uint4*)&As[node][qq*16];
        op[0] = sp[0]; op[1] = sp[1];
    }
}

// ========== per-graph tail v4: GMPool_G attn + p1fo rFF + SAB + PMA2 + head MLP ==========
// 512 threads (8 waves), 2 blocks/CU, ~79.9 KB LDS
struct TailArgs {
    const ushort_t* Khm; const ushort_t* Vhm;   // head-major K/V [(hp)*NN + ...]
    const ushort_t* q0;  const ushort_t* q2;
    const ushort_t* p1foW; const float* p1fob;
    const ushort_t* sfqW;  const float* sfqb;
    const ushort_t* skW;   const float* skb;
    const ushort_t* svW;   const float* svb;
    const ushort_t* sfoW;  const float* sfob;
    const ushort_t* p2kW;  const float* p2kb;
    const ushort_t* p2vW;  const float* p2vb;
    const ushort_t* p2foW; const float* p2fob;
    const ushort_t* lin2W; const float* lin2b;
    const float* hergv;
    const float* hoW; const float* hob;
    const float* fcW; const float* fcb;
    const float* sW;  const float* sb;
    float* outp;
};

__global__ __launch_bounds__(512, 4) void k_graph_tail(TailArgs a){
    __shared__ ushort_t bufA[83*136];
    __shared__ ushort_t bufB[80*136];
    __shared__ ushort_t bufC[80*136];
    __shared__ ushort_t vt4[64*104];
    const int b = blockIdx.x, tid = threadIdx.x;
    const int w = tid >> 6, lane = tid & 63, l15 = lane & 15, quad = lane >> 4;

    // ======== A0: GMPool_G attention (xA computed directly into bufA) ========
    // bufB = Ks[2][208][24] staging; bufC = Vs[2][16][232]; vt4 = per-wave P arena
    // Zero Vs pad keys 200..231 once (stage loop writes only keys < 200)
    for (int i = tid; i < 2*16*32; i += 512){
        int hh2 = i >> 9, rr = (i >> 5) & 15, kk = 200 + (i & 31);
        bufC[(hh2*16 + rr)*232 + kk] = 0;
    }
    for (int hp = 0; hp < 4; ++hp){
        __syncthreads();   // protect bufB/C from previous iteration's job reads
        const ushort_t* Kb = a.Khm + ((size_t)hp*NB + b)*(size_t)200*32;
        for (int idx = tid; idx < 200*8; idx += 512){
            int key = idx >> 3, p = idx & 7;
            int hh = p >> 2, dl = (p & 3)*4;
            const uint_t* src = (const uint_t*)(Kb + (size_t)key*32 + hh*16 + dl);
            uint_t* d = (uint_t*)&bufB[(hh*208 + key)*24 + dl];
            d[0] = src[0]; d[1] = src[1];
        }
        const ushort_t* Vb = a.Vhm + ((size_t)hp*NB + b)*(size_t)200*32;
        for (int idx = tid; idx < 200*8; idx += 512){
            int key = idx >> 3, p = idx & 7;
            int hh = p >> 2, dl = (p & 3)*4;
            const ushort_t* src = Vb + (size_t)key*32 + hh*16 + dl;
            bufC[(hh*16 + dl+0)*232 + key] = src[0];
            bufC[(hh*16 + dl+1)*232 + key] = src[1];
            bufC[(hh*16 + dl+2)*232 + key] = src[2];
            bufC[(hh*16 + dl+3)*232 + key] = src[3];
        }
        __syncthreads();
        // 10 jobs (2 local heads x 5 q-tiles) over 8 waves
        for (int j = w; j < 10; j += 8){
            int hl = j / 5, qt = j % 5;
            int gh = hp*2 + hl;
            ushort_t* psw = vt4 + w*512;
            int qr = qt*16 + l15; if (qr > NS-1) qr = NS-1;
            short8 av = *(const short8*)(a.q0 + (size_t)qr*H + gh*16 + (quad & 1)*8);
            short8 zero8 = (short8)0;
            bool klow = (quad < 2);
            short8 afrag = klow ? av : zero8;
            float4v s[13];
            #pragma unroll
            for (int kt = 0; kt < 13; ++kt){
                short8 bv = *(const short8*)(&bufB[(hl*208 + kt*16 + l15)*24 + (quad & 1)*8]);
                short8 bfrag = klow ? bv : zero8;
                s[kt] = __builtin_amdgcn_mfma_f32_16x16x32_bf16(afrag, bfrag, (float4v)0.f, 0, 0, 0);
            }
            float mx[4] = {-1e30f, -1e30f, -1e30f, -1e30f};
            #pragma unroll
            for (int kt = 0; kt < 13; ++kt){
                if (kt*16 + l15 >= 200){ s[kt][0]=-1e30f; s[kt][1]=-1e30f; s[kt][2]=-1e30f; s[kt][3]=-1e30f; }
                #pragma unroll
                for (int r = 0; r < 4; ++r) mx[r] = fmaxf(mx[r], s[kt][r]);
            }
            #pragma unroll
            for (int off = 1; off < 16; off <<= 1){
                #pragma unroll
                for (int r = 0; r < 4; ++r) mx[r] = fmaxf(mx[r], __shfl_xor(mx[r], off));
            }
            float sum[4] = {0.f, 0.f, 0.f, 0.f};
            float4v o = (float4v)0.f;
            #pragma unroll
            for (int kc = 0; kc < 7; ++kc){
                #pragma unroll
                for (int t2 = 0; t2 < 2; ++t2){
                    int kt = kc*2 + t2;
                    #pragma unroll
                    for (int r = 0; r < 4; ++r){
                        float e = 0.f;
                        if (kt < 13){ e = __expf((s[kt][r] - mx[r]) * SCALE); sum[r] += e; }
                        psw[(quad*4 + r)*32 + t2*16 + l15] = f2bf(e);
                    }
                }
                short8 pa = *(const short8*)(psw + l15*32 + quad*8);
                short8 vb = *(const short8*)(&bufC[(hl*16 + l15)*232 + kc*32 + quad*8]);
                o = __builtin_amdgcn_mfma_f32_16x16x32_bf16(pa, vb, o, 0, 0, 0);
            }
            #pragma unroll
            for (int off = 1; off < 16; off <<= 1){
                #pragma unroll
                for (int r = 0; r < 4; ++r) sum[r] += __shfl_xor(sum[r], off);
            }
            #pragma unroll
            for (int r = 0; r < 4; ++r){
                int row = qt*16 + quad*4 + r;
                if (row < NS){
                    float qv = bf2f(a.q0[(size_t)row*H + gh*16 + l15]);
                    bufA[row*136 + gh*16 + l15] = f2bf(qv + o[r] / sum[r]);
                }
            }
        }
    }
    __syncthreads();

    // P1: bufA = xA + relu(xA @ p1foW^T + b) IN-PLACE (waves 0-4); waves 5-7 zero vt4
    if (w >= 5){
        for (int i = tid - 320; i < 64*104/2; i += 192) ((uint_t*)vt4)[i] = 0u;
    }
    for (int rt = w; rt < 5; rt += 8){
        float4v o[8];
        #pragma unroll
        for (int i = 0; i < 8; ++i) o[i] = (float4v)0.f;
        #pragma unroll
        for (int kc = 0; kc < 4; ++kc){
            short8 av = *(const short8*)(bufA + (rt*16 + l15)*136 + kc*32 + quad*8);
            #pragma unroll
            for (int ct = 0; ct < 8; ++ct){
                short8 bv = *(const short8*)((const short*)(a.p1foW + (size_t)(ct*16 + l15)*H) + kc*32 + quad*8);
                o[ct] = __builtin_amdgcn_mfma_f32_16x16x32_bf16(av, bv, o[ct], 0, 0, 0);
            }
        }
        #pragma unroll
        for (int ct = 0; ct < 8; ++ct){
            int c = ct*16 + l15; float bb = a.p1fob[c];
            #pragma unroll
            for (int r = 0; r < 4; ++r){
                int row = rt*16 + quad*4 + r;
                float res = bf2f(bufA[row*136 + c]);
                bufA[row*136 + c] = f2bf(fmaxf(o[ct][r] + bb, 0.f) + res);
            }
        }
    }
    __syncthreads();

    // P2: SAB projections from bufA: Q->bufB, K->bufC
    for (int job = w; job < 40; job += 8){
        int rt = job >> 3, ct = job & 7;
        float4v o = (float4v)0.f;
        #pragma unroll
        for (int kc = 0; kc < 4; ++kc){
            short8 av = *(const short8*)(bufA + (rt*16 + l15)*136 + kc*32 + quad*8);
            short8 bv = *(const short8*)((const short*)(a.sfqW + (size_t)(ct*16 + l15)*H) + kc*32 + quad*8);
            o = __builtin_amdgcn_mfma_f32_16x16x32_bf16(av, bv, o, 0, 0, 0);
        }
        int c = ct*16 + l15; float bb = a.sfqb[c];
        #pragma unroll
        for (int r = 0; r < 4; ++r)
            bufB[(rt*16 + quad*4 + r)*136 + c] = f2bf(o[r] + bb);
    }
    for (int job = w; job < 40; job += 8){
        int rt = job >> 3, ct = job & 7;
        float4v o = (float4v)0.f;
        #pragma unroll
        for (int kc = 0; kc < 4; ++kc){
            short8 av = *(const short8*)(bufA + (rt*16 + l15)*136 + kc*32 + quad*8);
            short8 bv = *(const short8*)((const short*)(a.skW + (size_t)(ct*16 + l15)*H) + kc*32 + quad*8);
            o = __builtin_amdgcn_mfma_f32_16x16x32_bf16(av, bv, o, 0, 0, 0);
        }
        int c = ct*16 + l15; float bb = a.skb[c];
        #pragma unroll
        for (int r = 0; r < 4; ++r)
            bufC[(rt*16 + quad*4 + r)*136 + c] = f2bf(o[r] + bb);
    }
    __syncthreads();

    // P3: SAB attention, two 4-head passes (V-proj over 8 waves; attn on waves 0-3)
    for (int pass = 0; pass < 2; ++pass){
        int hbase = pass*4;
        for (int job = w; job < 20; job += 8){
            int rt = job >> 2, ctl = job & 3;
            int ct = hbase + ctl;
            float4v o = (float4v)0.f;
            #pragma unroll
            for (int kc = 0; kc < 4; ++kc){
                short8 av = *(const short8*)(bufA + (rt*16 + l15)*136 + kc*32 + quad*8);
                short8 bv = *(const short8*)((const short*)(a.svW + (size_t)(ct*16 + l15)*H) + kc*32 + quad*8);
                o = __builtin_amdgcn_mfma_f32_16x16x32_bf16(av, bv, o, 0, 0, 0);
            }
            int c = ct*16 + l15; float bb = a.svb[c];
            #pragma unroll
            for (int r = 0; r < 4; ++r){
                int key = rt*16 + quad*4 + r;
                if (key < NS) vt4[(ctl*16 + l15)*104 + key] = f2bf(o[r] + bb);
            }
        }
        __syncthreads();
        if (w < 4){
            ushort_t* psw = (w == 0) ? bufA + 10200 :
                            (w == 1) ? bufA + 10712 :
                            (w == 2) ? bufB + 10200 : bufC + 10200;
            int hl = w, h = hbase + w;
            short8 zero8 = (short8)0;
            bool klow = (quad < 2);
            for (int qt = 0; qt < 5; ++qt){
                short8 av = *(const short8*)(bufB + (qt*16 + l15)*136 + h*16 + (quad & 1)*8);
                short8 afrag = klow ? av : zero8;
                float4v s[5];
                #pragma unroll
                for (int kt = 0; kt < 5; ++kt){
                    short8 bv = *(const short8*)(bufC + (kt*16 + l15)*136 + h*16 + (quad & 1)*8);
                    short8 bfrag = klow ? bv : zero8;
                    s[kt] = __builtin_amdgcn_mfma_f32_16x16x32_bf16(afrag, bfrag, (float4v)0.f, 0, 0, 0);
                }
                float mx[4] = {-1e30f, -1e30f, -1e30f, -1e30f};
                #pragma unroll
                for (int kt = 0; kt < 5; ++kt){
                    if (kt*16 + l15 >= NS){ s[kt][0]=-1e30f; s[kt][1]=-1e30f; s[kt][2]=-1e30f; s[kt][3]=-1e30f; }
                    #pragma unroll
                    for (int r = 0; r < 4; ++r) mx[r] = fmaxf(mx[r], s[kt][r]);
                }
                #pragma unroll
                for (int off = 1; off < 16; off <<= 1){
                    #pragma unroll
                    for (int r = 0; r < 4; ++r) mx[r] = fmaxf(mx[r], __shfl_xor(mx[r], off));
                }
                float sum[4] = {0.f, 0.f, 0.f, 0.f};
                float4v o = (float4v)0.f;
                #pragma unroll
                for (int kc = 0; kc < 3; ++kc){
                    #pragma unroll
                    for (int t2 = 0; t2 < 2; ++t2){
                        int kt = kc*2 + t2;
                        #pragma unroll
                        for (int r = 0; r < 4; ++r){
                            float e = 0.f;
                            if (kt < 5){ e = __expf((s[kt][r] - mx[r]) * SCALE); sum[r] += e; }
                            psw[(quad*4 + r)*32 + t2*16 + l15] = f2bf(e);
                        }
                    }
                    short8 pa = *(const short8*)(psw + l15*32 + quad*8);
                    short8 vb = *(const short8*)(vt4 + (hl*16 + l15)*104 + kc*32 + quad*8);
                    o = __builtin_amdgcn_mfma_f32_16x16x32_bf16(pa, vb, o, 0, 0, 0);
                }
                #pragma unroll
                for (int off = 1; off < 16; off <<= 1){
                    #pragma unroll
                    for (int r = 0; r < 4; ++r) sum[r] += __shfl_xor(sum[r], off);
                }
                #pragma unroll
                for (int r = 0; r < 4; ++r){
                    int row = qt*16 + quad*4 + r;
                    if (row < NS){
                        float qv = bf2f(bufB[row*136 + h*16 + l15]);
                        bufB[row*136 + h*16 + l15] = f2bf(qv + o[r] / sum[r]);
                    }
                }
            }
        }
        __syncthreads();
    }

    // P4: xb2 = attnout(bufB) + relu(attnout @ sfoW^T + b) -> bufA (xb1 dead)
    for (int job = w; job < 40; job += 8){
        int rt = job >> 3, ct = job & 7;
        float4v o = (float4v)0.f;
        #pragma unroll
        for (int kc = 0; kc < 4; ++kc){
            short8 av = *(const short8*)(bufB + (rt*16 + l15)*136 + kc*32 + quad*8);
            short8 bv = *(const short8*)((const short*)(a.sfoW + (size_t)(ct*16 + l15)*H) + kc*32 + quad*8);
            o = __builtin_amdgcn_mfma_f32_16x16x32_bf16(av, bv, o, 0, 0, 0);
        }
        int c = ct*16 + l15; float bb = a.sfob[c];
        #pragma unroll
        for (int r = 0; r < 4; ++r){
            int row = rt*16 + quad*4 + r;
            bufA[row*136 + c] = f2bf(fmaxf(o[r] + bb, 0.f) + bf2f(bufB[row*136 + c]));
        }
    }
    __syncthreads();

    // P5: PMA2 K -> bufC, V -> bufB (from bufA = xb2)
    for (int job = w; job < 40; job += 8){
        int rt = job >> 3, ct = job & 7;
        float4v o = (float4v)0.f;
        #pragma unroll
        for (int kc = 0; kc < 4; ++kc){
            short8 av = *(const short8*)(bufA + (rt*16 + l15)*136 + kc*32 + quad*8);
            short8 bv = *(const short8*)((const short*)(a.p2kW + (size_t)(ct*16 + l15)*H) + kc*32 + quad*8);
            o = __builtin_amdgcn_mfma_f32_16x16x32_bf16(av, bv, o, 0, 0, 0);
        }
        int c = ct*16 + l15; float bb = a.p2kb[c];
        #pragma unroll
        for (int r = 0; r < 4; ++r)
            bufC[(rt*16 + quad*4 + r)*136 + c] = f2bf(o[r] + bb);
    }
    for (int job = w; job < 40; job += 8){
        int rt = job >> 3, ct = job & 7;
        float4v o = (float4v)0.f;
        #pragma unroll
        for (int kc = 0; kc < 4; ++kc){
            short8 av = *(const short8*)(bufA + (rt*16 + l15)*136 + kc*32 + quad*8);
            short8 bv = *(const short8*)((const short*)(a.p2vW + (size_t)(ct*16 + l15)*H) + kc*32 + quad*8);
            o = __builtin_amdgcn_mfma_f32_16x16x32_bf16(av, bv, o, 0, 0, 0);
        }
        int c = ct*16 + l15; float bb = a.p2vb[c];
        #pragma unroll
        for (int r = 0; r < 4; ++r)
            bufB[(rt*16 + quad*4 + r)*136 + c] = f2bf(o[r] + bb);
    }
    __syncthreads();

    // P6: 1-seed attention + p2fo residual + lin2 + head MLP (scratch aliases bufA)
    {
        int t = tid;
        char* sb8 = (char*)bufA;
        float* sc       = (float*)sb8;              // 8*76 floats
        float* sumh     = (float*)(sb8 + 2432);     // 8
        ushort_t* xa    = (ushort_t*)(sb8 + 2464);  // 128
        ushort_t* xb3   = (ushort_t*)(sb8 + 2720);  // 128
        float* tt       = (float*)(sb8 + 2976);     // 128
        float* v256     = (float*)(sb8 + 3488);     // 256
        float* red      = (float*)(sb8 + 4512);     // 128
        if (t < 256){
            int h = t >> 5, l32 = t & 31;
            const ushort_t* qr = a.q2 + h*16;
            for (int k = l32; k < NS; k += 32){
                float s = 0.f;
                #pragma unroll
                for (int d = 0; d < 16; ++d) s += bf2f(qr[d]) * bf2f(bufC[k*136 + h*16 + d]);
                sc[h*76 + k] = s;
            }
        }
        __syncthreads();
        if (t < 128){
            int hh = t >> 4, i = t & 15;
            float mx = -1e30f;
            for (int k = i; k < NS; k += 16) mx = fmaxf(mx, sc[hh*76 + k]);
            #pragma unroll
            for (int off = 1; off < 16; off <<= 1) mx = fmaxf(mx, __shfl_xor(mx, off));
            float sm = 0.f;
            for (int k = i; k < NS; k += 16){
                float e = __expf((sc[hh*76 + k] - mx) * SCALE);
                sc[hh*76 + k] = e;
                sm += e;
            }
            #pragma unroll
            for (int off = 1; off < 16; off <<= 1) sm += __shfl_xor(sm, off);
            if (i == 0) sumh[hh] = sm;
        }
        __syncthreads();
        if (t < 128){
            int hh = t >> 4;
            float o = 0.f;
            for (int k = 0; k < NS; ++k) o += sc[hh*76 + k] * bf2f(bufB[k*136 + t]);
            xa[t] = f2bf(bf2f(a.q2[t]) + o / sumh[hh]);
        }
        __syncthreads();
        if (t < 128){
            float acc = 0.f;
            const ushort_t* wr = a.p2foW + (size_t)t*H;
            for (int k = 0; k < H; ++k) acc += bf2f(xa[k]) * bf2f(wr[k]);
            xb3[t] = f2bf(fmaxf(acc + a.p2fob[t], 0.f) + bf2f(xa[t]));
        }
        __syncthreads();
        if (t < 128){
            float acc = 0.f;
            const ushort_t* wr = a.lin2W + (size_t)t*H;
            for (int k = 0; k < H; ++k) acc += bf2f(xb3[k]) * bf2f(wr[k]);
            v256[t] = acc + a.lin2b[t];
            v256[128 + t] = a.hergv[t];
        }
        __syncthreads();
        if (t < 128){
            float acc = 0.f;
            const float* wr = a.hoW + (size_t)t*256;
            for (int k = 0; k < 256; ++k) acc += v256[k] * wr[k];
            tt[t] = fmaxf(acc + a.hob[t], 0.f);
        }
        __syncthreads();
        if (t < 128){
            float acc = 0.f;
            const float* wr = a.fcW + (size_t)t*128;
            for (int k = 0; k < 128; ++k) acc += tt[k] * wr[k];
            float uv = fmaxf(acc + a.fcb[t], 0.f);
            red[t] = uv * a.sW[t];
        }
        __syncthreads();
        for (int s = 64; s > 0; s >>= 1){
            if (t < s) red[t] += red[t + s];
            __syncthreads();
        }
        if (t == 0){
            float logit = red[0] + a.sb[0];
            a.outp[b] = 1.f / (1.f + expf(-logit));
        }
    }
}

extern "C" void kernel_launch(void* const* d_in, const int* in_sizes, int n_in,
                              void* d_out, int out_size, void* d_ws, size_t ws_size,
                              hipStream_t stream)
{
    (void)in_sizes; (void)n_in; (void)out_size; (void)ws_size;
    const float* herg_em = (const float*)d_in[0];
    const float* x_in    = (const float*)d_in[1];
    const float* convW[4] = {(const float*)d_in[4], (const float*)d_in[6], (const float*)d_in[8], (const float*)d_in[10]};
    const float* convB[4] = {(const float*)d_in[5], (const float*)d_in[7], (const float*)d_in[9], (const float*)d_in[11]};
    const float* lin1W = (const float*)d_in[12]; const float* lin1b = (const float*)d_in[13];
    const float* lin2W = (const float*)d_in[14]; const float* lin2b = (const float*)d_in[15];
    const float* S1    = (const float*)d_in[16];
    const float* p1fqW = (const float*)d_in[17]; const float* p1fqb = (const float*)d_in[18];
    const float* p1kW  = (const float*)d_in[19]; const float* p1kb  = (const float*)d_in[20];
    const float* p1vW  = (const float*)d_in[21]; const float* p1vb  = (const float*)d_in[22];
    const float* p1foW = (const float*)d_in[23]; const float* p1fob = (const float*)d_in[24];
    const float* sfqW  = (const float*)d_in[25]; const float* sfqb  = (const float*)d_in[26];
    const float* skW   = (const float*)d_in[27]; const float* skb   = (const float*)d_in[28];
    const float* svW   = (const float*)d_in[29]; const float* svb   = (const float*)d_in[30];
    const float* sfoW  = (const float*)d_in[31]; const float* sfob  = (const float*)d_in[32];
    const float* p2fqW = (const float*)d_in[33]; const float* p2fqb = (const float*)d_in[34];
    const float* p2kW  = (const float*)d_in[35]; const float* p2kb  = (const float*)d_in[36];
    const float* p2vW  = (const float*)d_in[37]; const float* p2vb  = (const float*)d_in[38];
    const float* p2foW = (const float*)d_in[39]; const float* p2fob = (const float*)d_in[40];
    const float* S2    = (const float*)d_in[41];
    const float* hlW   = (const float*)d_in[42]; const float* hlb   = (const float*)d_in[43];
    const float* hoW   = (const float*)d_in[44]; const float* hob   = (const float*)d_in[45];
    const float* fcW   = (const float*)d_in[46]; const float* fcb   = (const float*)d_in[47];
    const float* sW    = (const float*)d_in[48]; const float* sb    = (const float*)d_in[49];
    const int*  ei    = (const int*)d_in[50];
    const int*  esrc  = ei;
    const int*  edst  = ei + NE;
    float* outp = (float*)d_out;

    // -------- workspace layout (byte offsets, 16B-aligned) --------
    char* WS = (char*)d_ws;
    int*   counts = (int*)(WS + 0);
    int*   cursor = (int*)(WS + 400384);
    int*   row_st = (int*)(WS + 800768);
    int*   bSums  = (int*)(WS + 1201152);
    int*   bOff   = (int*)(WS + 1203200);
    float* dinv   = (float*)(WS + 1205248);
    float* selfc  = (float*)(WS + 1605632);
    int*   srcs_s = (int*)(WS + 2005632);
    float* ce_s   = (float*)(WS + 3605632);
    ushort_t* wbf = (ushort_t*)(WS + 5205632); // 17*16384
    ushort_t* w0bf= (ushort_t*)(WS + 5762688);
    ushort_t* s1bf= (ushort_t*)(WS + 5779072);
    ushort_t* s2bf= (ushort_t*)(WS + 5798272);
    ushort_t* q0  = (ushort_t*)(WS + 5798528);
    ushort_t* q2  = (ushort_t*)(WS + 5817728);
    float* hergv  = (float*)(WS + 5817984);
    ushort_t* xb64= (ushort_t*)(WS + 6074496); // NN*64 bf16 padded raw x
    ushort_t* b0  = (ushort_t*)(WS + 18874496);// NN*128
    ushort_t* b1  = (ushort_t*)(WS + 44474496);
    ushort_t* b2  = (ushort_t*)(WS + 70074496);

    const int gN   = (NN + 255)/256;       // 391
    const int gE   = (NE + 255)/256;       // 1563
    const int gC   = (NN + 31)/32;         // 3125

    // ---- merged weight/input conversions + counts zeroing (1 launch, FIRST) ----
    CvtArgs ca;
    ca.w[0]=convW[1]; ca.w[1]=convW[2]; ca.w[2]=convW[3]; ca.w[3]=lin1W; ca.w[4]=lin2W;
    ca.w[5]=p1kW; ca.w[6]=p1vW; ca.w[7]=p1foW;
    ca.w[8]=sfqW; ca.w[9]=skW; ca.w[10]=svW; ca.w[11]=sfoW;
    ca.w[12]=p2kW; ca.w[13]=p2vW; ca.w[14]=p2foW; ca.w[15]=p1fqW; ca.w[16]=p2fqW;
    ca.w0 = convW[0]; ca.s1 = S1; ca.s2 = S2; ca.x37 = x_in;
    const int cvtTotal = CVT_W + CVT_W0 + CVT_S1 + CVT_S2 + CVT_X;
    k_cvt_all<<<(cvtTotal + 255)/256, 256, 0, stream>>>(ca, wbf, w0bf, s1bf, s2bf, xb64, counts);

    // ---- CSR build (+ seedQ/hERG/scan2 merged) ----
    k_hist  <<<gE, 256, 0, stream>>>(counts, edst, NE);
    k_scan1 <<<gN, 256, 0, stream>>>(counts, row_st, bSums, dinv, selfc, NN);
    k_seedq_scan2<<<5, 512, 0, stream>>>(s1bf, s2bf, wbf + (size_t)15*16384, p1fqb,
                                   wbf + (size_t)16*16384, p2fqb, q0, q2,
                                   herg_em, hlW, hlb, hergv,
                                   bSums, bOff, gN);
    k_scan3 <<<gN, 256, 0, stream>>>(row_st, cursor, bOff, NN, NE);
    k_fillcsr<<<gE, 256, 0, stream>>>(esrc, edst, dinv, cursor, srcs_s, ce_s, NE);

    // ---- conv0 (fused gather64 + GEMM) -> b0 ----
    k_conv0b<<<gC, 256, 0, stream>>>(xb64, row_st, srcs_s, ce_s, selfc, w0bf, convB[0], b0);
    // ---- conv1, conv2 ----
    k_conv_fused3<8,1,0,8><<<gC, 256, 0, stream>>>(b0, row_st, srcs_s, ce_s, selfc,
        wbf + (size_t)0*16384, convB[1], nullptr, nullptr, nullptr, b1, nullptr);
    k_conv_fused3<8,1,0,8><<<gC, 256, 0, stream>>>(b1, row_st, srcs_s, ce_s, selfc,
        wbf + (size_t)1*16384, convB[2], nullptr, nullptr, nullptr, b0, nullptr);
    // ---- conv3 + lin1 fused -> hx in b1 ----
    k_conv_fused3<8,1,1,8><<<gC, 256, 0, stream>>>(b0, row_st, srcs_s, ce_s, selfc,
        wbf + (size_t)2*16384, convB[3], nullptr, wbf + (size_t)3*16384, lin1b, b1, nullptr);
    // ---- pma1 K,V: fused shared-gather + dual GEMM, HEAD-MAJOR out (K->b2, V->b0) ----
    k_conv_fused3<16,0,0,4><<<gC, 256, 0, stream>>>(b1, row_st, srcs_s, ce_s, selfc,
        wbf + (size_t)5*16384, p1kb, p1vb, nullptr, nullptr, b2, b0);

    // ---- per-graph tail v4: GMPool_G attn + p1fo + SAB + PMA2 + head -> out ----
    TailArgs ta;
    ta.Khm = b2; ta.Vhm = b0; ta.q0 = q0; ta.q2 = q2;
    ta.p1foW = wbf + (size_t)7*16384;  ta.p1fob = p1fob;
    ta.sfqW  = wbf + (size_t)8*16384;  ta.sfqb  = sfqb;
    ta.skW   = wbf + (size_t)9*16384;  ta.skb   = skb;
    ta.svW   = wbf + (size_t)10*16384; ta.svb   = svb;
    ta.sfoW  = wbf + (size_t)11*16384; ta.sfob  = sfob;
    ta.p2kW  = wbf + (size_t)12*16384; ta.p2kb  = p2kb;
    ta.p2vW  = wbf + (size_t)13*16384; ta.p2vb  = p2vb;
    ta.p2foW = wbf + (size_t)14*16384; ta.p2fob = p2fob;
    ta.lin2W = wbf + (size_t)4*16384;  ta.lin2b = lin2b;
    ta.hergv = hergv;
    ta.hoW = hoW; ta.hob = hob;
    ta.fcW = fcW; ta.fcb = fcb;
    ta.sW = sW; ta.sb = sb;
    ta.outp = outp;
    k_graph_tail<<<NB, 512, 0, stream>>>(ta);
}

// Round 13
// 637.441 us; speedup vs baseline: 2.5086x; 1.0084x over previous
//
#include <hip/hip_runtime.h>
#include <hip/hip_bf16.h>

typedef unsigned short ushort_t;
typedef unsigned int uint_t;
typedef __attribute__((ext_vector_type(8))) short short8;
typedef __attribute__((ext_vector_type(4))) float float4v;

static constexpr int NN  = 100000;   // nodes
static constexpr int NE  = 400000;   // edges
static constexpr int NB  = 500;      // graphs
static constexpr int NS  = 75;       // seeds
static constexpr int H   = 128;
static constexpr float SCALE = 0.08838834764831845f; // 1/sqrt(128)

union U32 { uint_t u; float f; };
__device__ __forceinline__ float bf2f(ushort_t b){ U32 t; t.u = ((uint_t)b) << 16; return t.f; }
__device__ __forceinline__ ushort_t f2bf(float f){
    U32 t; t.f = f;
    uint_t r = t.u + 0x7fffu + ((t.u >> 16) & 1u);   // RNE
    return (ushort_t)(r >> 16);
}
__device__ __forceinline__ void fma8(float* a, uint4 u, float c){
    a[0] += c * bf2f((ushort_t)(u.x & 0xffff)); a[1] += c * bf2f((ushort_t)(u.x >> 16));
    a[2] += c * bf2f((ushort_t)(u.y & 0xffff)); a[3] += c * bf2f((ushort_t)(u.y >> 16));
    a[4] += c * bf2f((ushort_t)(u.z & 0xffff)); a[5] += c * bf2f((ushort_t)(u.z >> 16));
    a[6] += c * bf2f((ushort_t)(u.w & 0xffff)); a[7] += c * bf2f((ushort_t)(u.w >> 16));
}

// ================= CSR build =================
__global__ void k_hist(int* counts, const int* __restrict__ dst, int e){
    int i = blockIdx.x*256 + threadIdx.x;
    if (i < e) atomicAdd(&counts[dst[i]], 1);
}
// scan + degree norms fused
__global__ __launch_bounds__(256) void k_scan1(const int* __restrict__ counts,
    int* __restrict__ row_start, int* __restrict__ blockSums,
    float* __restrict__ dinv, float* __restrict__ selfc, int n){
    __shared__ int s[256];
    int t = threadIdx.x, i = blockIdx.x*256 + t;
    int v = (i < n) ? counts[i] : 0;
    s[t] = v; __syncthreads();
    #pragma unroll
    for (int off = 1; off < 256; off <<= 1){
        int add = (t >= off) ? s[t-off] : 0;
        __syncthreads();
        s[t] += add;
        __syncthreads();
    }
    if (i < n){
        row_start[i] = s[t] - v;
        float r = rsqrtf(1.f + (float)v);
        dinv[i] = r; selfc[i] = r*r;
    }
    if (t == 255) blockSums[blockIdx.x] = s[255];
}
__global__ void k_scan3(int* __restrict__ row_start, int* __restrict__ cursor,
                        const int* __restrict__ blockOff, int n, int total){
    int i = blockIdx.x*256 + threadIdx.x;
    if (i < n){
        int v = row_start[i] + blockOff[i >> 8];
        row_start[i] = v; cursor[i] = v;
    }
    if (i == 0) row_start[n] = total;
}
__global__ void k_fillcsr(const int* __restrict__ src, const int* __restrict__ dst,
    const float* __restrict__ dinv, int* cursor,
    int* __restrict__ srcs_s, float* __restrict__ ce_s, int e){
    int i = blockIdx.x*256 + threadIdx.x;
    if (i < e){
        int d = dst[i], s = src[i];
        int p = atomicAdd(&cursor[d], 1);
        srcs_s[p] = s;
        ce_s[p] = dinv[s] * dinv[d];
    }
}

// ================= merged conversions (+ counts zeroing) =================
struct CvtArgs { const float* w[17]; const float* w0; const float* s1; const float* s2; const float* x37; };
static constexpr int CVT_W   = 17*16384;
static constexpr int CVT_W0  = 8192;
static constexpr int CVT_S1  = 9600;
static constexpr int CVT_S2  = 128;
static constexpr int CVT_X   = NN*64;
__global__ void k_cvt_all(CvtArgs a, ushort_t* __restrict__ wbf, ushort_t* __restrict__ w0bf,
                          ushort_t* __restrict__ s1bf, ushort_t* __restrict__ s2bf,
                          ushort_t* __restrict__ xb64, int* __restrict__ counts){
    int i = blockIdx.x*256 + threadIdx.x;
    if (i < NN) counts[i] = 0;                       // folded k_zero_i
    if (i < CVT_W){ int idx = i >> 14, off = i & 16383; wbf[i] = f2bf(a.w[idx][off]); return; }
    i -= CVT_W;
    if (i < CVT_W0){ int r = i >> 6, c = i & 63; w0bf[i] = (c < 37) ? f2bf(a.w0[r*37 + c]) : (ushort_t)0; return; }
    i -= CVT_W0;
    if (i < CVT_S1){ s1bf[i] = f2bf(a.s1[i]); return; }
    i -= CVT_S1;
    if (i < CVT_S2){ s2bf[i] = f2bf(a.s2[i]); return; }
    i -= CVT_S2;
    if (i < CVT_X){ int r = i >> 6, c = i & 63; xb64[i] = (c < 37) ? f2bf(a.x37[(size_t)r*37 + c]) : (ushort_t)0; return; }
}

// ========== seed-Q projections + hERG + scan2 fused (5 blocks, 512 thr) ==========
__global__ __launch_bounds__(512) void k_seedq_scan2(
    const ushort_t* __restrict__ s1bf, const ushort_t* __restrict__ s2bf,
    const ushort_t* __restrict__ W1, const float* __restrict__ bias1,
    const ushort_t* __restrict__ W2q, const float* __restrict__ bias2,
    ushort_t* __restrict__ q0, ushort_t* __restrict__ q2,
    const float* __restrict__ hem, const float* __restrict__ hlW,
    const float* __restrict__ hlb, float* __restrict__ hergv,
    const int* __restrict__ blockSums, int* __restrict__ blockOff, int nb)
{
    int blk = blockIdx.x;
    int tid  = threadIdx.x;
    if (blk == 4){
        __shared__ int s[512];
        int t = tid;
        int v = (t < nb) ? blockSums[t] : 0;
        s[t] = v; __syncthreads();
        #pragma unroll
        for (int off = 1; off < 512; off <<= 1){
            int add = (t >= off) ? s[t-off] : 0;
            __syncthreads();
            s[t] += add;
            __syncthreads();
        }
        blockOff[t] = s[t] - v;
        return;
    }
    if (blk == 3){
        __shared__ float e[1280];
        for (int i = tid; i < 1280; i += 512) e[i] = hem[i];
        __syncthreads();
        if (tid < 128){
            float acc = 0.f;
            for (int k = 0; k < 1280; ++k) acc += e[k] * hlW[(size_t)tid*1280 + k];
            hergv[tid] = fmaxf(acc + hlb[tid], 0.f);
        }
        return;
    }
    if (tid >= 256) return;
    const ushort_t* x = (blk < 2) ? s1bf : s2bf;
    const ushort_t* W = (blk < 2) ? W1 : W2q;
    const float* bias = (blk < 2) ? bias1 : bias2;
    ushort_t* out = (blk < 2) ? q0 : q2;
    int M = (blk < 2) ? NS : 1;
    int base = (blk < 2) ? blk*64 : 0;
    int wid  = tid >> 6;
    int lane = tid & 63;
    int l15  = lane & 15, quad = lane >> 4;
    int row0 = base + wid*16;
    int ar   = row0 + l15; if (ar > M-1) ar = M-1;
    const short* xr = (const short*)(x + (size_t)ar*H) + quad*8;
    float4v acc[8];
    #pragma unroll
    for (int i = 0; i < 8; ++i) acc[i] = (float4v)0.f;
    #pragma unroll
    for (int kc = 0; kc < 4; ++kc){
        short8 a = *(const short8*)(xr + kc*32);
        #pragma unroll
        for (int nt = 0; nt < 8; ++nt){
            short8 b = *(const short8*)((const short*)(W + (size_t)(nt*16 + l15)*H) + kc*32 + quad*8);
            acc[nt] = __builtin_amdgcn_mfma_f32_16x16x32_bf16(a, b, acc[nt], 0, 0, 0);
        }
    }
    #pragma unroll
    for (int nt = 0; nt < 8; ++nt){
        int c = nt*16 + l15;
        float bv = bias[c];
        #pragma unroll
        for (int reg = 0; reg < 4; ++reg){
            int r = row0 + quad*4 + reg;
            if (r >= M) continue;
            out[(size_t)r*H + c] = f2bf(acc[nt][reg] + bv);
        }
    }
}

// ========== fused gather + MFMA GEMM v3 (2-edge unroll + index prefetch) ==========
// NOUT==16 writes K/V head-major: record = 32 elems (64B) per (head-pair, node)
template<int NOUT, int RELU, int STAGE2, int MINW>
__global__ __launch_bounds__(256, MINW) void k_conv_fused3(
    const ushort_t* __restrict__ x,
    const int* __restrict__ row_st, const int* __restrict__ srcs,
    const float* __restrict__ ces, const float* __restrict__ selfc,
    const ushort_t* __restrict__ W, const float* __restrict__ bias0,
    const float* __restrict__ bias1,
    const ushort_t* __restrict__ W2, const float* __restrict__ bias2,
    ushort_t* __restrict__ out0, ushort_t* __restrict__ out1)
{
    __shared__ ushort_t As[32][136];
    __shared__ ushort_t Bs[(NOUT==16)?32:1][(NOUT==16)?136:1];
    const int tid = threadIdx.x;
    const int node = tid >> 3, qq = tid & 7;   // 8 threads/node, 16 cols each
    const int g = blockIdx.x*32 + node;
    float acc[16];
    #pragma unroll
    for (int i = 0; i < 16; ++i) acc[i] = 0.f;
    if (g < NN){
        const uint4* xr = (const uint4*)(x + (size_t)g*H + qq*16);
        float sc = selfc[g];
        uint4 u0 = xr[0], u1 = xr[1];
        fma8(acc+0, u0, sc); fma8(acc+8, u1, sc);
        int e = row_st[g], e1 = row_st[g+1];
        int sA = 0, sB = 0; float cA = 0.f, cB = 0.f;
        if (e < e1){ sA = srcs[e]; cA = ces[e]; }
        if (e + 1 < e1){ sB = srcs[e+1]; cB = ces[e+1]; }
        while (e + 2 <= e1){
            int sA2 = 0, sB2 = 0; float cA2 = 0.f, cB2 = 0.f;
            if (e + 2 < e1){ sA2 = srcs[e+2]; cA2 = ces[e+2]; }
            if (e + 3 < e1){ sB2 = srcs[e+3]; cB2 = ces[e+3]; }
            const uint4* pa = (const uint4*)(x + (size_t)sA*H + qq*16);
            const uint4* pb = (const uint4*)(x + (size_t)sB*H + qq*16);
            uint4 a0 = pa[0], a1 = pa[1];
            uint4 c0 = pb[0], c1 = pb[1];
            fma8(acc+0, a0, cA); fma8(acc+8, a1, cA);
            fma8(acc+0, c0, cB); fma8(acc+8, c1, cB);
            sA = sA2; sB = sB2; cA = cA2; cB = cB2;
            e += 2;
        }
        if (e < e1){
            const uint4* pa = (const uint4*)(x + (size_t)sA*H + qq*16);
            uint4 a0 = pa[0], a1 = pa[1];
            fma8(acc+0, a0, cA); fma8(acc+8, a1, cA);
        }
    }
    {
        uint_t* dst = (uint_t*)&As[node][qq*16];
        #pragma unroll
        for (int i = 0; i < 8; ++i)
            dst[i] = (uint_t)f2bf(acc[2*i]) | ((uint_t)f2bf(acc[2*i+1]) << 16);
    }
    __syncthreads();
    const int w = tid >> 6, lane = tid & 63, l15 = lane & 15, quad = lane >> 4;
    const int rt = w & 1;                  // row tile (16 rows)
    constexpr int NT = NOUT/2;             // col tiles per wave
    const int ct0 = (w >> 1) * NT;
    float4v o[NT];
    #pragma unroll
    for (int t = 0; t < NT; ++t) o[t] = (float4v)0.f;
    #pragma unroll
    for (int kc = 0; kc < 4; ++kc){
        short8 a = *(const short8*)(&As[rt*16 + l15][kc*32 + quad*8]);
        #pragma unroll
        for (int t = 0; t < NT; ++t){
            short8 bfr = *(const short8*)(W + (size_t)((ct0 + t)*16 + l15)*H + kc*32 + quad*8);
            o[t] = __builtin_amdgcn_mfma_f32_16x16x32_bf16(a, bfr, o[t], 0, 0, 0);
        }
    }
    __syncthreads();
    #pragma unroll
    for (int t = 0; t < NT; ++t){
        int cg = (ct0 + t)*16 + l15;
        #pragma unroll
        for (int r = 0; r < 4; ++r){
            float v;
            if (NOUT == 8 || cg < 128){
                v = o[t][r] + bias0[cg];
                if (RELU) v = fmaxf(v, 0.f);
                As[rt*16 + quad*4 + r][cg] = f2bf(v);
            } else {
                v = o[t][r] + bias1[cg - 128];
                if (RELU) v = fmaxf(v, 0.f);
                Bs[rt*16 + quad*4 + r][cg - 128] = f2bf(v);
            }
        }
    }
    __syncthreads();
    if (STAGE2){
        float4v o2[4];
        #pragma unroll
        for (int t = 0; t < 4; ++t) o2[t] = (float4v)0.f;
        const int ct2 = (w >> 1) * 4;
        #pragma unroll
        for (int kc = 0; kc < 4; ++kc){
            short8 a = *(const short8*)(&As[rt*16 + l15][kc*32 + quad*8]);
            #pragma unroll
            for (int t = 0; t < 4; ++t){
                short8 bfr = *(const short8*)(W2 + (size_t)((ct2 + t)*16 + l15)*H + kc*32 + quad*8);
                o2[t] = __builtin_amdgcn_mfma_f32_16x16x32_bf16(a, bfr, o2[t], 0, 0, 0);
            }
        }
        __syncthreads();
        #pragma unroll
        for (int t = 0; t < 4; ++t){
            int cg = (ct2 + t)*16 + l15;
            #pragma unroll
            for (int r = 0; r < 4; ++r)
                As[rt*16 + quad*4 + r][cg] = f2bf(o2[t][r] + bias2[cg]);
        }
        __syncthreads();
    }
    if (g < NN){
        if (NOUT == 16){
            size_t kb = ((size_t)(qq >> 1)*NN + (size_t)g)*32 + (size_t)(qq & 1)*16;
            ((uint4*)(out0 + kb))[0] = *(const uint4*)&As[node][qq*16];
            ((uint4*)(out0 + kb))[1] = *(const uint4*)&As[node][qq*16 + 8];
            ((uint4*)(out1 + kb))[0] = *(const uint4*)&Bs[node][qq*16];
            ((uint4*)(out1 + kb))[1] = *(const uint4*)&Bs[node][qq*16 + 8];
        } else {
            uint4* op = (uint4*)(out0 + (size_t)g*H + qq*16);
            const uint4* sp = (const uint4*)&As[node][qq*16];
            op[0] = sp[0]; op[1] = sp[1];
        }
    }
}

// ========== conv0: gather padded-64 bf16 rows + MFMA GEMM (K=64) ==========
__global__ __launch_bounds__(256, 8) void k_conv0b(
    const ushort_t* __restrict__ x,   // [NN][64] bf16
    const int* __restrict__ row_st, const int* __restrict__ srcs,
    const float* __restrict__ ces, const float* __restrict__ selfc,
    const ushort_t* __restrict__ W,   // [128][64]
    const float* __restrict__ bias,
    ushort_t* __restrict__ out)
{
    __shared__ ushort_t As[32][136];
    const int tid = threadIdx.x;
    const int node = tid >> 3, qq = tid & 7;   // 8 cols (1 uint4) each
    const int g = blockIdx.x*32 + node;
    float acc[8];
    #pragma unroll
    for (int i = 0; i < 8; ++i) acc[i] = 0.f;
    if (g < NN){
        const uint4* xr = (const uint4*)(x + (size_t)g*64 + qq*8);
        float sc = selfc[g];
        fma8(acc, xr[0], sc);
        int e = row_st[g], e1 = row_st[g+1];
        int sA = 0, sB = 0; float cA = 0.f, cB = 0.f;
        if (e < e1){ sA = srcs[e]; cA = ces[e]; }
        if (e + 1 < e1){ sB = srcs[e+1]; cB = ces[e+1]; }
        while (e + 2 <= e1){
            int sA2 = 0, sB2 = 0; float cA2 = 0.f, cB2 = 0.f;
            if (e + 2 < e1){ sA2 = srcs[e+2]; cA2 = ces[e+2]; }
            if (e + 3 < e1){ sB2 = srcs[e+3]; cB2 = ces[e+3]; }
            uint4 a0 = *(const uint4*)(x + (size_t)sA*64 + qq*8);
            uint4 c0 = *(const uint4*)(x + (size_t)sB*64 + qq*8);
            fma8(acc, a0, cA);
            fma8(acc, c0, cB);
            sA = sA2; sB = sB2; cA = cA2; cB = cB2;
            e += 2;
        }
        if (e < e1){
            uint4 a0 = *(const uint4*)(x + (size_t)sA*64 + qq*8);
            fma8(acc, a0, cA);
        }
    }
    {
        uint_t* dst = (uint_t*)&As[node][qq*8];
        #pragma unroll
        for (int i = 0; i < 4; ++i)
            dst[i] = (uint_t)f2bf(acc[2*i]) | ((uint_t)f2bf(acc[2*i+1]) << 16);
    }
    __syncthreads();
    const int w = tid >> 6, lane = tid & 63, l15 = lane & 15, quad = lane >> 4;
    const int rt = w & 1;
    const int ct0 = (w >> 1) * 4;
    float4v o[4];
    #pragma unroll
    for (int t = 0; t < 4; ++t) o[t] = (float4v)0.f;
    #pragma unroll
    for (int kc = 0; kc < 2; ++kc){
        short8 a = *(const short8*)(&As[rt*16 + l15][kc*32 + quad*8]);
        #pragma unroll
        for (int t = 0; t < 4; ++t){
            short8 bfr = *(const short8*)(W + (size_t)((ct0 + t)*16 + l15)*64 + kc*32 + quad*8);
            o[t] = __builtin_amdgcn_mfma_f32_16x16x32_bf16(a, bfr, o[t], 0, 0, 0);
        }
    }
    __syncthreads();
    #pragma unroll
    for (int t = 0; t < 4; ++t){
        int cg = (ct0 + t)*16 + l15;
        #pragma unroll
        for (int r = 0; r < 4; ++r)
            As[rt*16 + quad*4 + r][cg] = f2bf(fmaxf(o[t][r] + bias[cg], 0.f));
    }
    __syncthreads();
    if (g < NN){
        uint4* op = (uint4*)(out + (size_t)g*H + qq*16);
        const uint4* sp = (const uint4*)&As[node][qq*16];
        op[0] = sp[0]; op[1] = sp[1];
    }
}

// ========== per-graph tail v5: GMPool_G attn + p1fo rFF + SAB + PMA2 + head MLP ==========
// 512 threads (8 waves), 2 blocks/CU, ~80 KB LDS; P-staging stride 40 (bank-spread)
struct TailArgs {
    const ushort_t* Khm; const ushort_t* Vhm;   // head-major K/V [(hp)*NN + ...]
    const ushort_t* q0;  const ushort_t* q2;
    const ushort_t* p1foW; const float* p1fob;
    const ushort_t* sfqW;  const float* sfqb;
    const ushort_t* skW;   const float* skb;
    const ushort_t* svW;   const float* svb;
    const ushort_t* sfoW;  const float* sfob;
    const ushort_t* p2kW;  const float* p2kb;
    const ushort_t* p2vW;  const float* p2vb;
    const ushort_t* p2foW; const float* p2fob;
    const ushort_t* lin2W; const float* lin2b;
    const float* hergv;
    const float* hoW; const float* hob;
    const float* fcW; const float* fcb;
    const float* sW;  const float* sb;
    float* outp;
};

__global__ __launch_bounds__(512, 4) void k_graph_tail(TailArgs a){
    __shared__ ushort_t bufA[85*136];
    __shared__ ushort_t bufB[80*136];
    __shared__ ushort_t bufC[80*136];
    __shared__ ushort_t vt4[64*104];
    const int b = blockIdx.x, tid = threadIdx.x;
    const int w = tid >> 6, lane = tid & 63, l15 = lane & 15, quad = lane >> 4;

    // ======== A0: GMPool_G attention (xA computed directly into bufA) ========
    // bufB = Ks[2][208][24] staging; bufC = Vs[2][16][232]; vt4 = per-wave P arena (stride 40)
    for (int i = tid; i < 2*16*32; i += 512){
        int hh2 = i >> 9, rr = (i >> 5) & 15, kk = 200 + (i & 31);
        bufC[(hh2*16 + rr)*232 + kk] = 0;
    }
    for (int hp = 0; hp < 4; ++hp){
        __syncthreads();   // protect bufB/C from previous iteration's job reads
        const ushort_t* Kb = a.Khm + ((size_t)hp*NB + b)*(size_t)200*32;
        for (int idx = tid; idx < 200*8; idx += 512){
            int key = idx >> 3, p = idx & 7;
            int hh = p >> 2, dl = (p & 3)*4;
            const uint_t* src = (const uint_t*)(Kb + (size_t)key*32 + hh*16 + dl);
            uint_t* d = (uint_t*)&bufB[(hh*208 + key)*24 + dl];
            d[0] = src[0]; d[1] = src[1];
        }
        const ushort_t* Vb = a.Vhm + ((size_t)hp*NB + b)*(size_t)200*32;
        for (int idx = tid; idx < 200*8; idx += 512){
            int key = idx >> 3, p = idx & 7;
            int hh = p >> 2, dl = (p & 3)*4;
            const ushort_t* src = Vb + (size_t)key*32 + hh*16 + dl;
            bufC[(hh*16 + dl+0)*232 + key] = src[0];
            bufC[(hh*16 + dl+1)*232 + key] = src[1];
            bufC[(hh*16 + dl+2)*232 + key] = src[2];
            bufC[(hh*16 + dl+3)*232 + key] = src[3];
        }
        __syncthreads();
        // 10 jobs (2 local heads x 5 q-tiles) over 8 waves
        for (int j = w; j < 10; j += 8){
            int hl = j / 5, qt = j % 5;
            int gh = hp*2 + hl;
            ushort_t* psw = vt4 + w*640;
            int qr = qt*16 + l15; if (qr > NS-1) qr = NS-1;
            short8 av = *(const short8*)(a.q0 + (size_t)qr*H + gh*16 + (quad & 1)*8);
            short8 zero8 = (short8)0;
            bool klow = (quad < 2);
            short8 afrag = klow ? av : zero8;
            float4v s[13];
            #pragma unroll
            for (int kt = 0; kt < 13; ++kt){
                short8 bv = *(const short8*)(&bufB[(hl*208 + kt*16 + l15)*24 + (quad & 1)*8]);
                short8 bfrag = klow ? bv : zero8;
                s[kt] = __builtin_amdgcn_mfma_f32_16x16x32_bf16(afrag, bfrag, (float4v)0.f, 0, 0, 0);
            }
            float mx[4] = {-1e30f, -1e30f, -1e30f, -1e30f};
            #pragma unroll
            for (int kt = 0; kt < 13; ++kt){
                if (kt*16 + l15 >= 200){ s[kt][0]=-1e30f; s[kt][1]=-1e30f; s[kt][2]=-1e30f; s[kt][3]=-1e30f; }
                #pragma unroll
                for (int r = 0; r < 4; ++r) mx[r] = fmaxf(mx[r], s[kt][r]);
            }
            #pragma unroll
            for (int off = 1; off < 16; off <<= 1){
                #pragma unroll
                for (int r = 0; r < 4; ++r) mx[r] = fmaxf(mx[r], __shfl_xor(mx[r], off));
            }
            float sum[4] = {0.f, 0.f, 0.f, 0.f};
            float4v o = (float4v)0.f;
            #pragma unroll
            for (int kc = 0; kc < 7; ++kc){
                #pragma unroll
                for (int t2 = 0; t2 < 2; ++t2){
                    int kt = kc*2 + t2;
                    #pragma unroll
                    for (int r = 0; r < 4; ++r){
                        float e = 0.f;
                        if (kt < 13){ e = __expf((s[kt][r] - mx[r]) * SCALE); sum[r] += e; }
                        psw[(quad*4 + r)*40 + t2*16 + l15] = f2bf(e);
                    }
                }
                short8 pa = *(const short8*)(psw + l15*40 + quad*8);
                short8 vb = *(const short8*)(&bufC[(hl*16 + l15)*232 + kc*32 + quad*8]);
                o = __builtin_amdgcn_mfma_f32_16x16x32_bf16(pa, vb, o, 0, 0, 0);
            }
            #pragma unroll
            for (int off = 1; off < 16; off <<= 1){
                #pragma unroll
                for (int r = 0; r < 4; ++r) sum[r] += __shfl_xor(sum[r], off);
            }
            #pragma unroll
            for (int r = 0; r < 4; ++r){
                int row = qt*16 + quad*4 + r;
                if (row < NS){
                    float qv = bf2f(a.q0[(size_t)row*H + gh*16 + l15]);
                    bufA[row*136 + gh*16 + l15] = f2bf(qv + o[r] / sum[r]);
                }
            }
        }
    }
    __syncthreads();

    // P1: bufA = xA + relu(xA @ p1foW^T + b) IN-PLACE (waves 0-4); waves 5-7 zero vt4
    if (w >= 5){
        for (int i = tid - 320; i < 64*104/2; i += 192) ((uint_t*)vt4)[i] = 0u;
    }
    for (int rt = w; rt < 5; rt += 8){
        float4v o[8];
        #pragma unroll
        for (int i = 0; i < 8; ++i) o[i] = (float4v)0.f;
        #pragma unroll
        for (int kc = 0; kc < 4; ++kc){
            short8 av = *(const short8*)(bufA + (rt*16 + l15)*136 + kc*32 + quad*8);
            #pragma unroll
            for (int ct = 0; ct < 8; ++ct){
                short8 bv = *(const short8*)((const short*)(a.p1foW + (size_t)(ct*16 + l15)*H) + kc*32 + quad*8);
                o[ct] = __builtin_amdgcn_mfma_f32_16x16x32_bf16(av, bv, o[ct], 0, 0, 0);
            }
        }
        #pragma unroll
        for (int ct = 0; ct < 8; ++ct){
            int c = ct*16 + l15; float bb = a.p1fob[c];
            #pragma unroll
            for (int r = 0; r < 4; ++r){
                int row = rt*16 + quad*4 + r;
                float res = bf2f(bufA[row*136 + c]);
                bufA[row*136 + c] = f2bf(fmaxf(o[ct][r] + bb, 0.f) + res);
            }
        }
    }
    __syncthreads();

    // P2: SAB projections from bufA: Q->bufB, K->bufC
    for (int job = w; job < 40; job += 8){
        int rt = job >> 3, ct = job & 7;
        float4v o = (float4v)0.f;
        #pragma unroll
        for (int kc = 0; kc < 4; ++kc){
            short8 av = *(const short8*)(bufA + (rt*16 + l15)*136 + kc*32 + quad*8);
            short8 bv = *(const short8*)((const short*)(a.sfqW + (size_t)(ct*16 + l15)*H) + kc*32 + quad*8);
            o = __builtin_amdgcn_mfma_f32_16x16x32_bf16(av, bv, o, 0, 0, 0);
        }
        int c = ct*16 + l15; float bb = a.sfqb[c];
        #pragma unroll
        for (int r = 0; r < 4; ++r)
            bufB[(rt*16 + quad*4 + r)*136 + c] = f2bf(o[r] + bb);
    }
    for (int job = w; job < 40; job += 8){
        int rt = job >> 3, ct = job & 7;
        float4v o = (float4v)0.f;
        #pragma unroll
        for (int kc = 0; kc < 4; ++kc){
            short8 av = *(const short8*)(bufA + (rt*16 + l15)*136 + kc*32 + quad*8);
            short8 bv = *(const short8*)((const short*)(a.skW + (size_t)(ct*16 + l15)*H) + kc*32 + quad*8);
            o = __builtin_amdgcn_mfma_f32_16x16x32_bf16(av, bv, o, 0, 0, 0);
        }
        int c = ct*16 + l15; float bb = a.skb[c];
        #pragma unroll
        for (int r = 0; r < 4; ++r)
            bufC[(rt*16 + quad*4 + r)*136 + c] = f2bf(o[r] + bb);
    }
    __syncthreads();

    // P3: SAB attention, two 4-head passes (V-proj over 8 waves; attn on waves 0-3)
    for (int pass = 0; pass < 2; ++pass){
        int hbase = pass*4;
        for (int job = w; job < 20; job += 8){
            int rt = job >> 2, ctl = job & 3;
            int ct = hbase + ctl;
            float4v o = (float4v)0.f;
            #pragma unroll
            for (int kc = 0; kc < 4; ++kc){
                short8 av = *(const short8*)(bufA + (rt*16 + l15)*136 + kc*32 + quad*8);
                short8 bv = *(const short8*)((const short*)(a.svW + (size_t)(ct*16 + l15)*H) + kc*32 + quad*8);
                o = __builtin_amdgcn_mfma_f32_16x16x32_bf16(av, bv, o, 0, 0, 0);
            }
            int c = ct*16 + l15; float bb = a.svb[c];
            #pragma unroll
            for (int r = 0; r < 4; ++r){
                int key = rt*16 + quad*4 + r;
                if (key < NS) vt4[(ctl*16 + l15)*104 + key] = f2bf(o[r] + bb);
            }
        }
        __syncthreads();
        if (w < 4){
            ushort_t* psw = (w == 0) ? bufA + 10200 :
                            (w == 1) ? bufA + 10840 :
                            (w == 2) ? bufB + 10200 : bufC + 10200;
            int hl = w, h = hbase + w;
            short8 zero8 = (short8)0;
            bool klow = (quad < 2);
            for (int qt = 0; qt < 5; ++qt){
                short8 av = *(const short8*)(bufB + (qt*16 + l15)*136 + h*16 + (quad & 1)*8);
                short8 afrag = klow ? av : zero8;
                float4v s[5];
                #pragma unroll
                for (int kt = 0; kt < 5; ++kt){
                    short8 bv = *(const short8*)(bufC + (kt*16 + l15)*136 + h*16 + (quad & 1)*8);
                    short8 bfrag = klow ? bv : zero8;
                    s[kt] = __builtin_amdgcn_mfma_f32_16x16x32_bf16(afrag, bfrag, (float4v)0.f, 0, 0, 0);
                }
                float mx[4] = {-1e30f, -1e30f, -1e30f, -1e30f};
                #pragma unroll
                for (int kt = 0; kt < 5; ++kt){
                    if (kt*16 + l15 >= NS){ s[kt][0]=-1e30f; s[kt][1]=-1e30f; s[kt][2]=-1e30f; s[kt][3]=-1e30f; }
                    #pragma unroll
                    for (int r = 0; r < 4; ++r) mx[r] = fmaxf(mx[r], s[kt][r]);
                }
                #pragma unroll
                for (int off = 1; off < 16; off <<= 1){
                    #pragma unroll
                    for (int r = 0; r < 4; ++r) mx[r] = fmaxf(mx[r], __shfl_xor(mx[r], off));
                }
                float sum[4] = {0.f, 0.f, 0.f, 0.f};
                float4v o = (float4v)0.f;
                #pragma unroll
                for (int kc = 0; kc < 3; ++kc){
                    #pragma unroll
                    for (int t2 = 0; t2 < 2; ++t2){
                        int kt = kc*2 + t2;
                        #pragma unroll
                        for (int r = 0; r < 4; ++r){
                            float e = 0.f;
                            if (kt < 5){ e = __expf((s[kt][r] - mx[r]) * SCALE); sum[r] += e; }
                            psw[(quad*4 + r)*40 + t2*16 + l15] = f2bf(e);
                        }
                    }
                    short8 pa = *(const short8*)(psw + l15*40 + quad*8);
                    short8 vb = *(const short8*)(vt4 + (hl*16 + l15)*104 + kc*32 + quad*8);
                    o = __builtin_amdgcn_mfma_f32_16x16x32_bf16(pa, vb, o, 0, 0, 0);
                }
                #pragma unroll
                for (int off = 1; off < 16; off <<= 1){
                    #pragma unroll
                    for (int r = 0; r < 4; ++r) sum[r] += __shfl_xor(sum[r], off);
                }
                #pragma unroll
                for (int r = 0; r < 4; ++r){
                    int row = qt*16 + quad*4 + r;
                    if (row < NS){
                        float qv = bf2f(bufB[row*136 + h*16 + l15]);
                        bufB[row*136 + h*16 + l15] = f2bf(qv + o[r] / sum[r]);
                    }
                }
            }
        }
        __syncthreads();
    }

    // P4: xb2 = attnout(bufB) + relu(attnout @ sfoW^T + b) -> bufA (xb1 dead)
    for (int job = w; job < 40; job += 8){
        int rt = job >> 3, ct = job & 7;
        float4v o = (float4v)0.f;
        #pragma unroll
        for (int kc = 0; kc < 4; ++kc){
            short8 av = *(const short8*)(bufB + (rt*16 + l15)*136 + kc*32 + quad*8);
            short8 bv = *(const short8*)((const short*)(a.sfoW + (size_t)(ct*16 + l15)*H) + kc*32 + quad*8);
            o = __builtin_amdgcn_mfma_f32_16x16x32_bf16(av, bv, o, 0, 0, 0);
        }
        int c = ct*16 + l15; float bb = a.sfob[c];
        #pragma unroll
        for (int r = 0; r < 4; ++r){
            int row = rt*16 + quad*4 + r;
            bufA[row*136 + c] = f2bf(fmaxf(o[r] + bb, 0.f) + bf2f(bufB[row*136 + c]));
        }
    }
    __syncthreads();

    // P5: PMA2 K -> bufC, V -> bufB (from bufA = xb2)
    for (int job = w; job < 40; job += 8){
        int rt = job >> 3, ct = job & 7;
        float4v o = (float4v)0.f;
        #pragma unroll
        for (int kc = 0; kc < 4; ++kc){
            short8 av = *(const short8*)(bufA + (rt*16 + l15)*136 + kc*32 + quad*8);
            short8 bv = *(const short8*)((const short*)(a.p2kW + (size_t)(ct*16 + l15)*H) + kc*32 + quad*8);
            o = __builtin_amdgcn_mfma_f32_16x16x32_bf16(av, bv, o, 0, 0, 0);
        }
        int c = ct*16 + l15; float bb = a.p2kb[c];
        #pragma unroll
        for (int r = 0; r < 4; ++r)
            bufC[(rt*16 + quad*4 + r)*136 + c] = f2bf(o[r] + bb);
    }
    for (int job = w; job < 40; job += 8){
        int rt = job >> 3, ct = job & 7;
        float4v o = (float4v)0.f;
        #pragma unroll
        for (int kc = 0; kc < 4; ++kc){
            short8 av = *(const short8*)(bufA + (rt*16 + l15)*136 + kc*32 + quad*8);
            short8 bv = *(const short8*)((const short*)(a.p2vW + (size_t)(ct*16 + l15)*H) + kc*32 + quad*8);
            o = __builtin_amdgcn_mfma_f32_16x16x32_bf16(av, bv, o, 0, 0, 0);
        }
        int c = ct*16 + l15; float bb = a.p2vb[c];
        #pragma unroll
        for (int r = 0; r < 4; ++r)
            bufB[(rt*16 + quad*4 + r)*136 + c] = f2bf(o[r] + bb);
    }
    __syncthreads();

    // P6: 1-seed attention + p2fo residual + lin2 + head MLP (scratch aliases bufA)
    {
        int t = tid;
        char* sb8 = (char*)bufA;
        float* sc       = (float*)sb8;              // 8*76 floats
        float* sumh     = (float*)(sb8 + 2432);     // 8
        ushort_t* xa    = (ushort_t*)(sb8 + 2464);  // 128
        ushort_t* xb3   = (ushort_t*)(sb8 + 2720);  // 128
        float* tt       = (float*)(sb8 + 2976);     // 128
        float* v256     = (float*)(sb8 + 3488);     // 256
        float* red      = (float*)(sb8 + 4512);     // 128
        if (t < 256){
            int h = t >> 5, l32 = t & 31;
            const ushort_t* qr = a.q2 + h*16;
            for (int k = l32; k < NS; k += 32){
                float s = 0.f;
                #pragma unroll
                for (int d = 0; d < 16; ++d) s += bf2f(qr[d]) * bf2f(bufC[k*136 + h*16 + d]);
                sc[h*76 + k] = s;
            }
        }
        __syncthreads();
        if (t < 128){
            int hh = t >> 4, i = t & 15;
            float mx = -1e30f;
            for (int k = i; k < NS; k += 16) mx = fmaxf(mx, sc[hh*76 + k]);
            #pragma unroll
            for (int off = 1; off < 16; off <<= 1) mx = fmaxf(mx, __shfl_xor(mx, off));
            float sm = 0.f;
            for (int k = i; k < NS; k += 16){
                float e = __expf((sc[hh*76 + k] - mx) * SCALE);
                sc[hh*76 + k] = e;
                sm += e;
            }
            #pragma unroll
            for (int off = 1; off < 16; off <<= 1) sm += __shfl_xor(sm, off);
            if (i == 0) sumh[hh] = sm;
        }
        __syncthreads();
        if (t < 128){
            int hh = t >> 4;
            float o = 0.f;
            for (int k = 0; k < NS; ++k) o += sc[hh*76 + k] * bf2f(bufB[k*136 + t]);
            xa[t] = f2bf(bf2f(a.q2[t]) + o / sumh[hh]);
        }
        __syncthreads();
        if (t < 128){
            float acc = 0.f;
            const ushort_t* wr = a.p2foW + (size_t)t*H;
            for (int k = 0; k < H; ++k) acc += bf2f(xa[k]) * bf2f(wr[k]);
            xb3[t] = f2bf(fmaxf(acc + a.p2fob[t], 0.f) + bf2f(xa[t]));
        }
        __syncthreads();
        if (t < 128){
            float acc = 0.f;
            const ushort_t* wr = a.lin2W + (size_t)t*H;
            for (int k = 0; k < H; ++k) acc += bf2f(xb3[k]) * bf2f(wr[k]);
            v256[t] = acc + a.lin2b[t];
            v256[128 + t] = a.hergv[t];
        }
        __syncthreads();
        if (t < 128){
            float acc = 0.f;
            const float* wr = a.hoW + (size_t)t*256;
            for (int k = 0; k < 256; ++k) acc += v256[k] * wr[k];
            tt[t] = fmaxf(acc + a.hob[t], 0.f);
        }
        __syncthreads();
        if (t < 128){
            float acc = 0.f;
            const float* wr = a.fcW + (size_t)t*128;
            for (int k = 0; k < 128; ++k) acc += tt[k] * wr[k];
            float uv = fmaxf(acc + a.fcb[t], 0.f);
            red[t] = uv * a.sW[t];
        }
        __syncthreads();
        for (int s = 64; s > 0; s >>= 1){
            if (t < s) red[t] += red[t + s];
            __syncthreads();
        }
        if (t == 0){
            float logit = red[0] + a.sb[0];
            a.outp[b] = 1.f / (1.f + expf(-logit));
        }
    }
}

extern "C" void kernel_launch(void* const* d_in, const int* in_sizes, int n_in,
                              void* d_out, int out_size, void* d_ws, size_t ws_size,
                              hipStream_t stream)
{
    (void)in_sizes; (void)n_in; (void)out_size; (void)ws_size;
    const float* herg_em = (const float*)d_in[0];
    const float* x_in    = (const float*)d_in[1];
    const float* convW[4] = {(const float*)d_in[4], (const float*)d_in[6], (const float*)d_in[8], (const float*)d_in[10]};
    const float* convB[4] = {(const float*)d_in[5], (const float*)d_in[7], (const float*)d_in[9], (const float*)d_in[11]};
    const float* lin1W = (const float*)d_in[12]; const float* lin1b = (const float*)d_in[13];
    const float* lin2W = (const float*)d_in[14]; const float* lin2b = (const float*)d_in[15];
    const float* S1    = (const float*)d_in[16];
    const float* p1fqW = (const float*)d_in[17]; const float* p1fqb = (const float*)d_in[18];
    const float* p1kW  = (const float*)d_in[19]; const float* p1kb  = (const float*)d_in[20];
    const float* p1vW  = (const float*)d_in[21]; const float* p1vb  = (const float*)d_in[22];
    const float* p1foW = (const float*)d_in[23]; const float* p1fob = (const float*)d_in[24];
    const float* sfqW  = (const float*)d_in[25]; const float* sfqb  = (const float*)d_in[26];
    const float* skW   = (const float*)d_in[27]; const float* skb   = (const float*)d_in[28];
    const float* svW   = (const float*)d_in[29]; const float* svb   = (const float*)d_in[30];
    const float* sfoW  = (const float*)d_in[31]; const float* sfob  = (const float*)d_in[32];
    const float* p2fqW = (const float*)d_in[33]; const float* p2fqb = (const float*)d_in[34];
    const float* p2kW  = (const float*)d_in[35]; const float* p2kb  = (const float*)d_in[36];
    const float* p2vW  = (const float*)d_in[37]; const float* p2vb  = (const float*)d_in[38];
    const float* p2foW = (const float*)d_in[39]; const float* p2fob = (const float*)d_in[40];
    const float* S2    = (const float*)d_in[41];
    const float* hlW   = (const float*)d_in[42]; const float* hlb   = (const float*)d_in[43];
    const float* hoW   = (const float*)d_in[44]; const float* hob   = (const float*)d_in[45];
    const float* fcW   = (const float*)d_in[46]; const float* fcb   = (const float*)d_in[47];
    const float* sW    = (const float*)d_in[48]; const float* sb    = (const float*)d_in[49];
    const int*  ei    = (const int*)d_in[50];
    const int*  esrc  = ei;
    const int*  edst  = ei + NE;
    float* outp = (float*)d_out;

    // -------- workspace layout (byte offsets, 16B-aligned) --------
    char* WS = (char*)d_ws;
    int*   counts = (int*)(WS + 0);
    int*   cursor = (int*)(WS + 400384);
    int*   row_st = (int*)(WS + 800768);
    int*   bSums  = (int*)(WS + 1201152);
    int*   bOff   = (int*)(WS + 1203200);
    float* dinv   = (float*)(WS + 1205248);
    float* selfc  = (float*)(WS + 1605632);
    int*   srcs_s = (int*)(WS + 2005632);
    float* ce_s   = (float*)(WS + 3605632);
    ushort_t* wbf = (ushort_t*)(WS + 5205632); // 17*16384
    ushort_t* w0bf= (ushort_t*)(WS + 5762688);
    ushort_t* s1bf= (ushort_t*)(WS + 5779072);
    ushort_t* s2bf= (ushort_t*)(WS + 5798272);
    ushort_t* q0  = (ushort_t*)(WS + 5798528);
    ushort_t* q2  = (ushort_t*)(WS + 5817728);
    float* hergv  = (float*)(WS + 5817984);
    ushort_t* xb64= (ushort_t*)(WS + 6074496); // NN*64 bf16 padded raw x
    ushort_t* b0  = (ushort_t*)(WS + 18874496);// NN*128
    ushort_t* b1  = (ushort_t*)(WS + 44474496);
    ushort_t* b2  = (ushort_t*)(WS + 70074496);

    const int gN   = (NN + 255)/256;       // 391
    const int gE   = (NE + 255)/256;       // 1563
    const int gC   = (NN + 31)/32;         // 3125

    // ---- merged weight/input conversions + counts zeroing (1 launch, FIRST) ----
    CvtArgs ca;
    ca.w[0]=convW[1]; ca.w[1]=convW[2]; ca.w[2]=convW[3]; ca.w[3]=lin1W; ca.w[4]=lin2W;
    ca.w[5]=p1kW; ca.w[6]=p1vW; ca.w[7]=p1foW;
    ca.w[8]=sfqW; ca.w[9]=skW; ca.w[10]=svW; ca.w[11]=sfoW;
    ca.w[12]=p2kW; ca.w[13]=p2vW; ca.w[14]=p2foW; ca.w[15]=p1fqW; ca.w[16]=p2fqW;
    ca.w0 = convW[0]; ca.s1 = S1; ca.s2 = S2; ca.x37 = x_in;
    const int cvtTotal = CVT_W + CVT_W0 + CVT_S1 + CVT_S2 + CVT_X;
    k_cvt_all<<<(cvtTotal + 255)/256, 256, 0, stream>>>(ca, wbf, w0bf, s1bf, s2bf, xb64, counts);

    // ---- CSR build (+ seedQ/hERG/scan2 merged) ----
    k_hist  <<<gE, 256, 0, stream>>>(counts, edst, NE);
    k_scan1 <<<gN, 256, 0, stream>>>(counts, row_st, bSums, dinv, selfc, NN);
    k_seedq_scan2<<<5, 512, 0, stream>>>(s1bf, s2bf, wbf + (size_t)15*16384, p1fqb,
                                   wbf + (size_t)16*16384, p2fqb, q0, q2,
                                   herg_em, hlW, hlb, hergv,
                                   bSums, bOff, gN);
    k_scan3 <<<gN, 256, 0, stream>>>(row_st, cursor, bOff, NN, NE);
    k_fillcsr<<<gE, 256, 0, stream>>>(esrc, edst, dinv, cursor, srcs_s, ce_s, NE);

    // ---- conv0 (fused gather64 + GEMM) -> b0 ----
    k_conv0b<<<gC, 256, 0, stream>>>(xb64, row_st, srcs_s, ce_s, selfc, w0bf, convB[0], b0);
    // ---- conv1, conv2 ----
    k_conv_fused3<8,1,0,8><<<gC, 256, 0, stream>>>(b0, row_st, srcs_s, ce_s, selfc,
        wbf + (size_t)0*16384, convB[1], nullptr, nullptr, nullptr, b1, nullptr);
    k_conv_fused3<8,1,0,8><<<gC, 256, 0, stream>>>(b1, row_st, srcs_s, ce_s, selfc,
        wbf + (size_t)1*16384, convB[2], nullptr, nullptr, nullptr, b0, nullptr);
    // ---- conv3 + lin1 fused -> hx in b1 ----
    k_conv_fused3<8,1,1,8><<<gC, 256, 0, stream>>>(b0, row_st, srcs_s, ce_s, selfc,
        wbf + (size_t)2*16384, convB[3], nullptr, wbf + (size_t)3*16384, lin1b, b1, nullptr);
    // ---- pma1 K,V: fused shared-gather + dual GEMM, HEAD-MAJOR out (K->b2, V->b0) ----
    k_conv_fused3<16,0,0,4><<<gC, 256, 0, stream>>>(b1, row_st, srcs_s, ce_s, selfc,
        wbf + (size_t)5*16384, p1kb, p1vb, nullptr, nullptr, b2, b0);

    // ---- per-graph tail v5: GMPool_G attn + p1fo + SAB + PMA2 + head -> out ----
    TailArgs ta;
    ta.Khm = b2; ta.Vhm = b0; ta.q0 = q0; ta.q2 = q2;
    ta.p1foW = wbf + (size_t)7*16384;  ta.p1fob = p1fob;
    ta.sfqW  = wbf + (size_t)8*16384;  ta.sfqb  = sfqb;
    ta.skW   = wbf + (size_t)9*16384;  ta.skb   = skb;
    ta.svW   = wbf + (size_t)10*16384; ta.svb   = svb;
    ta.sfoW  = wbf + (size_t)11*16384; ta.sfob  = sfob;
    ta.p2kW  = wbf + (size_t)12*16384; ta.p2kb  = p2kb;
    ta.p2vW  = wbf + (size_t)13*16384; ta.p2vb  = p2vb;
    ta.p2foW = wbf + (size_t)14*16384; ta.p2fob = p2fob;
    ta.lin2W = wbf + (size_t)4*16384;  ta.lin2b = lin2b;
    ta.hergv = hergv;
    ta.hoW = hoW; ta.hob = hob;
    ta.fcW = fcW; ta.fcb = fcb;
    ta.sW = sW; ta.sb = sb;
    ta.outp = outp;
    k_graph_tail<<<NB, 512, 0, stream>>>(ta);
}

// Round 14
// 628.942 us; speedup vs baseline: 2.5425x; 1.0135x over previous
//
#include <hip/hip_runtime.h>
#include <hip/hip_bf16.h>

typedef unsigned short ushort_t;
typedef unsigned int uint_t;
typedef __attribute__((ext_vector_type(8))) short short8;
typedef __attribute__((ext_vector_type(4))) float float4v;

static constexpr int NN  = 100000;   // nodes
static constexpr int NE  = 400000;   // edges
static constexpr int NB  = 500;      // graphs
static constexpr int NS  = 75;       // seeds
static constexpr int H   = 128;
static constexpr float SCALE = 0.08838834764831845f; // 1/sqrt(128)

union U32 { uint_t u; float f; };
__device__ __forceinline__ float bf2f(ushort_t b){ U32 t; t.u = ((uint_t)b) << 16; return t.f; }
__device__ __forceinline__ ushort_t f2bf(float f){
    U32 t; t.f = f;
    uint_t r = t.u + 0x7fffu + ((t.u >> 16) & 1u);   // RNE
    return (ushort_t)(r >> 16);
}
__device__ __forceinline__ void fma8(float* a, uint4 u, float c){
    a[0] += c * bf2f((ushort_t)(u.x & 0xffff)); a[1] += c * bf2f((ushort_t)(u.x >> 16));
    a[2] += c * bf2f((ushort_t)(u.y & 0xffff)); a[3] += c * bf2f((ushort_t)(u.y >> 16));
    a[4] += c * bf2f((ushort_t)(u.z & 0xffff)); a[5] += c * bf2f((ushort_t)(u.z >> 16));
    a[6] += c * bf2f((ushort_t)(u.w & 0xffff)); a[7] += c * bf2f((ushort_t)(u.w >> 16));
}

// ================= CSR build =================
__global__ void k_hist(int* counts, const int* __restrict__ dst, int e){
    int i = blockIdx.x*256 + threadIdx.x;
    if (i < e) atomicAdd(&counts[dst[i]], 1);
}
// scan + degree norms fused
__global__ __launch_bounds__(256) void k_scan1(const int* __restrict__ counts,
    int* __restrict__ row_start, int* __restrict__ blockSums,
    float* __restrict__ dinv, float* __restrict__ selfc, int n){
    __shared__ int s[256];
    int t = threadIdx.x, i = blockIdx.x*256 + t;
    int v = (i < n) ? counts[i] : 0;
    s[t] = v; __syncthreads();
    #pragma unroll
    for (int off = 1; off < 256; off <<= 1){
        int add = (t >= off) ? s[t-off] : 0;
        __syncthreads();
        s[t] += add;
        __syncthreads();
    }
    if (i < n){
        row_start[i] = s[t] - v;
        float r = rsqrtf(1.f + (float)v);
        dinv[i] = r; selfc[i] = r*r;
    }
    if (t == 255) blockSums[blockIdx.x] = s[255];
}
__global__ void k_scan3(int* __restrict__ row_start, int* __restrict__ cursor,
                        const int* __restrict__ blockOff, int n, int total){
    int i = blockIdx.x*256 + threadIdx.x;
    if (i < n){
        int v = row_start[i] + blockOff[i >> 8];
        row_start[i] = v; cursor[i] = v;
    }
    if (i == 0) row_start[n] = total;
}
__global__ void k_fillcsr(const int* __restrict__ src, const int* __restrict__ dst,
    const float* __restrict__ dinv, int* cursor,
    int* __restrict__ srcs_s, float* __restrict__ ce_s, int e){
    int i = blockIdx.x*256 + threadIdx.x;
    if (i < e){
        int d = dst[i], s = src[i];
        int p = atomicAdd(&cursor[d], 1);
        srcs_s[p] = s;
        ce_s[p] = dinv[s] * dinv[d];
    }
}

// ================= merged conversions (+ counts zeroing) =================
struct CvtArgs { const float* w[17]; const float* w0; const float* s1; const float* s2; const float* x37; };
static constexpr int CVT_W   = 17*16384;
static constexpr int CVT_W0  = 8192;
static constexpr int CVT_S1  = 9600;
static constexpr int CVT_S2  = 128;
static constexpr int CVT_X   = NN*64;
__global__ void k_cvt_all(CvtArgs a, ushort_t* __restrict__ wbf, ushort_t* __restrict__ w0bf,
                          ushort_t* __restrict__ s1bf, ushort_t* __restrict__ s2bf,
                          ushort_t* __restrict__ xb64, int* __restrict__ counts){
    int i = blockIdx.x*256 + threadIdx.x;
    if (i < NN) counts[i] = 0;                       // folded k_zero_i
    if (i < CVT_W){ int idx = i >> 14, off = i & 16383; wbf[i] = f2bf(a.w[idx][off]); return; }
    i -= CVT_W;
    if (i < CVT_W0){ int r = i >> 6, c = i & 63; w0bf[i] = (c < 37) ? f2bf(a.w0[r*37 + c]) : (ushort_t)0; return; }
    i -= CVT_W0;
    if (i < CVT_S1){ s1bf[i] = f2bf(a.s1[i]); return; }
    i -= CVT_S1;
    if (i < CVT_S2){ s2bf[i] = f2bf(a.s2[i]); return; }
    i -= CVT_S2;
    if (i < CVT_X){ int r = i >> 6, c = i & 63; xb64[i] = (c < 37) ? f2bf(a.x37[(size_t)r*37 + c]) : (ushort_t)0; return; }
}

// ========== seed-Q projections + hERG + scan2 fused (5 blocks, 512 thr) ==========
__global__ __launch_bounds__(512) void k_seedq_scan2(
    const ushort_t* __restrict__ s1bf, const ushort_t* __restrict__ s2bf,
    const ushort_t* __restrict__ W1, const float* __restrict__ bias1,
    const ushort_t* __restrict__ W2q, const float* __restrict__ bias2,
    ushort_t* __restrict__ q0, ushort_t* __restrict__ q2,
    const float* __restrict__ hem, const float* __restrict__ hlW,
    const float* __restrict__ hlb, float* __restrict__ hergv,
    const int* __restrict__ blockSums, int* __restrict__ blockOff, int nb)
{
    int blk = blockIdx.x;
    int tid  = threadIdx.x;
    if (blk == 4){
        __shared__ int s[512];
        int t = tid;
        int v = (t < nb) ? blockSums[t] : 0;
        s[t] = v; __syncthreads();
        #pragma unroll
        for (int off = 1; off < 512; off <<= 1){
            int add = (t >= off) ? s[t-off] : 0;
            __syncthreads();
            s[t] += add;
            __syncthreads();
        }
        blockOff[t] = s[t] - v;
        return;
    }
    if (blk == 3){
        __shared__ float e[1280];
        for (int i = tid; i < 1280; i += 512) e[i] = hem[i];
        __syncthreads();
        if (tid < 128){
            float acc = 0.f;
            for (int k = 0; k < 1280; ++k) acc += e[k] * hlW[(size_t)tid*1280 + k];
            hergv[tid] = fmaxf(acc + hlb[tid], 0.f);
        }
        return;
    }
    if (tid >= 256) return;
    const ushort_t* x = (blk < 2) ? s1bf : s2bf;
    const ushort_t* W = (blk < 2) ? W1 : W2q;
    const float* bias = (blk < 2) ? bias1 : bias2;
    ushort_t* out = (blk < 2) ? q0 : q2;
    int M = (blk < 2) ? NS : 1;
    int base = (blk < 2) ? blk*64 : 0;
    int wid  = tid >> 6;
    int lane = tid & 63;
    int l15  = lane & 15, quad = lane >> 4;
    int row0 = base + wid*16;
    int ar   = row0 + l15; if (ar > M-1) ar = M-1;
    const short* xr = (const short*)(x + (size_t)ar*H) + quad*8;
    float4v acc[8];
    #pragma unroll
    for (int i = 0; i < 8; ++i) acc[i] = (float4v)0.f;
    #pragma unroll
    for (int kc = 0; kc < 4; ++kc){
        short8 a = *(const short8*)(xr + kc*32);
        #pragma unroll
        for (int nt = 0; nt < 8; ++nt){
            short8 b = *(const short8*)((const short*)(W + (size_t)(nt*16 + l15)*H) + kc*32 + quad*8);
            acc[nt] = __builtin_amdgcn_mfma_f32_16x16x32_bf16(a, b, acc[nt], 0, 0, 0);
        }
    }
    #pragma unroll
    for (int nt = 0; nt < 8; ++nt){
        int c = nt*16 + l15;
        float bv = bias[c];
        #pragma unroll
        for (int reg = 0; reg < 4; ++reg){
            int r = row0 + quad*4 + reg;
            if (r >= M) continue;
            out[(size_t)r*H + c] = f2bf(acc[nt][reg] + bv);
        }
    }
}

// ========== fused gather + MFMA GEMM v3 (2-edge unroll + index prefetch) ==========
// NOUT==16 writes K/V head-major: record = 32 elems (64B) per (head-pair, node)
template<int NOUT, int RELU, int STAGE2, int MINW>
__global__ __launch_bounds__(256, MINW) void k_conv_fused3(
    const ushort_t* __restrict__ x,
    const int* __restrict__ row_st, const int* __restrict__ srcs,
    const float* __restrict__ ces, const float* __restrict__ selfc,
    const ushort_t* __restrict__ W, const float* __restrict__ bias0,
    const float* __restrict__ bias1,
    const ushort_t* __restrict__ W2, const float* __restrict__ bias2,
    ushort_t* __restrict__ out0, ushort_t* __restrict__ out1)
{
    __shared__ ushort_t As[32][136];
    __shared__ ushort_t Bs[(NOUT==16)?32:1][(NOUT==16)?136:1];
    const int tid = threadIdx.x;
    const int node = tid >> 3, qq = tid & 7;   // 8 threads/node, 16 cols each
    const int g = blockIdx.x*32 + node;
    float acc[16];
    #pragma unroll
    for (int i = 0; i < 16; ++i) acc[i] = 0.f;
    if (g < NN){
        const uint4* xr = (const uint4*)(x + (size_t)g*H + qq*16);
        float sc = selfc[g];
        uint4 u0 = xr[0], u1 = xr[1];
        fma8(acc+0, u0, sc); fma8(acc+8, u1, sc);
        int e = row_st[g], e1 = row_st[g+1];
        int sA = 0, sB = 0; float cA = 0.f, cB = 0.f;
        if (e < e1){ sA = srcs[e]; cA = ces[e]; }
        if (e + 1 < e1){ sB = srcs[e+1]; cB = ces[e+1]; }
        while (e + 2 <= e1){
            int sA2 = 0, sB2 = 0; float cA2 = 0.f, cB2 = 0.f;
            if (e + 2 < e1){ sA2 = srcs[e+2]; cA2 = ces[e+2]; }
            if (e + 3 < e1){ sB2 = srcs[e+3]; cB2 = ces[e+3]; }
            const uint4* pa = (const uint4*)(x + (size_t)sA*H + qq*16);
            const uint4* pb = (const uint4*)(x + (size_t)sB*H + qq*16);
            uint4 a0 = pa[0], a1 = pa[1];
            uint4 c0 = pb[0], c1 = pb[1];
            fma8(acc+0, a0, cA); fma8(acc+8, a1, cA);
            fma8(acc+0, c0, cB); fma8(acc+8, c1, cB);
            sA = sA2; sB = sB2; cA = cA2; cB = cB2;
            e += 2;
        }
        if (e < e1){
            const uint4* pa = (const uint4*)(x + (size_t)sA*H + qq*16);
            uint4 a0 = pa[0], a1 = pa[1];
            fma8(acc+0, a0, cA); fma8(acc+8, a1, cA);
        }
    }
    {
        uint_t* dst = (uint_t*)&As[node][qq*16];
        #pragma unroll
        for (int i = 0; i < 8; ++i)
            dst[i] = (uint_t)f2bf(acc[2*i]) | ((uint_t)f2bf(acc[2*i+1]) << 16);
    }
    __syncthreads();
    const int w = tid >> 6, lane = tid & 63, l15 = lane & 15, quad = lane >> 4;
    const int rt = w & 1;                  // row tile (16 rows)
    constexpr int NT = NOUT/2;             // col tiles per wave
    const int ct0 = (w >> 1) * NT;
    float4v o[NT];
    #pragma unroll
    for (int t = 0; t < NT; ++t) o[t] = (float4v)0.f;
    #pragma unroll
    for (int kc = 0; kc < 4; ++kc){
        short8 a = *(const short8*)(&As[rt*16 + l15][kc*32 + quad*8]);
        #pragma unroll
        for (int t = 0; t < NT; ++t){
            short8 bfr = *(const short8*)(W + (size_t)((ct0 + t)*16 + l15)*H + kc*32 + quad*8);
            o[t] = __builtin_amdgcn_mfma_f32_16x16x32_bf16(a, bfr, o[t], 0, 0, 0);
        }
    }
    __syncthreads();
    #pragma unroll
    for (int t = 0; t < NT; ++t){
        int cg = (ct0 + t)*16 + l15;
        #pragma unroll
        for (int r = 0; r < 4; ++r){
            float v;
            if (NOUT == 8 || cg < 128){
                v = o[t][r] + bias0[cg];
                if (RELU) v = fmaxf(v, 0.f);
                As[rt*16 + quad*4 + r][cg] = f2bf(v);
            } else {
                v = o[t][r] + bias1[cg - 128];
                if (RELU) v = fmaxf(v, 0.f);
                Bs[rt*16 + quad*4 + r][cg - 128] = f2bf(v);
            }
        }
    }
    __syncthreads();
    if (STAGE2){
        float4v o2[4];
        #pragma unroll
        for (int t = 0; t < 4; ++t) o2[t] = (float4v)0.f;
        const int ct2 = (w >> 1) * 4;
        #pragma unroll
        for (int kc = 0; kc < 4; ++kc){
            short8 a = *(const short8*)(&As[rt*16 + l15][kc*32 + quad*8]);
            #pragma unroll
            for (int t = 0; t < 4; ++t){
                short8 bfr = *(const short8*)(W2 + (size_t)((ct2 + t)*16 + l15)*H + kc*32 + quad*8);
                o2[t] = __builtin_amdgcn_mfma_f32_16x16x32_bf16(a, bfr, o2[t], 0, 0, 0);
            }
        }
        __syncthreads();
        #pragma unroll
        for (int t = 0; t < 4; ++t){
            int cg = (ct2 + t)*16 + l15;
            #pragma unroll
            for (int r = 0; r < 4; ++r)
                As[rt*16 + quad*4 + r][cg] = f2bf(o2[t][r] + bias2[cg]);
        }
        __syncthreads();
    }
    if (g < NN){
        if (NOUT == 16){
            size_t kb = ((size_t)(qq >> 1)*NN + (size_t)g)*32 + (size_t)(qq & 1)*16;
            ((uint4*)(out0 + kb))[0] = *(const uint4*)&As[node][qq*16];
            ((uint4*)(out0 + kb))[1] = *(const uint4*)&As[node][qq*16 + 8];
            ((uint4*)(out1 + kb))[0] = *(const uint4*)&Bs[node][qq*16];
            ((uint4*)(out1 + kb))[1] = *(const uint4*)&Bs[node][qq*16 + 8];
        } else {
            uint4* op = (uint4*)(out0 + (size_t)g*H + qq*16);
            const uint4* sp = (const uint4*)&As[node][qq*16];
            op[0] = sp[0]; op[1] = sp[1];
        }
    }
}

// ========== conv0: gather padded-64 bf16 rows + MFMA GEMM (K=64) ==========
__global__ __launch_bounds__(256, 8) void k_conv0b(
    const ushort_t* __restrict__ x,   // [NN][64] bf16
    const int* __restrict__ row_st, const int* __restrict__ srcs,
    const float* __restrict__ ces, const float* __restrict__ selfc,
    const ushort_t* __restrict__ W,   // [128][64]
    const float* __restrict__ bias,
    ushort_t* __restrict__ out)
{
    __shared__ ushort_t As[32][136];
    const int tid = threadIdx.x;
    const int node = tid >> 3, qq = tid & 7;   // 8 cols (1 uint4) each
    const int g = blockIdx.x*32 + node;
    float acc[8];
    #pragma unroll
    for (int i = 0; i < 8; ++i) acc[i] = 0.f;
    if (g < NN){
        const uint4* xr = (const uint4*)(x + (size_t)g*64 + qq*8);
        float sc = selfc[g];
        fma8(acc, xr[0], sc);
        int e = row_st[g], e1 = row_st[g+1];
        int sA = 0, sB = 0; float cA = 0.f, cB = 0.f;
        if (e < e1){ sA = srcs[e]; cA = ces[e]; }
        if (e + 1 < e1){ sB = srcs[e+1]; cB = ces[e+1]; }
        while (e + 2 <= e1){
            int sA2 = 0, sB2 = 0; float cA2 = 0.f, cB2 = 0.f;
            if (e + 2 < e1){ sA2 = srcs[e+2]; cA2 = ces[e+2]; }
            if (e + 3 < e1){ sB2 = srcs[e+3]; cB2 = ces[e+3]; }
            uint4 a0 = *(const uint4*)(x + (size_t)sA*64 + qq*8);
            uint4 c0 = *(const uint4*)(x + (size_t)sB*64 + qq*8);
            fma8(acc, a0, cA);
            fma8(acc, c0, cB);
            sA = sA2; sB = sB2; cA = cA2; cB = cB2;
            e += 2;
        }
        if (e < e1){
            uint4 a0 = *(const uint4*)(x + (size_t)sA*64 + qq*8);
            fma8(acc, a0, cA);
        }
    }
    {
        uint_t* dst = (uint_t*)&As[node][qq*8];
        #pragma unroll
        for (int i = 0; i < 4; ++i)
            dst[i] = (uint_t)f2bf(acc[2*i]) | ((uint_t)f2bf(acc[2*i+1]) << 16);
    }
    __syncthreads();
    const int w = tid >> 6, lane = tid & 63, l15 = lane & 15, quad = lane >> 4;
    const int rt = w & 1;
    const int ct0 = (w >> 1) * 4;
    float4v o[4];
    #pragma unroll
    for (int t = 0; t < 4; ++t) o[t] = (float4v)0.f;
    #pragma unroll
    for (int kc = 0; kc < 2; ++kc){
        short8 a = *(const short8*)(&As[rt*16 + l15][kc*32 + quad*8]);
        #pragma unroll
        for (int t = 0; t < 4; ++t){
            short8 bfr = *(const short8*)(W + (size_t)((ct0 + t)*16 + l15)*64 + kc*32 + quad*8);
            o[t] = __builtin_amdgcn_mfma_f32_16x16x32_bf16(a, bfr, o[t], 0, 0, 0);
        }
    }
    __syncthreads();
    #pragma unroll
    for (int t = 0; t < 4; ++t){
        int cg = (ct0 + t)*16 + l15;
        #pragma unroll
        for (int r = 0; r < 4; ++r)
            As[rt*16 + quad*4 + r][cg] = f2bf(fmaxf(o[t][r] + bias[cg], 0.f));
    }
    __syncthreads();
    if (g < NN){
        uint4* op = (uint4*)(out + (size_t)g*H + qq*16);
        const uint4* sp = (const uint4*)&As[node][qq*16];
        op[0] = sp[0]; op[1] = sp[1];
    }
}

// ========== per-graph tail v6: A0 (K direct-global, 2 head-pairs/iter) + SAB + PMA2 + head ==========
// 512 threads (8 waves), 2 blocks/CU, ~81.5 KB LDS
struct TailArgs {
    const ushort_t* Khm; const ushort_t* Vhm;   // head-major K/V [(hp)*NB + b]
    const ushort_t* q0;  const ushort_t* q2;
    const ushort_t* p1foW; const float* p1fob;
    const ushort_t* sfqW;  const float* sfqb;
    const ushort_t* skW;   const float* skb;
    const ushort_t* svW;   const float* svb;
    const ushort_t* sfoW;  const float* sfob;
    const ushort_t* p2kW;  const float* p2kb;
    const ushort_t* p2vW;  const float* p2vb;
    const ushort_t* p2foW; const float* p2fob;
    const ushort_t* lin2W; const float* lin2b;
    const float* hergv;
    const float* hoW; const float* hob;
    const float* fcW; const float* fcb;
    const float* sW;  const float* sb;
    float* outp;
};

__global__ __launch_bounds__(512, 4) void k_graph_tail(TailArgs a){
    __shared__ ushort_t bufA[85*136];
    __shared__ ushort_t bufB[80*136];
    __shared__ ushort_t bufC[80*136];
    __shared__ ushort_t vt4[7424];        // A0: Vs heads 2-3 [2][16][232]; SAB: V^T [4][16][104]
    const int b = blockIdx.x, tid = threadIdx.x;
    const int w = tid >> 6, lane = tid & 63, l15 = lane & 15, quad = lane >> 4;

    // ======== A0: GMPool_G attention, 2 head-pairs (4 heads) per iteration ========
    // Vs4: head 0-1 -> bufC [2][16][232]; head 2-3 -> vt4 [2][16][232]; psw in bufB (w*512)
    // K read directly from global (L2-hot), key clamped to 199 (junk masked).
    // zero V pad keys 200..231 (stage writes only keys < 200; pads persist both iters)
    for (int i = tid; i < 64*32; i += 512){
        int r4 = i >> 5, kk = 200 + (i & 31);
        int head4 = r4 >> 4, dim = r4 & 15;
        ushort_t* dst = (head4 < 2) ? &bufC[(head4*16 + dim)*232] : &vt4[((head4-2)*16 + dim)*232];
        dst[kk] = 0;
    }
    for (int hpp = 0; hpp < 2; ++hpp){
        __syncthreads();   // protect Vs (and pads on iter 0) from prior reads
        // stage V for head-pairs hpp*2, hpp*2+1 (4 heads) transposed
        for (int idx = tid; idx < 2*200*8; idx += 512){
            int hpl = idx / 1600, rem = idx % 1600;
            int key = rem >> 3, p = rem & 7;
            int hh = p >> 2, dl = (p & 3)*4;
            int hp = hpp*2 + hpl;
            int head4 = hpl*2 + hh;
            const ushort_t* src = a.Vhm + ((size_t)hp*NB + b)*(size_t)200*32 + (size_t)key*32 + hh*16 + dl;
            ushort_t* base = (head4 < 2) ? &bufC[(head4*16)*232] : &vt4[((head4-2)*16)*232];
            base[(dl+0)*232 + key] = src[0];
            base[(dl+1)*232 + key] = src[1];
            base[(dl+2)*232 + key] = src[2];
            base[(dl+3)*232 + key] = src[3];
        }
        __syncthreads();
        // 20 jobs (4 heads x 5 q-tiles) over 8 waves
        for (int j = w; j < 20; j += 8){
            int hl4 = j / 5, qt = j % 5;
            int hp = hpp*2 + (hl4 >> 1);
            int hh = hl4 & 1;
            int gh = hp*2 + hh;
            ushort_t* psw = bufB + w*512;
            const ushort_t* Kb = a.Khm + ((size_t)hp*NB + b)*(size_t)200*32;
            int qr = qt*16 + l15; if (qr > NS-1) qr = NS-1;
            short8 av = *(const short8*)(a.q0 + (size_t)qr*H + gh*16 + (quad & 1)*8);
            short8 zero8 = (short8)0;
            bool klow = (quad < 2);
            short8 afrag = klow ? av : zero8;
            float4v s[13];
            #pragma unroll
            for (int kt = 0; kt < 13; ++kt){
                int kk = kt*16 + l15; if (kk > 199) kk = 199;   // junk rows masked below
                short8 bv = *(const short8*)(Kb + (size_t)kk*32 + hh*16 + (quad & 1)*8);
                short8 bfrag = klow ? bv : zero8;
                s[kt] = __builtin_amdgcn_mfma_f32_16x16x32_bf16(afrag, bfrag, (float4v)0.f, 0, 0, 0);
            }
            float mx[4] = {-1e30f, -1e30f, -1e30f, -1e30f};
            #pragma unroll
            for (int kt = 0; kt < 13; ++kt){
                if (kt*16 + l15 >= 200){ s[kt][0]=-1e30f; s[kt][1]=-1e30f; s[kt][2]=-1e30f; s[kt][3]=-1e30f; }
                #pragma unroll
                for (int r = 0; r < 4; ++r) mx[r] = fmaxf(mx[r], s[kt][r]);
            }
            #pragma unroll
            for (int off = 1; off < 16; off <<= 1){
                #pragma unroll
                for (int r = 0; r < 4; ++r) mx[r] = fmaxf(mx[r], __shfl_xor(mx[r], off));
            }
            const ushort_t* vbase = (hl4 < 2) ? &bufC[(hl4*16)*232] : &vt4[((hl4-2)*16)*232];
            float sum[4] = {0.f, 0.f, 0.f, 0.f};
            float4v o = (float4v)0.f;
            #pragma unroll
            for (int kc = 0; kc < 7; ++kc){
                #pragma unroll
                for (int t2 = 0; t2 < 2; ++t2){
                    int kt = kc*2 + t2;
                    #pragma unroll
                    for (int r = 0; r < 4; ++r){
                        float e = 0.f;
                        if (kt < 13){ e = __expf((s[kt][r] - mx[r]) * SCALE); sum[r] += e; }
                        psw[(quad*4 + r)*32 + t2*16 + l15] = f2bf(e);
                    }
                }
                short8 pa = *(const short8*)(psw + l15*32 + quad*8);
                short8 vb = *(const short8*)(vbase + l15*232 + kc*32 + quad*8);
                o = __builtin_amdgcn_mfma_f32_16x16x32_bf16(pa, vb, o, 0, 0, 0);
            }
            #pragma unroll
            for (int off = 1; off < 16; off <<= 1){
                #pragma unroll
                for (int r = 0; r < 4; ++r) sum[r] += __shfl_xor(sum[r], off);
            }
            #pragma unroll
            for (int r = 0; r < 4; ++r){
                int row = qt*16 + quad*4 + r;
                if (row < NS){
                    float qv = bf2f(a.q0[(size_t)row*H + gh*16 + l15]);
                    bufA[row*136 + gh*16 + l15] = f2bf(qv + o[r] / sum[r]);
                }
            }
        }
    }
    __syncthreads();

    // P1: bufA = xA + relu(xA @ p1foW^T + b) IN-PLACE (waves 0-4); waves 5-7 zero vt4 SAB arena
    if (w >= 5){
        for (int i = tid - 320; i < 64*104/2; i += 192) ((uint_t*)vt4)[i] = 0u;
    }
    for (int rt = w; rt < 5; rt += 8){
        float4v o[8];
        #pragma unroll
        for (int i = 0; i < 8; ++i) o[i] = (float4v)0.f;
        #pragma unroll
        for (int kc = 0; kc < 4; ++kc){
            short8 av = *(const short8*)(bufA + (rt*16 + l15)*136 + kc*32 + quad*8);
            #pragma unroll
            for (int ct = 0; ct < 8; ++ct){
                short8 bv = *(const short8*)((const short*)(a.p1foW + (size_t)(ct*16 + l15)*H) + kc*32 + quad*8);
                o[ct] = __builtin_amdgcn_mfma_f32_16x16x32_bf16(av, bv, o[ct], 0, 0, 0);
            }
        }
        #pragma unroll
        for (int ct = 0; ct < 8; ++ct){
            int c = ct*16 + l15; float bb = a.p1fob[c];
            #pragma unroll
            for (int r = 0; r < 4; ++r){
                int row = rt*16 + quad*4 + r;
                float res = bf2f(bufA[row*136 + c]);
                bufA[row*136 + c] = f2bf(fmaxf(o[ct][r] + bb, 0.f) + res);
            }
        }
    }
    __syncthreads();

    // P2: SAB projections from bufA: Q->bufB, K->bufC
    for (int job = w; job < 40; job += 8){
        int rt = job >> 3, ct = job & 7;
        float4v o = (float4v)0.f;
        #pragma unroll
        for (int kc = 0; kc < 4; ++kc){
            short8 av = *(const short8*)(bufA + (rt*16 + l15)*136 + kc*32 + quad*8);
            short8 bv = *(const short8*)((const short*)(a.sfqW + (size_t)(ct*16 + l15)*H) + kc*32 + quad*8);
            o = __builtin_amdgcn_mfma_f32_16x16x32_bf16(av, bv, o, 0, 0, 0);
        }
        int c = ct*16 + l15; float bb = a.sfqb[c];
        #pragma unroll
        for (int r = 0; r < 4; ++r)
            bufB[(rt*16 + quad*4 + r)*136 + c] = f2bf(o[r] + bb);
    }
    for (int job = w; job < 40; job += 8){
        int rt = job >> 3, ct = job & 7;
        float4v o = (float4v)0.f;
        #pragma unroll
        for (int kc = 0; kc < 4; ++kc){
            short8 av = *(const short8*)(bufA + (rt*16 + l15)*136 + kc*32 + quad*8);
            short8 bv = *(const short8*)((const short*)(a.skW + (size_t)(ct*16 + l15)*H) + kc*32 + quad*8);
            o = __builtin_amdgcn_mfma_f32_16x16x32_bf16(av, bv, o, 0, 0, 0);
        }
        int c = ct*16 + l15; float bb = a.skb[c];
        #pragma unroll
        for (int r = 0; r < 4; ++r)
            bufC[(rt*16 + quad*4 + r)*136 + c] = f2bf(o[r] + bb);
    }
    __syncthreads();

    // P3: SAB attention, two 4-head passes (V-proj over 8 waves; attn on waves 0-3)
    for (int pass = 0; pass < 2; ++pass){
        int hbase = pass*4;
        for (int job = w; job < 20; job += 8){
            int rt = job >> 2, ctl = job & 3;
            int ct = hbase + ctl;
            float4v o = (float4v)0.f;
            #pragma unroll
            for (int kc = 0; kc < 4; ++kc){
                short8 av = *(const short8*)(bufA + (rt*16 + l15)*136 + kc*32 + quad*8);
                short8 bv = *(const short8*)((const short*)(a.svW + (size_t)(ct*16 + l15)*H) + kc*32 + quad*8);
                o = __builtin_amdgcn_mfma_f32_16x16x32_bf16(av, bv, o, 0, 0, 0);
            }
            int c = ct*16 + l15; float bb = a.svb[c];
            #pragma unroll
            for (int r = 0; r < 4; ++r){
                int key = rt*16 + quad*4 + r;
                if (key < NS) vt4[(ctl*16 + l15)*104 + key] = f2bf(o[r] + bb);
            }
        }
        __syncthreads();
        if (w < 4){
            ushort_t* psw = (w == 0) ? bufA + 10200 :
                            (w == 1) ? bufA + 10712 :
                            (w == 2) ? bufB + 10200 : bufC + 10200;
            int hl = w, h = hbase + w;
            short8 zero8 = (short8)0;
            bool klow = (quad < 2);
            for (int qt = 0; qt < 5; ++qt){
                short8 av = *(const short8*)(bufB + (qt*16 + l15)*136 + h*16 + (quad & 1)*8);
                short8 afrag = klow ? av : zero8;
                float4v s[5];
                #pragma unroll
                for (int kt = 0; kt < 5; ++kt){
                    short8 bv = *(const short8*)(bufC + (kt*16 + l15)*136 + h*16 + (quad & 1)*8);
                    short8 bfrag = klow ? bv : zero8;
                    s[kt] = __builtin_amdgcn_mfma_f32_16x16x32_bf16(afrag, bfrag, (float4v)0.f, 0, 0, 0);
                }
                float mx[4] = {-1e30f, -1e30f, -1e30f, -1e30f};
                #pragma unroll
                for (int kt = 0; kt < 5; ++kt){
                    if (kt*16 + l15 >= NS){ s[kt][0]=-1e30f; s[kt][1]=-1e30f; s[kt][2]=-1e30f; s[kt][3]=-1e30f; }
                    #pragma unroll
                    for (int r = 0; r < 4; ++r) mx[r] = fmaxf(mx[r], s[kt][r]);
                }
                #pragma unroll
                for (int off = 1; off < 16; off <<= 1){
                    #pragma unroll
                    for (int r = 0; r < 4; ++r) mx[r] = fmaxf(mx[r], __shfl_xor(mx[r], off));
                }
                float sum[4] = {0.f, 0.f, 0.f, 0.f};
                float4v o = (float4v)0.f;
                #pragma unroll
                for (int kc = 0; kc < 3; ++kc){
                    #pragma unroll
                    for (int t2 = 0; t2 < 2; ++t2){
                        int kt = kc*2 + t2;
                        #pragma unroll
                        for (int r = 0; r < 4; ++r){
                            float e = 0.f;
                            if (kt < 5){ e = __expf((s[kt][r] - mx[r]) * SCALE); sum[r] += e; }
                            psw[(quad*4 + r)*32 + t2*16 + l15] = f2bf(e);
                        }
                    }
                    short8 pa = *(const short8*)(psw + l15*32 + quad*8);
                    short8 vb = *(const short8*)(vt4 + (hl*16 + l15)*104 + kc*32 + quad*8);
                    o = __builtin_amdgcn_mfma_f32_16x16x32_bf16(pa, vb, o, 0, 0, 0);
                }
                #pragma unroll
                for (int off = 1; off < 16; off <<= 1){
                    #pragma unroll
                    for (int r = 0; r < 4; ++r) sum[r] += __shfl_xor(sum[r], off);
                }
                #pragma unroll
                for (int r = 0; r < 4; ++r){
                    int row = qt*16 + quad*4 + r;
                    if (row < NS){
                        float qv = bf2f(bufB[row*136 + h*16 + l15]);
                        bufB[row*136 + h*16 + l15] = f2bf(qv + o[r] / sum[r]);
                    }
                }
            }
        }
        __syncthreads();
    }

    // P4: xb2 = attnout(bufB) + relu(attnout @ sfoW^T + b) -> bufA (xb1 dead)
    for (int job = w; job < 40; job += 8){
        int rt = job >> 3, ct = job & 7;
        float4v o = (float4v)0.f;
        #pragma unroll
        for (int kc = 0; kc < 4; ++kc){
            short8 av = *(const short8*)(bufB + (rt*16 + l15)*136 + kc*32 + quad*8);
            short8 bv = *(const short8*)((const short*)(a.sfoW + (size_t)(ct*16 + l15)*H) + kc*32 + quad*8);
            o = __builtin_amdgcn_mfma_f32_16x16x32_bf16(av, bv, o, 0, 0, 0);
        }
        int c = ct*16 + l15; float bb = a.sfob[c];
        #pragma unroll
        for (int r = 0; r < 4; ++r){
            int row = rt*16 + quad*4 + r;
            bufA[row*136 + c] = f2bf(fmaxf(o[r] + bb, 0.f) + bf2f(bufB[row*136 + c]));
        }
    }
    __syncthreads();

    // P5: PMA2 K -> bufC, V -> bufB (from bufA = xb2)
    for (int job = w; job < 40; job += 8){
        int rt = job >> 3, ct = job & 7;
        float4v o = (float4v)0.f;
        #pragma unroll
        for (int kc = 0; kc < 4; ++kc){
            short8 av = *(const short8*)(bufA + (rt*16 + l15)*136 + kc*32 + quad*8);
            short8 bv = *(const short8*)((const short*)(a.p2kW + (size_t)(ct*16 + l15)*H) + kc*32 + quad*8);
            o = __builtin_amdgcn_mfma_f32_16x16x32_bf16(av, bv, o, 0, 0, 0);
        }
        int c = ct*16 + l15; float bb = a.p2kb[c];
        #pragma unroll
        for (int r = 0; r < 4; ++r)
            bufC[(rt*16 + quad*4 + r)*136 + c] = f2bf(o[r] + bb);
    }
    for (int job = w; job < 40; job += 8){
        int rt = job >> 3, ct = job & 7;
        float4v o = (float4v)0.f;
        #pragma unroll
        for (int kc = 0; kc < 4; ++kc){
            short8 av = *(const short8*)(bufA + (rt*16 + l15)*136 + kc*32 + quad*8);
            short8 bv = *(const short8*)((const short*)(a.p2vW + (size_t)(ct*16 + l15)*H) + kc*32 + quad*8);
            o = __builtin_amdgcn_mfma_f32_16x16x32_bf16(av, bv, o, 0, 0, 0);
        }
        int c = ct*16 + l15; float bb = a.p2vb[c];
        #pragma unroll
        for (int r = 0; r < 4; ++r)
            bufB[(rt*16 + quad*4 + r)*136 + c] = f2bf(o[r] + bb);
    }
    __syncthreads();

    // P6: 1-seed attention + p2fo residual + lin2 + head MLP (scratch aliases bufA)
    {
        int t = tid;
        char* sb8 = (char*)bufA;
        float* sc       = (float*)sb8;              // 8*76 floats
        float* sumh     = (float*)(sb8 + 2432);     // 8
        ushort_t* xa    = (ushort_t*)(sb8 + 2464);  // 128
        ushort_t* xb3   = (ushort_t*)(sb8 + 2720);  // 128
        float* tt       = (float*)(sb8 + 2976);     // 128
        float* v256     = (float*)(sb8 + 3488);     // 256
        float* red      = (float*)(sb8 + 4512);     // 128
        if (t < 256){
            int h = t >> 5, l32 = t & 31;
            const ushort_t* qr = a.q2 + h*16;
            for (int k = l32; k < NS; k += 32){
                float s = 0.f;
                #pragma unroll
                for (int d = 0; d < 16; ++d) s += bf2f(qr[d]) * bf2f(bufC[k*136 + h*16 + d]);
                sc[h*76 + k] = s;
            }
        }
        __syncthreads();
        if (t < 128){
            int hh = t >> 4, i = t & 15;
            float mx = -1e30f;
            for (int k = i; k < NS; k += 16) mx = fmaxf(mx, sc[hh*76 + k]);
            #pragma unroll
            for (int off = 1; off < 16; off <<= 1) mx = fmaxf(mx, __shfl_xor(mx, off));
            float sm = 0.f;
            for (int k = i; k < NS; k += 16){
                float e = __expf((sc[hh*76 + k] - mx) * SCALE);
                sc[hh*76 + k] = e;
                sm += e;
            }
            #pragma unroll
            for (int off = 1; off < 16; off <<= 1) sm += __shfl_xor(sm, off);
            if (i == 0) sumh[hh] = sm;
        }
        __syncthreads();
        if (t < 128){
            int hh = t >> 4;
            float o = 0.f;
            for (int k = 0; k < NS; ++k) o += sc[hh*76 + k] * bf2f(bufB[k*136 + t]);
            xa[t] = f2bf(bf2f(a.q2[t]) + o / sumh[hh]);
        }
        __syncthreads();
        if (t < 128){
            float acc = 0.f;
            const ushort_t* wr = a.p2foW + (size_t)t*H;
            for (int k = 0; k < H; ++k) acc += bf2f(xa[k]) * bf2f(wr[k]);
            xb3[t] = f2bf(fmaxf(acc + a.p2fob[t], 0.f) + bf2f(xa[t]));
        }
        __syncthreads();
        if (t < 128){
            float acc = 0.f;
            const ushort_t* wr = a.lin2W + (size_t)t*H;
            for (int k = 0; k < H; ++k) acc += bf2f(xb3[k]) * bf2f(wr[k]);
            v256[t] = acc + a.lin2b[t];
            v256[128 + t] = a.hergv[t];
        }
        __syncthreads();
        if (t < 128){
            float acc = 0.f;
            const float* wr = a.hoW + (size_t)t*256;
            for (int k = 0; k < 256; ++k) acc += v256[k] * wr[k];
            tt[t] = fmaxf(acc + a.hob[t], 0.f);
        }
        __syncthreads();
        if (t < 128){
            float acc = 0.f;
            const float* wr = a.fcW + (size_t)t*128;
            for (int k = 0; k < 128; ++k) acc += tt[k] * wr[k];
            float uv = fmaxf(acc + a.fcb[t], 0.f);
            red[t] = uv * a.sW[t];
        }
        __syncthreads();
        for (int s = 64; s > 0; s >>= 1){
            if (t < s) red[t] += red[t + s];
            __syncthreads();
        }
        if (t == 0){
            float logit = red[0] + a.sb[0];
            a.outp[b] = 1.f / (1.f + expf(-logit));
        }
    }
}

extern "C" void kernel_launch(void* const* d_in, const int* in_sizes, int n_in,
                              void* d_out, int out_size, void* d_ws, size_t ws_size,
                              hipStream_t stream)
{
    (void)in_sizes; (void)n_in; (void)out_size; (void)ws_size;
    const float* herg_em = (const float*)d_in[0];
    const float* x_in    = (const float*)d_in[1];
    const float* convW[4] = {(const float*)d_in[4], (const float*)d_in[6], (const float*)d_in[8], (const float*)d_in[10]};
    const float* convB[4] = {(const float*)d_in[5], (const float*)d_in[7], (const float*)d_in[9], (const float*)d_in[11]};
    const float* lin1W = (const float*)d_in[12]; const float* lin1b = (const float*)d_in[13];
    const float* lin2W = (const float*)d_in[14]; const float* lin2b = (const float*)d_in[15];
    const float* S1    = (const float*)d_in[16];
    const float* p1fqW = (const float*)d_in[17]; const float* p1fqb = (const float*)d_in[18];
    const float* p1kW  = (const float*)d_in[19]; const float* p1kb  = (const float*)d_in[20];
    const float* p1vW  = (const float*)d_in[21]; const float* p1vb  = (const float*)d_in[22];
    const float* p1foW = (const float*)d_in[23]; const float* p1fob = (const float*)d_in[24];
    const float* sfqW  = (const float*)d_in[25]; const float* sfqb  = (const float*)d_in[26];
    const float* skW   = (const float*)d_in[27]; const float* skb   = (const float*)d_in[28];
    const float* svW   = (const float*)d_in[29]; const float* svb   = (const float*)d_in[30];
    const float* sfoW  = (const float*)d_in[31]; const float* sfob  = (const float*)d_in[32];
    const float* p2fqW = (const float*)d_in[33]; const float* p2fqb = (const float*)d_in[34];
    const float* p2kW  = (const float*)d_in[35]; const float* p2kb  = (const float*)d_in[36];
    const float* p2vW  = (const float*)d_in[37]; const float* p2vb  = (const float*)d_in[38];
    const float* p2foW = (const float*)d_in[39]; const float* p2fob = (const float*)d_in[40];
    const float* S2    = (const float*)d_in[41];
    const float* hlW   = (const float*)d_in[42]; const float* hlb   = (const float*)d_in[43];
    const float* hoW   = (const float*)d_in[44]; const float* hob   = (const float*)d_in[45];
    const float* fcW   = (const float*)d_in[46]; const float* fcb   = (const float*)d_in[47];
    const float* sW    = (const float*)d_in[48]; const float* sb    = (const float*)d_in[49];
    const int*  ei    = (const int*)d_in[50];
    const int*  esrc  = ei;
    const int*  edst  = ei + NE;
    float* outp = (float*)d_out;

    // -------- workspace layout (byte offsets, 16B-aligned) --------
    char* WS = (char*)d_ws;
    int*   counts = (int*)(WS + 0);
    int*   cursor = (int*)(WS + 400384);
    int*   row_st = (int*)(WS + 800768);
    int*   bSums  = (int*)(WS + 1201152);
    int*   bOff   = (int*)(WS + 1203200);
    float* dinv   = (float*)(WS + 1205248);
    float* selfc  = (float*)(WS + 1605632);
    int*   srcs_s = (int*)(WS + 2005632);
    float* ce_s   = (float*)(WS + 3605632);
    ushort_t* wbf = (ushort_t*)(WS + 5205632); // 17*16384
    ushort_t* w0bf= (ushort_t*)(WS + 5762688);
    ushort_t* s1bf= (ushort_t*)(WS + 5779072);
    ushort_t* s2bf= (ushort_t*)(WS + 5798272);
    ushort_t* q0  = (ushort_t*)(WS + 5798528);
    ushort_t* q2  = (ushort_t*)(WS + 5817728);
    float* hergv  = (float*)(WS + 5817984);
    ushort_t* xb64= (ushort_t*)(WS + 6074496); // NN*64 bf16 padded raw x
    ushort_t* b0  = (ushort_t*)(WS + 18874496);// NN*128
    ushort_t* b1  = (ushort_t*)(WS + 44474496);
    ushort_t* b2  = (ushort_t*)(WS + 70074496);

    const int gN   = (NN + 255)/256;       // 391
    const int gE   = (NE + 255)/256;       // 1563
    const int gC   = (NN + 31)/32;         // 3125

    // ---- merged weight/input conversions + counts zeroing (1 launch, FIRST) ----
    CvtArgs ca;
    ca.w[0]=convW[1]; ca.w[1]=convW[2]; ca.w[2]=convW[3]; ca.w[3]=lin1W; ca.w[4]=lin2W;
    ca.w[5]=p1kW; ca.w[6]=p1vW; ca.w[7]=p1foW;
    ca.w[8]=sfqW; ca.w[9]=skW; ca.w[10]=svW; ca.w[11]=sfoW;
    ca.w[12]=p2kW; ca.w[13]=p2vW; ca.w[14]=p2foW; ca.w[15]=p1fqW; ca.w[16]=p2fqW;
    ca.w0 = convW[0]; ca.s1 = S1; ca.s2 = S2; ca.x37 = x_in;
    const int cvtTotal = CVT_W + CVT_W0 + CVT_S1 + CVT_S2 + CVT_X;
    k_cvt_all<<<(cvtTotal + 255)/256, 256, 0, stream>>>(ca, wbf, w0bf, s1bf, s2bf, xb64, counts);

    // ---- CSR build (+ seedQ/hERG/scan2 merged) ----
    k_hist  <<<gE, 256, 0, stream>>>(counts, edst, NE);
    k_scan1 <<<gN, 256, 0, stream>>>(counts, row_st, bSums, dinv, selfc, NN);
    k_seedq_scan2<<<5, 512, 0, stream>>>(s1bf, s2bf, wbf + (size_t)15*16384, p1fqb,
                                   wbf + (size_t)16*16384, p2fqb, q0, q2,
                                   herg_em, hlW, hlb, hergv,
                                   bSums, bOff, gN);
    k_scan3 <<<gN, 256, 0, stream>>>(row_st, cursor, bOff, NN, NE);
    k_fillcsr<<<gE, 256, 0, stream>>>(esrc, edst, dinv, cursor, srcs_s, ce_s, NE);

    // ---- conv0 (fused gather64 + GEMM) -> b0 ----
    k_conv0b<<<gC, 256, 0, stream>>>(xb64, row_st, srcs_s, ce_s, selfc, w0bf, convB[0], b0);
    // ---- conv1, conv2 ----
    k_conv_fused3<8,1,0,8><<<gC, 256, 0, stream>>>(b0, row_st, srcs_s, ce_s, selfc,
        wbf + (size_t)0*16384, convB[1], nullptr, nullptr, nullptr, b1, nullptr);
    k_conv_fused3<8,1,0,8><<<gC, 256, 0, stream>>>(b1, row_st, srcs_s, ce_s, selfc,
        wbf + (size_t)1*16384, convB[2], nullptr, nullptr, nullptr, b0, nullptr);
    // ---- conv3 + lin1 fused -> hx in b1 ----
    k_conv_fused3<8,1,1,8><<<gC, 256, 0, stream>>>(b0, row_st, srcs_s, ce_s, selfc,
        wbf + (size_t)2*16384, convB[3], nullptr, wbf + (size_t)3*16384, lin1b, b1, nullptr);
    // ---- pma1 K,V: fused shared-gather + dual GEMM, HEAD-MAJOR out (K->b2, V->b0) ----
    k_conv_fused3<16,0,0,4><<<gC, 256, 0, stream>>>(b1, row_st, srcs_s, ce_s, selfc,
        wbf + (size_t)5*16384, p1kb, p1vb, nullptr, nullptr, b2, b0);

    // ---- per-graph tail v6 ----
    TailArgs ta;
    ta.Khm = b2; ta.Vhm = b0; ta.q0 = q0; ta.q2 = q2;
    ta.p1foW = wbf + (size_t)7*16384;  ta.p1fob = p1fob;
    ta.sfqW  = wbf + (size_t)8*16384;  ta.sfqb  = sfqb;
    ta.skW   = wbf + (size_t)9*16384;  ta.skb   = skb;
    ta.svW   = wbf + (size_t)10*16384; ta.svb   = svb;
    ta.sfoW  = wbf + (size_t)11*16384; ta.sfob  = sfob;
    ta.p2kW  = wbf + (size_t)12*16384; ta.p2kb  = p2kb;
    ta.p2vW  = wbf + (size_t)13*16384; ta.p2vb  = p2vb;
    ta.p2foW = wbf + (size_t)14*16384; ta.p2fob = p2fob;
    ta.lin2W = wbf + (size_t)4*16384;  ta.lin2b = lin2b;
    ta.hergv = hergv;
    ta.hoW = hoW; ta.hob = hob;
    ta.fcW = fcW; ta.fcb = fcb;
    ta.sW = sW; ta.sb = sb;
    ta.outp = outp;
    k_graph_tail<<<NB, 512, 0, stream>>>(ta);
}